// Round 14
// baseline (673.180 us; speedup 1.0000x reference)
//
#include <hip/hip_runtime.h>
#include <stdint.h>

typedef short bf16x8 __attribute__((ext_vector_type(8)));
typedef short s16x4 __attribute__((ext_vector_type(4)));
typedef float f32x4 __attribute__((ext_vector_type(4)));
typedef unsigned int u32;

#define EPS_A 1e-8f
#define THR_A 1e-6f
#define NN 8192

static __device__ __forceinline__ short f2bf(float f) {
  u32 u = __float_as_uint(f);
  u = u + 0x7FFFu + ((u >> 16) & 1u);   // RNE, no NaN inputs here
  return (short)(u >> 16);
}
static __device__ __forceinline__ float bf2f(short s) {
  return __uint_as_float(((u32)(unsigned short)s) << 16);
}
// async global->LDS, 16B per lane; DIRECT addrspacecasts (proven round 12)
static __device__ __forceinline__ void gld16(const short* g, short* l) {
  __builtin_amdgcn_global_load_lds(
      (const __attribute__((address_space(1))) u32*)g,
      (__attribute__((address_space(3))) u32*)l, 16, 0, 0);
}

// ---- fused prep: Mt transpose-cast + colsum/colmax, all weight/feature casts,
//      bias folds — ONE launch, 9603 blocks
__global__ __launch_bounds__(256) void k_prep_all(
    const float* __restrict__ Mob, const float* __restrict__ nf,
    const float* __restrict__ W_in1, const float* __restrict__ W_out1,
    const float* __restrict__ W_self1, const float* __restrict__ W_in2,
    const float* __restrict__ W_out2, const float* __restrict__ W_self2,
    const float* __restrict__ b_in1, const float* __restrict__ b_out1,
    const float* __restrict__ b_self1, const float* __restrict__ b_out2,
    const float* __restrict__ b_self2,
    short* __restrict__ Mt, float* __restrict__ colsum, u32* __restrict__ colmax,
    short* __restrict__ nft, short* __restrict__ A1cat, short* __restrict__ Win1b,
    short* __restrict__ Wout1t, short* __restrict__ Bcat1, short* __restrict__ Win2t,
    short* __restrict__ Bcat2, float* __restrict__ bias1c, float* __restrict__ bias2c)
{
  __shared__ __align__(16) short sbuf[256 * 66];
  int b = blockIdx.x;
  const int t = threadIdx.x;
  if (b < 4096) {                      // Mt: transpose-cast + colsum/colmax
    const int i0 = (b & 31) * 256;
    const int j0 = (b >> 5) * 64;
    const int i = i0 + t;
    float s = 0.f, mx = 0.f;
    #pragma unroll 4
    for (int jj = 0; jj < 64; ++jj) {
      float v = Mob[(size_t)(j0 + jj) * NN + i];   // coalesced: t -> i
      s += v;
      mx = fmaxf(mx, v);
      sbuf[t * 66 + jj] = f2bf(v);
    }
    atomicAdd(&colsum[i], s);
    atomicMax(&colmax[i], __float_as_uint(mx));
    __syncthreads();
    #pragma unroll
    for (int p = 0; p < 8; ++p) {
      const int r = p * 32 + (t >> 3);
      const int c = t & 7;
      const u32* src = (const u32*)((const char*)sbuf + r * 132 + c * 16);
      int4 w = make_int4(src[0], src[1], src[2], src[3]);
      *(int4*)((char*)Mt + (((size_t)(i0 + r) * NN + j0) * 2 + c * 16)) = w;
    }
    return;
  }
  b -= 4096;
  if (b < 512) {                       // nf^T: LDS-tiled transpose-cast 8192x256
    short (*tile)[65] = (short(*)[65])sbuf;
    const int r0 = (b & 127) * 64, c0 = (b >> 7) * 64;
    #pragma unroll
    for (int p = 0; p < 16; ++p) {
      const int rr = p * 4 + (t >> 6), cc = t & 63;
      tile[rr][cc] = f2bf(nf[(size_t)(r0 + rr) * 256 + c0 + cc]);
    }
    __syncthreads();
    #pragma unroll
    for (int q = 0; q < 16; ++q) {
      const int cc = q * 4 + (t >> 6), rr = t & 63;
      nft[(size_t)(c0 + cc) * 8192 + r0 + rr] = tile[rr][cc];
    }
    return;
  }
  b -= 512;
  if (b < 2048) {                      // nf -> A1cat cols 256:512
    const int idx = b * 256 + t;
    const float4 v = ((const float4*)nf)[idx];
    const int i = idx >> 6;
    const int c = (idx & 63) * 4;
    s16x4 o;
    o.x = f2bf(v.x); o.y = f2bf(v.y); o.z = f2bf(v.z); o.w = f2bf(v.w);
    *(s16x4*)&A1cat[(size_t)i * 512 + 256 + c] = o;
    return;
  }
  b -= 2048;
  if (b < 128) {                       // W_in1 straight cast 256x512
    const int idx = b * 256 + t;
    const float4 v = ((const float4*)W_in1)[idx];
    s16x4 o;
    o.x = f2bf(v.x); o.y = f2bf(v.y); o.z = f2bf(v.z); o.w = f2bf(v.w);
    *(s16x4*)&Win1b[idx * 4] = o;
    return;
  }
  b -= 128;
  if (b < 1024) {                      // W_out1^T 512x512 -> Wout1t ld 512
    const int idx = b * 256 + t;
    const int r = idx >> 9, c = idx & 511;
    Wout1t[(size_t)c * 512 + r] = f2bf(W_out1[idx]);
    return;
  }
  b -= 1024;
  if (b < 512) {                       // W_self1^T 256x512 -> Bcat1+256 ld 512
    const int idx = b * 256 + t;
    const int r = idx >> 9, c = idx & 511;
    Bcat1[(size_t)c * 512 + 256 + r] = f2bf(W_self1[idx]);
    return;
  }
  b -= 512;
  if (b < 512) {                       // W_in2^T 512x256 -> Win2t ld 512
    const int idx = b * 256 + t;
    const int r = idx >> 8, c = idx & 255;
    Win2t[(size_t)c * 512 + r] = f2bf(W_in2[idx]);
    return;
  }
  b -= 512;
  if (b < 256) {                       // W_out2^T 256x256 -> Bcat2 ld 768
    const int idx = b * 256 + t;
    const int r = idx >> 8, c = idx & 255;
    Bcat2[(size_t)c * 768 + r] = f2bf(W_out2[idx]);
    return;
  }
  b -= 256;
  if (b < 512) {                       // W_self2^T 512x256 -> Bcat2+256 ld 768
    const int idx = b * 256 + t;
    const int r = idx >> 8, c = idx & 255;
    Bcat2[(size_t)c * 768 + 256 + r] = f2bf(W_self2[idx]);
    return;
  }
  b -= 512;
  if (b < 2) {                         // bias1c = b_in1@W_out1 + b_out1 + b_self1
    const int n = b * 256 + t;
    float a = b_out1[n] + b_self1[n];
    for (int p = 0; p < 512; ++p) a += b_in1[p] * W_out1[(size_t)p * 512 + n];
    bias1c[n] = a;
    return;
  }
  bias2c[t] = b_out2[t] + b_self2[t];  // last block
}

// ---- old 64x64 reg-staged body (kept ONLY for tiny Wc1 GEMM; proven)
__global__ __launch_bounds__(256) void k_gemm_raw_n(
    const short* __restrict__ A, const short* __restrict__ B, int K, int ldA, int ldB,
    short* __restrict__ C, int ldC)
{
  constexpr int LDP = 40;
  __shared__ __align__(16) short As[64 * LDP];
  __shared__ __align__(16) short Bs[64 * LDP];
  const int t = threadIdx.x;
  const int m0 = blockIdx.y * 64, n0 = blockIdx.x * 64;
  const int wid = t >> 6, l = t & 63;
  const int wr = wid >> 1, wc = wid & 1;
  const int lr = l & 15, lk = l >> 4;
  f32x4 acc[2][2] = {};
  const int sr = t >> 2;
  const int sc = (t & 3) * 8;
  const short* gA0 = A + (size_t)(m0 + sr) * ldA + sc;
  const short* gB0 = B + (size_t)(n0 + sr) * ldB + sc;
  for (int k0 = 0; k0 < K; k0 += 32) {
    const int4 a0 = *(const int4*)(gA0 + k0);
    const int4 b0 = *(const int4*)(gB0 + k0);
    __syncthreads();
    *(int4*)&As[sr * LDP + sc] = a0;
    *(int4*)&Bs[sr * LDP + sc] = b0;
    __syncthreads();
    bf16x8 av[2], bv[2];
    #pragma unroll
    for (int mi = 0; mi < 2; ++mi)
      av[mi] = *(const bf16x8*)&As[(wr * 32 + mi * 16 + lr) * LDP + lk * 8];
    #pragma unroll
    for (int ni = 0; ni < 2; ++ni)
      bv[ni] = *(const bf16x8*)&Bs[(wc * 32 + ni * 16 + lr) * LDP + lk * 8];
    #pragma unroll
    for (int mi = 0; mi < 2; ++mi)
      #pragma unroll
      for (int ni = 0; ni < 2; ++ni)
        acc[mi][ni] = __builtin_amdgcn_mfma_f32_16x16x32_bf16(av[mi], bv[ni], acc[mi][ni], 0, 0, 0);
  }
  #pragma unroll
  for (int mi = 0; mi < 2; ++mi)
    #pragma unroll
    for (int r = 0; r < 4; ++r) {
      const int m = m0 + wr * 32 + mi * 16 + lk * 4 + r;
      #pragma unroll
      for (int ni = 0; ni < 2; ++ni) {
        const int n = n0 + wc * 32 + ni * 16 + lr;
        C[(size_t)m * ldC + n] = f2bf(acc[mi][ni][r]);
      }
    }
}

// ---- 64 x BN GEMM, BK=64, gld_lds staging, swizzled unified LDS (A rows 0..63,
// B rows 64..64+BN), 8-row chunks per wave, staggered K.  EPI 0: +bias0[m] bf16;
// EPI 2: +bias0[n] fp32.
template <int BN, int EPI>
__global__ __launch_bounds__(256) void k_g64(
    const short* __restrict__ A, const short* __restrict__ B, int K, int ldA, int ldB,
    void* __restrict__ Cout, int ldC, const float* __restrict__ bias0)
{
  constexpr int ROWS = 64 + BN;
  constexpr int CH = ROWS / 32;             // chunks per wave (8 rows each)
  constexpr int NI = BN / 32;
  __shared__ __align__(16) short S[ROWS * 64];
  const int t = threadIdx.x;

  const int gx = gridDim.x;
  int flat = blockIdx.y * gx + blockIdx.x;
  const int cpx = (gx * gridDim.y) >> 3;
  flat = (flat & 7) * cpx + (flat >> 3);
  const int bx = flat % gx, by = flat / gx;
  const int m0 = by * 64, n0 = bx * BN;

  const int wid = t >> 6, l = t & 63;
  const int wr = wid >> 1, wc = wid & 1;
  const int lr = l & 15, lk = l >> 4;

  f32x4 acc[2][NI] = {};

  const int lrow = l >> 3, lcol = l & 7;
  const int wbase = wid * (ROWS / 4);
  short* dbase = S + wbase * 64;            // wave-uniform LDS base
  const short* gsrc[CH];
  #pragma unroll
  for (int c = 0; c < CH; ++c) {
    const int ar = wbase + c * 8 + lrow;    // chunk wholly A or wholly B (8-aligned)
    const int scol = (lcol ^ (ar & 7)) * 8;
    gsrc[c] = (ar < 64) ? A + (size_t)(m0 + ar) * ldA + scol
                        : B + (size_t)(n0 + ar - 64) * ldB + scol;
  }

  const int niters = K >> 6;                // 8 or 12
  int kk = flat % niters;                   // staggered start
  for (int it = 0; it < niters; ++it) {
    const int koff = kk << 6;
    kk = (kk + 1 == niters) ? 0 : kk + 1;
    __syncthreads();
    #pragma unroll
    for (int c = 0; c < CH; ++c)
      gld16(gsrc[c] + koff, dbase + c * 512);
    __syncthreads();

    #pragma unroll
    for (int ks = 0; ks < 2; ++ks) {
      bf16x8 av[2], bv[NI];
      #pragma unroll
      for (int mi = 0; mi < 2; ++mi) {
        const int row = wr * 32 + mi * 16 + lr;
        av[mi] = *(const bf16x8*)&S[row * 64 + ((ks * 4 + lk) ^ (row & 7)) * 8];
      }
      #pragma unroll
      for (int ni = 0; ni < NI; ++ni) {
        const int row = 64 + wc * (BN / 2) + ni * 16 + lr;
        bv[ni] = *(const bf16x8*)&S[row * 64 + ((ks * 4 + lk) ^ (row & 7)) * 8];
      }
      #pragma unroll
      for (int mi = 0; mi < 2; ++mi)
        #pragma unroll
        for (int ni = 0; ni < NI; ++ni)
          acc[mi][ni] = __builtin_amdgcn_mfma_f32_16x16x32_bf16(av[mi], bv[ni], acc[mi][ni], 0, 0, 0);
    }
  }

  #pragma unroll
  for (int mi = 0; mi < 2; ++mi) {
    #pragma unroll
    for (int r = 0; r < 4; ++r) {
      const int m = m0 + wr * 32 + mi * 16 + lk * 4 + r;
      float bm = 0.f;
      if (EPI == 0) bm = bias0[m];
      #pragma unroll
      for (int ni = 0; ni < NI; ++ni) {
        const int n = n0 + wc * (BN / 2) + ni * 16 + lr;
        float v = acc[mi][ni][r];
        if (EPI == 0) ((short*)Cout)[(size_t)m * ldC + n] = f2bf(v + bm);
        else          ((float*)Cout)[(size_t)m * ldC + n] = v + bias0[n];
      }
    }
  }
}

// ---- 128x128 split-K GEMM (BK=64, gld_lds, stagger) + FUSED cross-z reduction:
// last z-block per tile (agent-scope counter) sums the 8 partials and applies the
// aggregation epilogue.  FB 0: row-substitute fallback; FB 1: gather fallback.
template <int FB>
__global__ __launch_bounds__(256) void k_sk128_red(
    const short* __restrict__ A, const short* __restrict__ B, int K, int ldA, int ldB,
    short* __restrict__ P, size_t pstride, u32* __restrict__ cnt,
    const float* __restrict__ colsum, const u32* __restrict__ colmax,
    const short* __restrict__ fb, int ldfb,
    short* __restrict__ out, int ldo)
{
  __shared__ __align__(16) short As[128 * 64];
  __shared__ __align__(16) short Bs[128 * 64];
  __shared__ int lastf;
  const int t = threadIdx.x;

  const int sk = blockIdx.z;
  A += (size_t)sk * K;
  B += (size_t)sk * K;

  const int gx = gridDim.x;
  int flat = blockIdx.y * gx + blockIdx.x;
  const int cpx = (gx * gridDim.y) >> 3;
  flat = (flat & 7) * cpx + (flat >> 3);
  const int bx = flat % gx, by = flat / gx;
  const int m0 = by * 128, n0 = bx * 128;

  const int wid = t >> 6, l = t & 63;
  const int wr = wid >> 1, wc = wid & 1;
  const int lr = l & 15, lk = l >> 4;

  f32x4 acc[4][4] = {};

  const int side = wid >> 1;
  const int hrow = (wid & 1) * 64;
  const short* Xp = side ? B : A;
  const int ldX = side ? ldB : ldA;
  const int x0 = side ? n0 : m0;
  short* dbase = (side ? Bs : As) + hrow * 64;
  const int lrow = l >> 3, lcol = l & 7;
  const short* g0 = Xp + (size_t)(x0 + hrow + lrow) * ldX + (lcol ^ lrow) * 8;
  const size_t st8 = (size_t)8 * ldX;

  const int niters = K >> 6;                 // 16
  int kk = (flat + sk * 3) & (niters - 1);   // staggered start

  for (int it = 0; it < niters; ++it) {
    const int koff = kk << 6;
    kk = (kk + 1) & (niters - 1);
    __syncthreads();
    gld16(g0 + koff,           dbase);
    gld16(g0 + koff + st8,     dbase + 512);
    gld16(g0 + koff + 2 * st8, dbase + 1024);
    gld16(g0 + koff + 3 * st8, dbase + 1536);
    gld16(g0 + koff + 4 * st8, dbase + 2048);
    gld16(g0 + koff + 5 * st8, dbase + 2560);
    gld16(g0 + koff + 6 * st8, dbase + 3072);
    gld16(g0 + koff + 7 * st8, dbase + 3584);
    __syncthreads();

    #pragma unroll
    for (int ks = 0; ks < 2; ++ks) {
      bf16x8 av[4], bv[4];
      #pragma unroll
      for (int mi = 0; mi < 4; ++mi) {
        const int row = wr * 64 + mi * 16 + lr;
        av[mi] = *(const bf16x8*)&As[row * 64 + ((ks * 4 + lk) ^ (lr & 7)) * 8];
      }
      #pragma unroll
      for (int ni = 0; ni < 4; ++ni) {
        const int row = wc * 64 + ni * 16 + lr;
        bv[ni] = *(const bf16x8*)&Bs[row * 64 + ((ks * 4 + lk) ^ (lr & 7)) * 8];
      }
      #pragma unroll
      for (int mi = 0; mi < 4; ++mi)
        #pragma unroll
        for (int ni = 0; ni < 4; ++ni)
          acc[mi][ni] = __builtin_amdgcn_mfma_f32_16x16x32_bf16(av[mi], bv[ni], acc[mi][ni], 0, 0, 0);
    }
  }

  // store this slice's bf16 partial
  short* outp = P + pstride * sk;
  #pragma unroll
  for (int mi = 0; mi < 4; ++mi)
    #pragma unroll
    for (int r = 0; r < 4; ++r) {
      const int m = m0 + wr * 64 + mi * 16 + lk * 4 + r;
      #pragma unroll
      for (int ni = 0; ni < 4; ++ni) {
        const int n = n0 + wc * 64 + ni * 16 + lr;
        outp[(size_t)m * 256 + n] = f2bf(acc[mi][ni][r]);
      }
    }

  // fused reduction: last-arriving z-block for this tile sums all 8 partials
  __threadfence();                           // release partial stores (agent scope)
  __syncthreads();
  if (t == 0)
    lastf = (atomicAdd(&cnt[by * gx + bx], 1u) == gridDim.z - 1) ? 1 : 0;
  __syncthreads();
  if (!lastf) return;
  __threadfence();                           // acquire other slices' stores

  #pragma unroll 2
  for (int i = 0; i < 16; ++i) {
    const int q = i * 256 + t;               // 4096 quads in the 128x128 tile
    const int m = m0 + (q >> 5);
    const int n = n0 + (q & 31) * 4;
    const size_t base = (size_t)m * 256 + n;
    float a0 = 0.f, a1 = 0.f, a2 = 0.f, a3 = 0.f;
    for (int s = 0; s < 8; ++s) {
      s16x4 v = *(const s16x4*)&P[pstride * s + base];
      a0 += bf2f(v.x); a1 += bf2f(v.y); a2 += bf2f(v.z); a3 += bf2f(v.w);
    }
    const float cs = colsum[m];
    const float rc = 1.f / (cs + EPS_A);
    const float rcw = rc / (cs * rc + EPS_A);
    const bool he = __uint_as_float(colmax[m]) * rc > THR_A;
    s16x4 o;
    if (FB == 0) {
      if (he) {
        o.x = f2bf(a0 * rcw); o.y = f2bf(a1 * rcw);
        o.z = f2bf(a2 * rcw); o.w = f2bf(a3 * rcw);
      } else {
        o = *(const s16x4*)&fb[(size_t)m * ldfb + n];
      }
    } else {
      a0 *= rcw; a1 *= rcw; a2 *= rcw; a3 *= rcw;
      if (__ballot(!he)) {
        if (!he) {
          a0 = bf2f(fb[(size_t)(n + 0) * NN + m]);
          a1 = bf2f(fb[(size_t)(n + 1) * NN + m]);
          a2 = bf2f(fb[(size_t)(n + 2) * NN + m]);
          a3 = bf2f(fb[(size_t)(n + 3) * NN + m]);
        }
      }
      o.x = f2bf(a0); o.y = f2bf(a1); o.z = f2bf(a2); o.w = f2bf(a3);
    }
    *(s16x4*)&out[(size_t)m * ldo + n] = o;
  }
}

// ---- row LayerNorm + ReLU, fp32 in.  MODE 0: bf16 out (ld-strided), MODE 1: fp32 out
template <int MODE>
__device__ __forceinline__ void ln_relu_body(
    const float* __restrict__ X, int W,
    const float* __restrict__ g, const float* __restrict__ be,
    void* __restrict__ out, int ldo)
{
  const int row = blockIdx.x;
  const int t = threadIdx.x;
  const float* x = X + (size_t)row * W;
  float v0 = x[t], v1 = 0.f;
  float s = v0, ss = v0 * v0;
  if (W == 512) { v1 = x[t + 256]; s += v1; ss += v1 * v1; }
  #pragma unroll
  for (int off = 32; off; off >>= 1) {
    s += __shfl_down(s, off);
    ss += __shfl_down(ss, off);
  }
  __shared__ float red[8];
  const int wid = t >> 6;
  if ((t & 63) == 0) { red[wid] = s; red[4 + wid] = ss; }
  __syncthreads();
  s = red[0] + red[1] + red[2] + red[3];
  ss = red[4] + red[5] + red[6] + red[7];
  const float mu = s / W;
  const float var = ss / W - mu * mu;
  const float sc = rsqrtf(var + 1e-5f);
  float y = fmaxf((v0 - mu) * sc * g[t] + be[t], 0.f);
  if (MODE == 0) ((short*)out)[(size_t)row * ldo + t] = f2bf(y);
  else           ((float*)out)[(size_t)row * ldo + t] = y;
  if (W == 512) {
    float y1 = fmaxf((v1 - mu) * sc * g[t + 256] + be[t + 256], 0.f);
    if (MODE == 0) ((short*)out)[(size_t)row * ldo + t + 256] = f2bf(y1);
    else           ((float*)out)[(size_t)row * ldo + t + 256] = y1;
  }
}

__global__ __launch_bounds__(256) void k_ln_relu_bf16(
    const float* __restrict__ X, int W, const float* __restrict__ g,
    const float* __restrict__ be, short* __restrict__ out, int ldo) {
  ln_relu_body<0>(X, W, g, be, out, ldo);
}
__global__ __launch_bounds__(256) void k_ln_relu_f32(
    const float* __restrict__ X, int W, const float* __restrict__ g,
    const float* __restrict__ be, float* __restrict__ out, int ldo) {
  ln_relu_body<1>(X, W, g, be, out, ldo);
}

extern "C" void kernel_launch(void* const* d_in, const int* in_sizes, int n_in,
                              void* d_out, int out_size, void* d_ws, size_t ws_size,
                              hipStream_t stream) {
  const float* nf      = (const float*)d_in[0];
  const float* Mob     = (const float*)d_in[1];
  const float* W_in1   = (const float*)d_in[2];
  const float* b_in1   = (const float*)d_in[3];
  const float* W_out1  = (const float*)d_in[4];
  const float* b_out1  = (const float*)d_in[5];
  const float* W_self1 = (const float*)d_in[6];
  const float* b_self1 = (const float*)d_in[7];
  const float* g1      = (const float*)d_in[8];
  const float* be1     = (const float*)d_in[9];
  const float* W_in2   = (const float*)d_in[10];
  const float* b_in2   = (const float*)d_in[11];
  const float* W_out2  = (const float*)d_in[12];
  const float* b_out2  = (const float*)d_in[13];
  const float* W_self2 = (const float*)d_in[14];
  const float* b_self2 = (const float*)d_in[15];
  const float* g2      = (const float*)d_in[16];
  const float* be2     = (const float*)d_in[17];

  char* ws = (char*)d_ws;
  float* colsum = (float*)(ws);                       // 32 KB
  u32*   colmax = (u32*)(ws + 32768);                 // 32 KB
  u32*   cnt1   = (u32*)(ws + 65536);                 // 128 u32
  u32*   cnt2   = (u32*)(ws + 66048);                 // 128 u32
  short* Mt     = (short*)(ws + 131072);              // [8192][8192] bf16
  short* nft    = (short*)(ws + 134348800);           // [256][8192]
  short* A1cat  = (short*)(ws + 138543104);           // [8192][512]: [A1|nf]
  float* C2f    = (float*)(ws + 146931712);           // [8192][512] f32
  short* Acat2  = (short*)(ws + 163708928);           // [8192][768]: [agg2|h1]
  short* T2t    = (short*)(ws + 176291840);           // [256][8192]
  short* Bcat1  = (short*)(ws + 180486144);           // [512][512]: [Wc1^T|Wself1^T]
  short* Bcat2  = (short*)(ws + 181010432);           // [256][768]
  short* Win2t  = (short*)(ws + 181403648);           // [256][512]
  short* Wout1t = (short*)(ws + 181665792);           // [512][512]
  short* Win1b  = (short*)(ws + 182190080);           // [256][512]
  float* bias1c = (float*)(ws + 182452224);           // [512]
  float* bias2c = (float*)(ws + 182454272);           // [256]
  short* P1     = (short*)(ws + 188743680);           // 8 x [8192][256] bf16
  short* P2     = (short*)(ws + 222298112);           // 8 x [8192][256] bf16

  hipMemsetAsync(ws, 0, 69632, stream);  // zero colsum + colmax + tile counters

  k_prep_all<<<9603, 256, 0, stream>>>(Mob, nf, W_in1, W_out1, W_self1, W_in2,
                                       W_out2, W_self2, b_in1, b_out1, b_self1,
                                       b_out2, b_self2, Mt, colsum, colmax, nft,
                                       A1cat, Win1b, Wout1t, Bcat1, Win2t, Bcat2,
                                       bias1c, bias2c);
  // Wc1^T = W_out1^T @ W_in1 : [512][256] into Bcat1 cols 0:256
  k_gemm_raw_n<<<dim3(4, 8), 256, 0, stream>>>(Wout1t, Win1b, 512, 512, 512,
                                               Bcat1, 512);

  // ---- layer 1 (reassociated): A1 = norm(Mt @ nft^T), fused reduce
  k_sk128_red<0><<<dim3(2, 64, 8), 256, 0, stream>>>(
      Mt, nft, 1024, NN, NN, P1, (size_t)8192 * 256, cnt1,
      colsum, colmax, A1cat + 256, 512, A1cat, 512);
  k_g64<128, 2><<<dim3(4, 128), 256, 0, stream>>>(A1cat, Bcat1, 512, 512, 512,
                                                  C2f, 512, bias1c);
  k_ln_relu_bf16<<<8192, 256, 0, stream>>>(C2f, 512, g1, be1, Acat2 + 256, 768);

  // ---- layer 2: T2t = W_in2^T@h1^T + b_in2; fused agg2; out2; LN
  k_g64<64, 0><<<dim3(128, 4), 256, 0, stream>>>(Win2t, Acat2 + 256, 512, 512, 768,
                                                 T2t, NN, b_in2);
  k_sk128_red<1><<<dim3(2, 64, 8), 256, 0, stream>>>(
      Mt, T2t, 1024, NN, NN, P2, (size_t)8192 * 256, cnt2,
      colsum, colmax, T2t, NN, Acat2, 768);
  k_g64<64, 2><<<dim3(4, 128), 256, 0, stream>>>(Acat2, Bcat2, 768, 768, 768,
                                                 C2f, 256, bias2c);
  k_ln_relu_f32<<<8192, 256, 0, stream>>>(C2f, 256, g2, be2, (float*)d_out, 256);
}

// Round 16
// 304.884 us; speedup vs baseline: 2.2080x; 2.2080x over previous
//
#include <hip/hip_runtime.h>
#include <stdint.h>

typedef short bf16x8 __attribute__((ext_vector_type(8)));
typedef short s16x4 __attribute__((ext_vector_type(4)));
typedef float f32x4 __attribute__((ext_vector_type(4)));
typedef unsigned int u32;

#define EPS_A 1e-8f
#define THR_A 1e-6f
#define NN 8192

static __device__ __forceinline__ short f2bf(float f) {
  u32 u = __float_as_uint(f);
  u = u + 0x7FFFu + ((u >> 16) & 1u);   // RNE, no NaN inputs here
  return (short)(u >> 16);
}
static __device__ __forceinline__ float bf2f(short s) {
  return __uint_as_float(((u32)(unsigned short)s) << 16);
}
// async global->LDS, 16B per lane; DIRECT addrspacecasts (proven round 12)
static __device__ __forceinline__ void gld16(const short* g, short* l) {
  __builtin_amdgcn_global_load_lds(
      (const __attribute__((address_space(1))) u32*)g,
      (__attribute__((address_space(3))) u32*)l, 16, 0, 0);
}

// ---- fused prep: Mt transpose-cast + colsum/colmax, all weight/feature casts,
//      bias folds — ONE launch, 9603 blocks
__global__ __launch_bounds__(256) void k_prep_all(
    const float* __restrict__ Mob, const float* __restrict__ nf,
    const float* __restrict__ W_in1, const float* __restrict__ W_out1,
    const float* __restrict__ W_self1, const float* __restrict__ W_in2,
    const float* __restrict__ W_out2, const float* __restrict__ W_self2,
    const float* __restrict__ b_in1, const float* __restrict__ b_out1,
    const float* __restrict__ b_self1, const float* __restrict__ b_out2,
    const float* __restrict__ b_self2,
    short* __restrict__ Mt, float* __restrict__ colsum, u32* __restrict__ colmax,
    short* __restrict__ nft, short* __restrict__ A1cat, short* __restrict__ Win1b,
    short* __restrict__ Wout1t, short* __restrict__ Bcat1, short* __restrict__ Win2t,
    short* __restrict__ Bcat2, float* __restrict__ bias1c, float* __restrict__ bias2c)
{
  __shared__ __align__(16) short sbuf[256 * 66];
  int b = blockIdx.x;
  const int t = threadIdx.x;
  if (b < 4096) {                      // Mt: transpose-cast + colsum/colmax
    const int i0 = (b & 31) * 256;
    const int j0 = (b >> 5) * 64;
    const int i = i0 + t;
    float s = 0.f, mx = 0.f;
    #pragma unroll 4
    for (int jj = 0; jj < 64; ++jj) {
      float v = Mob[(size_t)(j0 + jj) * NN + i];   // coalesced: t -> i
      s += v;
      mx = fmaxf(mx, v);
      sbuf[t * 66 + jj] = f2bf(v);
    }
    atomicAdd(&colsum[i], s);
    atomicMax(&colmax[i], __float_as_uint(mx));
    __syncthreads();
    #pragma unroll
    for (int p = 0; p < 8; ++p) {
      const int r = p * 32 + (t >> 3);
      const int c = t & 7;
      const u32* src = (const u32*)((const char*)sbuf + r * 132 + c * 16);
      int4 w = make_int4(src[0], src[1], src[2], src[3]);
      *(int4*)((char*)Mt + (((size_t)(i0 + r) * NN + j0) * 2 + c * 16)) = w;
    }
    return;
  }
  b -= 4096;
  if (b < 512) {                       // nf^T: LDS-tiled transpose-cast 8192x256
    short (*tile)[65] = (short(*)[65])sbuf;
    const int r0 = (b & 127) * 64, c0 = (b >> 7) * 64;
    #pragma unroll
    for (int p = 0; p < 16; ++p) {
      const int rr = p * 4 + (t >> 6), cc = t & 63;
      tile[rr][cc] = f2bf(nf[(size_t)(r0 + rr) * 256 + c0 + cc]);
    }
    __syncthreads();
    #pragma unroll
    for (int q = 0; q < 16; ++q) {
      const int cc = q * 4 + (t >> 6), rr = t & 63;
      nft[(size_t)(c0 + cc) * 8192 + r0 + rr] = tile[rr][cc];
    }
    return;
  }
  b -= 512;
  if (b < 2048) {                      // nf -> A1cat cols 256:512
    const int idx = b * 256 + t;
    const float4 v = ((const float4*)nf)[idx];
    const int i = idx >> 6;
    const int c = (idx & 63) * 4;
    s16x4 o;
    o.x = f2bf(v.x); o.y = f2bf(v.y); o.z = f2bf(v.z); o.w = f2bf(v.w);
    *(s16x4*)&A1cat[(size_t)i * 512 + 256 + c] = o;
    return;
  }
  b -= 2048;
  if (b < 128) {                       // W_in1 straight cast 256x512
    const int idx = b * 256 + t;
    const float4 v = ((const float4*)W_in1)[idx];
    s16x4 o;
    o.x = f2bf(v.x); o.y = f2bf(v.y); o.z = f2bf(v.z); o.w = f2bf(v.w);
    *(s16x4*)&Win1b[idx * 4] = o;
    return;
  }
  b -= 128;
  if (b < 1024) {                      // W_out1^T 512x512 -> Wout1t ld 512
    const int idx = b * 256 + t;
    const int r = idx >> 9, c = idx & 511;
    Wout1t[(size_t)c * 512 + r] = f2bf(W_out1[idx]);
    return;
  }
  b -= 1024;
  if (b < 512) {                       // W_self1^T 256x512 -> Bcat1+256 ld 512
    const int idx = b * 256 + t;
    const int r = idx >> 9, c = idx & 511;
    Bcat1[(size_t)c * 512 + 256 + r] = f2bf(W_self1[idx]);
    return;
  }
  b -= 512;
  if (b < 512) {                       // W_in2^T 512x256 -> Win2t ld 512
    const int idx = b * 256 + t;
    const int r = idx >> 8, c = idx & 255;
    Win2t[(size_t)c * 512 + r] = f2bf(W_in2[idx]);
    return;
  }
  b -= 512;
  if (b < 256) {                       // W_out2^T 256x256 -> Bcat2 ld 768
    const int idx = b * 256 + t;
    const int r = idx >> 8, c = idx & 255;
    Bcat2[(size_t)c * 768 + r] = f2bf(W_out2[idx]);
    return;
  }
  b -= 256;
  if (b < 512) {                       // W_self2^T 512x256 -> Bcat2+256 ld 768
    const int idx = b * 256 + t;
    const int r = idx >> 8, c = idx & 255;
    Bcat2[(size_t)c * 768 + 256 + r] = f2bf(W_self2[idx]);
    return;
  }
  b -= 512;
  if (b < 2) {                         // bias1c = b_in1@W_out1 + b_out1 + b_self1
    const int n = b * 256 + t;
    float a = b_out1[n] + b_self1[n];
    for (int p = 0; p < 512; ++p) a += b_in1[p] * W_out1[(size_t)p * 512 + n];
    bias1c[n] = a;
    return;
  }
  bias2c[t] = b_out2[t] + b_self2[t];  // last block
}

// ---- old 64x64 reg-staged body (kept ONLY for tiny Wc1 GEMM; proven)
__global__ __launch_bounds__(256) void k_gemm_raw_n(
    const short* __restrict__ A, const short* __restrict__ B, int K, int ldA, int ldB,
    short* __restrict__ C, int ldC)
{
  constexpr int LDP = 40;
  __shared__ __align__(16) short As[64 * LDP];
  __shared__ __align__(16) short Bs[64 * LDP];
  const int t = threadIdx.x;
  const int m0 = blockIdx.y * 64, n0 = blockIdx.x * 64;
  const int wid = t >> 6, l = t & 63;
  const int wr = wid >> 1, wc = wid & 1;
  const int lr = l & 15, lk = l >> 4;
  f32x4 acc[2][2] = {};
  const int sr = t >> 2;
  const int sc = (t & 3) * 8;
  const short* gA0 = A + (size_t)(m0 + sr) * ldA + sc;
  const short* gB0 = B + (size_t)(n0 + sr) * ldB + sc;
  for (int k0 = 0; k0 < K; k0 += 32) {
    const int4 a0 = *(const int4*)(gA0 + k0);
    const int4 b0 = *(const int4*)(gB0 + k0);
    __syncthreads();
    *(int4*)&As[sr * LDP + sc] = a0;
    *(int4*)&Bs[sr * LDP + sc] = b0;
    __syncthreads();
    bf16x8 av[2], bv[2];
    #pragma unroll
    for (int mi = 0; mi < 2; ++mi)
      av[mi] = *(const bf16x8*)&As[(wr * 32 + mi * 16 + lr) * LDP + lk * 8];
    #pragma unroll
    for (int ni = 0; ni < 2; ++ni)
      bv[ni] = *(const bf16x8*)&Bs[(wc * 32 + ni * 16 + lr) * LDP + lk * 8];
    #pragma unroll
    for (int mi = 0; mi < 2; ++mi)
      #pragma unroll
      for (int ni = 0; ni < 2; ++ni)
        acc[mi][ni] = __builtin_amdgcn_mfma_f32_16x16x32_bf16(av[mi], bv[ni], acc[mi][ni], 0, 0, 0);
  }
  #pragma unroll
  for (int mi = 0; mi < 2; ++mi)
    #pragma unroll
    for (int r = 0; r < 4; ++r) {
      const int m = m0 + wr * 32 + mi * 16 + lk * 4 + r;
      #pragma unroll
      for (int ni = 0; ni < 2; ++ni) {
        const int n = n0 + wc * 32 + ni * 16 + lr;
        C[(size_t)m * ldC + n] = f2bf(acc[mi][ni][r]);
      }
    }
}

// ---- 64 x BN GEMM, BK=64, gld_lds staging, swizzled unified LDS (A rows 0..63,
// B rows 64..64+BN), 8-row chunks per wave, staggered K.  EPI 0: +bias0[m] bf16;
// EPI 2: +bias0[n] fp32.
template <int BN, int EPI>
__global__ __launch_bounds__(256) void k_g64(
    const short* __restrict__ A, const short* __restrict__ B, int K, int ldA, int ldB,
    void* __restrict__ Cout, int ldC, const float* __restrict__ bias0)
{
  constexpr int ROWS = 64 + BN;
  constexpr int CH = ROWS / 32;             // chunks per wave (8 rows each)
  constexpr int NI = BN / 32;
  __shared__ __align__(16) short S[ROWS * 64];
  const int t = threadIdx.x;

  const int gx = gridDim.x;
  int flat = blockIdx.y * gx + blockIdx.x;
  const int cpx = (gx * gridDim.y) >> 3;
  flat = (flat & 7) * cpx + (flat >> 3);
  const int bx = flat % gx, by = flat / gx;
  const int m0 = by * 64, n0 = bx * BN;

  const int wid = t >> 6, l = t & 63;
  const int wr = wid >> 1, wc = wid & 1;
  const int lr = l & 15, lk = l >> 4;

  f32x4 acc[2][NI] = {};

  const int lrow = l >> 3, lcol = l & 7;
  const int wbase = wid * (ROWS / 4);
  short* dbase = S + wbase * 64;            // wave-uniform LDS base
  const short* gsrc[CH];
  #pragma unroll
  for (int c = 0; c < CH; ++c) {
    const int ar = wbase + c * 8 + lrow;    // chunk wholly A or wholly B (8-aligned)
    const int scol = (lcol ^ (ar & 7)) * 8;
    gsrc[c] = (ar < 64) ? A + (size_t)(m0 + ar) * ldA + scol
                        : B + (size_t)(n0 + ar - 64) * ldB + scol;
  }

  const int niters = K >> 6;                // 8 or 12
  int kk = flat % niters;                   // staggered start
  for (int it = 0; it < niters; ++it) {
    const int koff = kk << 6;
    kk = (kk + 1 == niters) ? 0 : kk + 1;
    __syncthreads();
    #pragma unroll
    for (int c = 0; c < CH; ++c)
      gld16(gsrc[c] + koff, dbase + c * 512);
    __syncthreads();

    #pragma unroll
    for (int ks = 0; ks < 2; ++ks) {
      bf16x8 av[2], bv[NI];
      #pragma unroll
      for (int mi = 0; mi < 2; ++mi) {
        const int row = wr * 32 + mi * 16 + lr;
        av[mi] = *(const bf16x8*)&S[row * 64 + ((ks * 4 + lk) ^ (row & 7)) * 8];
      }
      #pragma unroll
      for (int ni = 0; ni < NI; ++ni) {
        const int row = 64 + wc * (BN / 2) + ni * 16 + lr;
        bv[ni] = *(const bf16x8*)&S[row * 64 + ((ks * 4 + lk) ^ (row & 7)) * 8];
      }
      #pragma unroll
      for (int mi = 0; mi < 2; ++mi)
        #pragma unroll
        for (int ni = 0; ni < NI; ++ni)
          acc[mi][ni] = __builtin_amdgcn_mfma_f32_16x16x32_bf16(av[mi], bv[ni], acc[mi][ni], 0, 0, 0);
    }
  }

  #pragma unroll
  for (int mi = 0; mi < 2; ++mi) {
    #pragma unroll
    for (int r = 0; r < 4; ++r) {
      const int m = m0 + wr * 32 + mi * 16 + lk * 4 + r;
      float bm = 0.f;
      if (EPI == 0) bm = bias0[m];
      #pragma unroll
      for (int ni = 0; ni < NI; ++ni) {
        const int n = n0 + wc * (BN / 2) + ni * 16 + lr;
        float v = acc[mi][ni][r];
        if (EPI == 0) ((short*)Cout)[(size_t)m * ldC + n] = f2bf(v + bm);
        else          ((float*)Cout)[(size_t)m * ldC + n] = v + bias0[n];
      }
    }
  }
}

// ---- 128x128 split-K GEMM, BK=64, gld_lds staging, staggered circular K-loop
// (round-13 proven; NO fences, NO atomics — cross-z reduce is a separate kernel)
__global__ __launch_bounds__(256) void k_gemm_sk128(
    const short* __restrict__ A, const short* __restrict__ B, int K, int ldA, int ldB,
    short* __restrict__ P, int ldC, size_t pstride)
{
  __shared__ __align__(16) short As[128 * 64];   // 16 KB each
  __shared__ __align__(16) short Bs[128 * 64];
  const int t = threadIdx.x;

  const int sk = blockIdx.z;
  A += (size_t)sk * K;
  B += (size_t)sk * K;

  const int gx = gridDim.x;
  int flat = blockIdx.y * gx + blockIdx.x;
  const int cpx = (gx * gridDim.y) >> 3;
  flat = (flat & 7) * cpx + (flat >> 3);
  const int bx = flat % gx, by = flat / gx;
  const int m0 = by * 128, n0 = bx * 128;

  const int wid = t >> 6, l = t & 63;
  const int wr = wid >> 1, wc = wid & 1;
  const int lr = l & 15, lk = l >> 4;

  f32x4 acc[4][4] = {};

  const int side = wid >> 1;
  const int hrow = (wid & 1) * 64;             // wave-uniform row base
  const short* Xp = side ? B : A;
  const int ldX = side ? ldB : ldA;
  const int x0 = side ? n0 : m0;
  short* dbase = (side ? Bs : As) + hrow * 64; // wave-uniform LDS base
  const int lrow = l >> 3, lcol = l & 7;
  const short* g0 = Xp + (size_t)(x0 + hrow + lrow) * ldX + (lcol ^ lrow) * 8;
  const size_t st8 = (size_t)8 * ldX;          // +8 rows per chunk

  const int niters = K >> 6;                   // 16 for K=1024
  int kk = (flat + sk * 3) & (niters - 1);     // staggered start de-correlates drains

  for (int it = 0; it < niters; ++it) {
    const int koff = kk << 6;
    kk = (kk + 1) & (niters - 1);
    __syncthreads();                           // previous iteration's reads done
    gld16(g0 + koff,            dbase);
    gld16(g0 + koff + st8,      dbase + 512);
    gld16(g0 + koff + 2 * st8,  dbase + 1024);
    gld16(g0 + koff + 3 * st8,  dbase + 1536);
    gld16(g0 + koff + 4 * st8,  dbase + 2048);
    gld16(g0 + koff + 5 * st8,  dbase + 2560);
    gld16(g0 + koff + 6 * st8,  dbase + 3072);
    gld16(g0 + koff + 7 * st8,  dbase + 3584);
    __syncthreads();                           // compiler drains vmcnt before barrier

    #pragma unroll
    for (int ks = 0; ks < 2; ++ks) {
      bf16x8 av[4], bv[4];
      #pragma unroll
      for (int mi = 0; mi < 4; ++mi) {
        const int row = wr * 64 + mi * 16 + lr;
        av[mi] = *(const bf16x8*)&As[row * 64 + ((ks * 4 + lk) ^ (lr & 7)) * 8];
      }
      #pragma unroll
      for (int ni = 0; ni < 4; ++ni) {
        const int row = wc * 64 + ni * 16 + lr;
        bv[ni] = *(const bf16x8*)&Bs[row * 64 + ((ks * 4 + lk) ^ (lr & 7)) * 8];
      }
      #pragma unroll
      for (int mi = 0; mi < 4; ++mi)
        #pragma unroll
        for (int ni = 0; ni < 4; ++ni)
          acc[mi][ni] = __builtin_amdgcn_mfma_f32_16x16x32_bf16(av[mi], bv[ni], acc[mi][ni], 0, 0, 0);
    }
  }

  short* outp = P + pstride * sk;
  #pragma unroll
  for (int mi = 0; mi < 4; ++mi) {
    #pragma unroll
    for (int r = 0; r < 4; ++r) {
      const int m = m0 + wr * 64 + mi * 16 + lk * 4 + r;
      #pragma unroll
      for (int ni = 0; ni < 4; ++ni) {
        const int n = n0 + wc * 64 + ni * 16 + lr;
        outp[(size_t)m * ldC + n] = f2bf(acc[mi][ni][r]);
      }
    }
  }
}

// ---- reduce S partials + normalize; fallback substitutes raw h row (coalesced)
__global__ __launch_bounds__(256) void k_sk_reduce_sub(
    const short* __restrict__ P, int N, size_t pstride, int S,
    const float* __restrict__ colsum, const u32* __restrict__ colmax,
    const short* __restrict__ hraw, int ldh,
    short* __restrict__ out, int ldo)
{
  const int idx = blockIdx.x * 256 + threadIdx.x;
  const int nq = N >> 2;
  const int m = idx / nq;
  const int c4 = (idx - m * nq) * 4;
  const size_t base = (size_t)m * N + c4;
  float a0 = 0.f, a1 = 0.f, a2 = 0.f, a3 = 0.f;
  for (int s = 0; s < S; ++s) {
    s16x4 v = *(const s16x4*)&P[pstride * s + base];
    a0 += bf2f(v.x); a1 += bf2f(v.y); a2 += bf2f(v.z); a3 += bf2f(v.w);
  }
  const float cs = colsum[m];
  const float rc = 1.f / (cs + EPS_A);
  const float rcw = rc / (cs * rc + EPS_A);
  const bool he = __uint_as_float(colmax[m]) * rc > THR_A;
  s16x4 o;
  if (he) {
    o.x = f2bf(a0 * rcw); o.y = f2bf(a1 * rcw);
    o.z = f2bf(a2 * rcw); o.w = f2bf(a3 * rcw);
  } else {
    o = *(const s16x4*)&hraw[(size_t)m * ldh + c4];
  }
  *(s16x4*)&out[(size_t)m * ldo + c4] = o;
}

// ---- reduce S partials + normalize; fallback gathers T^T (rare, ballot-skipped)
__global__ __launch_bounds__(256) void k_sk_reduce(
    const short* __restrict__ P, int N, size_t pstride, int S,
    const float* __restrict__ colsum, const u32* __restrict__ colmax,
    const short* __restrict__ Tfall, short* __restrict__ out, int ldo)
{
  const int idx = blockIdx.x * 256 + threadIdx.x;
  const int nq = N >> 2;
  const int m = idx / nq;
  const int c4 = (idx - m * nq) * 4;
  const size_t base = (size_t)m * N + c4;
  float a0 = 0.f, a1 = 0.f, a2 = 0.f, a3 = 0.f;
  for (int s = 0; s < S; ++s) {
    s16x4 v = *(const s16x4*)&P[pstride * s + base];
    a0 += bf2f(v.x); a1 += bf2f(v.y); a2 += bf2f(v.z); a3 += bf2f(v.w);
  }
  const float cs = colsum[m];
  const float rc = 1.f / (cs + EPS_A);
  const float rcw = rc / (cs * rc + EPS_A);
  const bool he = __uint_as_float(colmax[m]) * rc > THR_A;
  a0 *= rcw; a1 *= rcw; a2 *= rcw; a3 *= rcw;
  if (__ballot(!he)) {
    if (!he) {
      a0 = bf2f(Tfall[(size_t)(c4 + 0) * NN + m]);
      a1 = bf2f(Tfall[(size_t)(c4 + 1) * NN + m]);
      a2 = bf2f(Tfall[(size_t)(c4 + 2) * NN + m]);
      a3 = bf2f(Tfall[(size_t)(c4 + 3) * NN + m]);
    }
  }
  s16x4 o;
  o.x = f2bf(a0); o.y = f2bf(a1); o.z = f2bf(a2); o.w = f2bf(a3);
  *(s16x4*)&out[(size_t)m * ldo + c4] = o;
}

// ---- row LayerNorm + ReLU, fp32 in.  MODE 0: bf16 out (ld-strided), MODE 1: fp32 out
template <int MODE>
__device__ __forceinline__ void ln_relu_body(
    const float* __restrict__ X, int W,
    const float* __restrict__ g, const float* __restrict__ be,
    void* __restrict__ out, int ldo)
{
  const int row = blockIdx.x;
  const int t = threadIdx.x;
  const float* x = X + (size_t)row * W;
  float v0 = x[t], v1 = 0.f;
  float s = v0, ss = v0 * v0;
  if (W == 512) { v1 = x[t + 256]; s += v1; ss += v1 * v1; }
  #pragma unroll
  for (int off = 32; off; off >>= 1) {
    s += __shfl_down(s, off);
    ss += __shfl_down(ss, off);
  }
  __shared__ float red[8];
  const int wid = t >> 6;
  if ((t & 63) == 0) { red[wid] = s; red[4 + wid] = ss; }
  __syncthreads();
  s = red[0] + red[1] + red[2] + red[3];
  ss = red[4] + red[5] + red[6] + red[7];
  const float mu = s / W;
  const float var = ss / W - mu * mu;
  const float sc = rsqrtf(var + 1e-5f);
  float y = fmaxf((v0 - mu) * sc * g[t] + be[t], 0.f);
  if (MODE == 0) ((short*)out)[(size_t)row * ldo + t] = f2bf(y);
  else           ((float*)out)[(size_t)row * ldo + t] = y;
  if (W == 512) {
    float y1 = fmaxf((v1 - mu) * sc * g[t + 256] + be[t + 256], 0.f);
    if (MODE == 0) ((short*)out)[(size_t)row * ldo + t + 256] = f2bf(y1);
    else           ((float*)out)[(size_t)row * ldo + t + 256] = y1;
  }
}

__global__ __launch_bounds__(256) void k_ln_relu_bf16(
    const float* __restrict__ X, int W, const float* __restrict__ g,
    const float* __restrict__ be, short* __restrict__ out, int ldo) {
  ln_relu_body<0>(X, W, g, be, out, ldo);
}
__global__ __launch_bounds__(256) void k_ln_relu_f32(
    const float* __restrict__ X, int W, const float* __restrict__ g,
    const float* __restrict__ be, float* __restrict__ out, int ldo) {
  ln_relu_body<1>(X, W, g, be, out, ldo);
}

extern "C" void kernel_launch(void* const* d_in, const int* in_sizes, int n_in,
                              void* d_out, int out_size, void* d_ws, size_t ws_size,
                              hipStream_t stream) {
  const float* nf      = (const float*)d_in[0];
  const float* Mob     = (const float*)d_in[1];
  const float* W_in1   = (const float*)d_in[2];
  const float* b_in1   = (const float*)d_in[3];
  const float* W_out1  = (const float*)d_in[4];
  const float* b_out1  = (const float*)d_in[5];
  const float* W_self1 = (const float*)d_in[6];
  const float* b_self1 = (const float*)d_in[7];
  const float* g1      = (const float*)d_in[8];
  const float* be1     = (const float*)d_in[9];
  const float* W_in2   = (const float*)d_in[10];
  const float* b_in2   = (const float*)d_in[11];
  const float* W_out2  = (const float*)d_in[12];
  const float* b_out2  = (const float*)d_in[13];
  const float* W_self2 = (const float*)d_in[14];
  const float* b_self2 = (const float*)d_in[15];
  const float* g2      = (const float*)d_in[16];
  const float* be2     = (const float*)d_in[17];

  char* ws = (char*)d_ws;
  float* colsum = (float*)(ws);                       // 32 KB
  u32*   colmax = (u32*)(ws + 32768);                 // 32 KB
  short* Mt     = (short*)(ws + 131072);              // [8192][8192] bf16
  short* nft    = (short*)(ws + 134348800);           // [256][8192]
  short* A1cat  = (short*)(ws + 138543104);           // [8192][512]: [A1|nf]
  float* C2f    = (float*)(ws + 146931712);           // [8192][512] f32
  short* Acat2  = (short*)(ws + 163708928);           // [8192][768]: [agg2|h1]
  short* T2t    = (short*)(ws + 176291840);           // [256][8192]
  short* Bcat1  = (short*)(ws + 180486144);           // [512][512]: [Wc1^T|Wself1^T]
  short* Bcat2  = (short*)(ws + 181010432);           // [256][768]
  short* Win2t  = (short*)(ws + 181403648);           // [256][512]
  short* Wout1t = (short*)(ws + 181665792);           // [512][512]
  short* Win1b  = (short*)(ws + 182190080);           // [256][512]
  float* bias1c = (float*)(ws + 182452224);           // [512]
  float* bias2c = (float*)(ws + 182454272);           // [256]
  short* P1     = (short*)(ws + 188743680);           // 8 x [8192][256] bf16
  short* P2     = (short*)(ws + 222298112);           // 8 x [8192][256] bf16

  hipMemsetAsync(ws, 0, 65536, stream);  // zero colsum + colmax every call

  k_prep_all<<<9603, 256, 0, stream>>>(Mob, nf, W_in1, W_out1, W_self1, W_in2,
                                       W_out2, W_self2, b_in1, b_out1, b_self1,
                                       b_out2, b_self2, Mt, colsum, colmax, nft,
                                       A1cat, Win1b, Wout1t, Bcat1, Win2t, Bcat2,
                                       bias1c, bias2c);
  // Wc1^T = W_out1^T @ W_in1 : [512][256] into Bcat1 cols 0:256
  k_gemm_raw_n<<<dim3(4, 8), 256, 0, stream>>>(Wout1t, Win1b, 512, 512, 512,
                                               Bcat1, 512);

  // ---- layer 1 (reassociated): G1 = Mt @ nft^T  (M=8192,N=256,K=8192, z=8)
  k_gemm_sk128<<<dim3(2, 64, 8), 256, 0, stream>>>(Mt, nft, 1024, NN, NN,
                                                   P1, 256, (size_t)8192 * 256);
  k_sk_reduce_sub<<<2048, 256, 0, stream>>>(P1, 256, (size_t)8192 * 256, 8,
                                            colsum, colmax, A1cat + 256, 512,
                                            A1cat, 512);
  k_g64<128, 2><<<dim3(4, 128), 256, 0, stream>>>(A1cat, Bcat1, 512, 512, 512,
                                                  C2f, 512, bias1c);
  k_ln_relu_bf16<<<8192, 256, 0, stream>>>(C2f, 512, g1, be1, Acat2 + 256, 768);

  // ---- layer 2: T2t = W_in2^T@h1^T + b_in2; agg2; out2; LN
  k_g64<64, 0><<<dim3(128, 4), 256, 0, stream>>>(Win2t, Acat2 + 256, 512, 512, 768,
                                                 T2t, NN, b_in2);
  k_gemm_sk128<<<dim3(2, 64, 8), 256, 0, stream>>>(Mt, T2t, 1024, NN, NN,
                                                   P2, 256, (size_t)8192 * 256);
  k_sk_reduce<<<2048, 256, 0, stream>>>(P2, 256, (size_t)8192 * 256, 8,
                                        colsum, colmax, T2t, Acat2, 768);
  k_g64<64, 2><<<dim3(4, 128), 256, 0, stream>>>(Acat2, Bcat2, 768, 768, 768,
                                                 C2f, 256, bias2c);
  k_ln_relu_f32<<<8192, 256, 0, stream>>>(C2f, 256, g2, be2, (float*)d_out, 256);
}

// Round 17
// 298.304 us; speedup vs baseline: 2.2567x; 1.0221x over previous
//
#include <hip/hip_runtime.h>
#include <stdint.h>

typedef short bf16x8 __attribute__((ext_vector_type(8)));
typedef short s16x4 __attribute__((ext_vector_type(4)));
typedef float f32x4 __attribute__((ext_vector_type(4)));
typedef unsigned int u32;

#define EPS_A 1e-8f
#define THR_A 1e-6f
#define NN 8192

static __device__ __forceinline__ short f2bf(float f) {
  u32 u = __float_as_uint(f);
  u = u + 0x7FFFu + ((u >> 16) & 1u);   // RNE, no NaN inputs here
  return (short)(u >> 16);
}
static __device__ __forceinline__ float bf2f(short s) {
  return __uint_as_float(((u32)(unsigned short)s) << 16);
}
// async global->LDS, 16B per lane; DIRECT addrspacecasts (proven round 12)
static __device__ __forceinline__ void gld16(const short* g, short* l) {
  __builtin_amdgcn_global_load_lds(
      (const __attribute__((address_space(1))) u32*)g,
      (__attribute__((address_space(3))) u32*)l, 16, 0, 0);
}

// ---- fused prep: Mt transpose-cast + colsum/colmax, all weight/feature casts,
//      bias folds — ONE launch, 9603 blocks
__global__ __launch_bounds__(256) void k_prep_all(
    const float* __restrict__ Mob, const float* __restrict__ nf,
    const float* __restrict__ W_in1, const float* __restrict__ W_out1,
    const float* __restrict__ W_self1, const float* __restrict__ W_in2,
    const float* __restrict__ W_out2, const float* __restrict__ W_self2,
    const float* __restrict__ b_in1, const float* __restrict__ b_out1,
    const float* __restrict__ b_self1, const float* __restrict__ b_out2,
    const float* __restrict__ b_self2,
    short* __restrict__ Mt, float* __restrict__ colsum, u32* __restrict__ colmax,
    short* __restrict__ nft, short* __restrict__ A1cat, short* __restrict__ Win1b,
    short* __restrict__ Wout1t, short* __restrict__ Bcat1, short* __restrict__ Win2t,
    short* __restrict__ Bcat2, float* __restrict__ bias1c, float* __restrict__ bias2c)
{
  __shared__ __align__(16) short sbuf[256 * 66];
  int b = blockIdx.x;
  const int t = threadIdx.x;
  if (b < 4096) {                      // Mt: transpose-cast + colsum/colmax
    const int i0 = (b & 31) * 256;
    const int j0 = (b >> 5) * 64;
    const int i = i0 + t;
    float s = 0.f, mx = 0.f;
    #pragma unroll 4
    for (int jj = 0; jj < 64; ++jj) {
      float v = Mob[(size_t)(j0 + jj) * NN + i];   // coalesced: t -> i
      s += v;
      mx = fmaxf(mx, v);
      sbuf[t * 66 + jj] = f2bf(v);
    }
    atomicAdd(&colsum[i], s);
    atomicMax(&colmax[i], __float_as_uint(mx));
    __syncthreads();
    #pragma unroll
    for (int p = 0; p < 8; ++p) {
      const int r = p * 32 + (t >> 3);
      const int c = t & 7;
      const u32* src = (const u32*)((const char*)sbuf + r * 132 + c * 16);
      int4 w = make_int4(src[0], src[1], src[2], src[3]);
      *(int4*)((char*)Mt + (((size_t)(i0 + r) * NN + j0) * 2 + c * 16)) = w;
    }
    return;
  }
  b -= 4096;
  if (b < 512) {                       // nf^T: LDS-tiled transpose-cast 8192x256
    short (*tile)[65] = (short(*)[65])sbuf;
    const int r0 = (b & 127) * 64, c0 = (b >> 7) * 64;
    #pragma unroll
    for (int p = 0; p < 16; ++p) {
      const int rr = p * 4 + (t >> 6), cc = t & 63;
      tile[rr][cc] = f2bf(nf[(size_t)(r0 + rr) * 256 + c0 + cc]);
    }
    __syncthreads();
    #pragma unroll
    for (int q = 0; q < 16; ++q) {
      const int cc = q * 4 + (t >> 6), rr = t & 63;
      nft[(size_t)(c0 + cc) * 8192 + r0 + rr] = tile[rr][cc];
    }
    return;
  }
  b -= 512;
  if (b < 2048) {                      // nf -> A1cat cols 256:512
    const int idx = b * 256 + t;
    const float4 v = ((const float4*)nf)[idx];
    const int i = idx >> 6;
    const int c = (idx & 63) * 4;
    s16x4 o;
    o.x = f2bf(v.x); o.y = f2bf(v.y); o.z = f2bf(v.z); o.w = f2bf(v.w);
    *(s16x4*)&A1cat[(size_t)i * 512 + 256 + c] = o;
    return;
  }
  b -= 2048;
  if (b < 128) {                       // W_in1 straight cast 256x512
    const int idx = b * 256 + t;
    const float4 v = ((const float4*)W_in1)[idx];
    s16x4 o;
    o.x = f2bf(v.x); o.y = f2bf(v.y); o.z = f2bf(v.z); o.w = f2bf(v.w);
    *(s16x4*)&Win1b[idx * 4] = o;
    return;
  }
  b -= 128;
  if (b < 1024) {                      // W_out1^T 512x512 -> Wout1t ld 512
    const int idx = b * 256 + t;
    const int r = idx >> 9, c = idx & 511;
    Wout1t[(size_t)c * 512 + r] = f2bf(W_out1[idx]);
    return;
  }
  b -= 1024;
  if (b < 512) {                       // W_self1^T 256x512 -> Bcat1+256 ld 512
    const int idx = b * 256 + t;
    const int r = idx >> 9, c = idx & 511;
    Bcat1[(size_t)c * 512 + 256 + r] = f2bf(W_self1[idx]);
    return;
  }
  b -= 512;
  if (b < 512) {                       // W_in2^T 512x256 -> Win2t ld 512
    const int idx = b * 256 + t;
    const int r = idx >> 8, c = idx & 255;
    Win2t[(size_t)c * 512 + r] = f2bf(W_in2[idx]);
    return;
  }
  b -= 512;
  if (b < 256) {                       // W_out2^T 256x256 -> Bcat2 ld 768
    const int idx = b * 256 + t;
    const int r = idx >> 8, c = idx & 255;
    Bcat2[(size_t)c * 768 + r] = f2bf(W_out2[idx]);
    return;
  }
  b -= 256;
  if (b < 512) {                       // W_self2^T 512x256 -> Bcat2+256 ld 768
    const int idx = b * 256 + t;
    const int r = idx >> 8, c = idx & 255;
    Bcat2[(size_t)c * 768 + 256 + r] = f2bf(W_self2[idx]);
    return;
  }
  b -= 512;
  if (b < 2) {                         // bias1c = b_in1@W_out1 + b_out1 + b_self1
    const int n = b * 256 + t;
    float a = b_out1[n] + b_self1[n];
    for (int p = 0; p < 512; ++p) a += b_in1[p] * W_out1[(size_t)p * 512 + n];
    bias1c[n] = a;
    return;
  }
  bias2c[t] = b_out2[t] + b_self2[t];  // last block
}

// ---- old 64x64 reg-staged body (kept ONLY for tiny Wc1 GEMM; proven)
__global__ __launch_bounds__(256) void k_gemm_raw_n(
    const short* __restrict__ A, const short* __restrict__ B, int K, int ldA, int ldB,
    short* __restrict__ C, int ldC)
{
  constexpr int LDP = 40;
  __shared__ __align__(16) short As[64 * LDP];
  __shared__ __align__(16) short Bs[64 * LDP];
  const int t = threadIdx.x;
  const int m0 = blockIdx.y * 64, n0 = blockIdx.x * 64;
  const int wid = t >> 6, l = t & 63;
  const int wr = wid >> 1, wc = wid & 1;
  const int lr = l & 15, lk = l >> 4;
  f32x4 acc[2][2] = {};
  const int sr = t >> 2;
  const int sc = (t & 3) * 8;
  const short* gA0 = A + (size_t)(m0 + sr) * ldA + sc;
  const short* gB0 = B + (size_t)(n0 + sr) * ldB + sc;
  for (int k0 = 0; k0 < K; k0 += 32) {
    const int4 a0 = *(const int4*)(gA0 + k0);
    const int4 b0 = *(const int4*)(gB0 + k0);
    __syncthreads();
    *(int4*)&As[sr * LDP + sc] = a0;
    *(int4*)&Bs[sr * LDP + sc] = b0;
    __syncthreads();
    bf16x8 av[2], bv[2];
    #pragma unroll
    for (int mi = 0; mi < 2; ++mi)
      av[mi] = *(const bf16x8*)&As[(wr * 32 + mi * 16 + lr) * LDP + lk * 8];
    #pragma unroll
    for (int ni = 0; ni < 2; ++ni)
      bv[ni] = *(const bf16x8*)&Bs[(wc * 32 + ni * 16 + lr) * LDP + lk * 8];
    #pragma unroll
    for (int mi = 0; mi < 2; ++mi)
      #pragma unroll
      for (int ni = 0; ni < 2; ++ni)
        acc[mi][ni] = __builtin_amdgcn_mfma_f32_16x16x32_bf16(av[mi], bv[ni], acc[mi][ni], 0, 0, 0);
  }
  #pragma unroll
  for (int mi = 0; mi < 2; ++mi)
    #pragma unroll
    for (int r = 0; r < 4; ++r) {
      const int m = m0 + wr * 32 + mi * 16 + lk * 4 + r;
      #pragma unroll
      for (int ni = 0; ni < 2; ++ni) {
        const int n = n0 + wc * 32 + ni * 16 + lr;
        C[(size_t)m * ldC + n] = f2bf(acc[mi][ni][r]);
      }
    }
}

// ---- 64 x BN GEMM, BK=64, gld_lds staging, swizzled unified LDS (A rows 0..63,
// B rows 64..64+BN), 8-row chunks per wave, staggered K.  EPI 0: +bias0[m] bf16;
// EPI 2: +bias0[n] fp32.  s_setprio wraps the compute phase (T5).
template <int BN, int EPI>
__global__ __launch_bounds__(256) void k_g64(
    const short* __restrict__ A, const short* __restrict__ B, int K, int ldA, int ldB,
    void* __restrict__ Cout, int ldC, const float* __restrict__ bias0)
{
  constexpr int ROWS = 64 + BN;
  constexpr int CH = ROWS / 32;             // chunks per wave (8 rows each)
  constexpr int NI = BN / 32;
  __shared__ __align__(16) short S[ROWS * 64];
  const int t = threadIdx.x;

  const int gx = gridDim.x;
  int flat = blockIdx.y * gx + blockIdx.x;
  const int cpx = (gx * gridDim.y) >> 3;
  flat = (flat & 7) * cpx + (flat >> 3);
  const int bx = flat % gx, by = flat / gx;
  const int m0 = by * 64, n0 = bx * BN;

  const int wid = t >> 6, l = t & 63;
  const int wr = wid >> 1, wc = wid & 1;
  const int lr = l & 15, lk = l >> 4;

  f32x4 acc[2][NI] = {};

  const int lrow = l >> 3, lcol = l & 7;
  const int wbase = wid * (ROWS / 4);
  short* dbase = S + wbase * 64;            // wave-uniform LDS base
  const short* gsrc[CH];
  #pragma unroll
  for (int c = 0; c < CH; ++c) {
    const int ar = wbase + c * 8 + lrow;    // chunk wholly A or wholly B (8-aligned)
    const int scol = (lcol ^ (ar & 7)) * 8;
    gsrc[c] = (ar < 64) ? A + (size_t)(m0 + ar) * ldA + scol
                        : B + (size_t)(n0 + ar - 64) * ldB + scol;
  }

  const int niters = K >> 6;                // 8 or 12
  int kk = flat % niters;                   // staggered start
  for (int it = 0; it < niters; ++it) {
    const int koff = kk << 6;
    kk = (kk + 1 == niters) ? 0 : kk + 1;
    __syncthreads();
    #pragma unroll
    for (int c = 0; c < CH; ++c)
      gld16(gsrc[c] + koff, dbase + c * 512);
    __syncthreads();

    __builtin_amdgcn_s_setprio(1);          // T5: favor compute-phase wave
    #pragma unroll
    for (int ks = 0; ks < 2; ++ks) {
      bf16x8 av[2], bv[NI];
      #pragma unroll
      for (int mi = 0; mi < 2; ++mi) {
        const int row = wr * 32 + mi * 16 + lr;
        av[mi] = *(const bf16x8*)&S[row * 64 + ((ks * 4 + lk) ^ (row & 7)) * 8];
      }
      #pragma unroll
      for (int ni = 0; ni < NI; ++ni) {
        const int row = 64 + wc * (BN / 2) + ni * 16 + lr;
        bv[ni] = *(const bf16x8*)&S[row * 64 + ((ks * 4 + lk) ^ (row & 7)) * 8];
      }
      #pragma unroll
      for (int mi = 0; mi < 2; ++mi)
        #pragma unroll
        for (int ni = 0; ni < NI; ++ni)
          acc[mi][ni] = __builtin_amdgcn_mfma_f32_16x16x32_bf16(av[mi], bv[ni], acc[mi][ni], 0, 0, 0);
    }
    __builtin_amdgcn_s_setprio(0);
  }

  #pragma unroll
  for (int mi = 0; mi < 2; ++mi) {
    #pragma unroll
    for (int r = 0; r < 4; ++r) {
      const int m = m0 + wr * 32 + mi * 16 + lk * 4 + r;
      float bm = 0.f;
      if (EPI == 0) bm = bias0[m];
      #pragma unroll
      for (int ni = 0; ni < NI; ++ni) {
        const int n = n0 + wc * (BN / 2) + ni * 16 + lr;
        float v = acc[mi][ni][r];
        if (EPI == 0) ((short*)Cout)[(size_t)m * ldC + n] = f2bf(v + bm);
        else          ((float*)Cout)[(size_t)m * ldC + n] = v + bias0[n];
      }
    }
  }
}

// ---- 128x128 split-K GEMM, BK=64, gld_lds staging, staggered circular K-loop
// (round-13 proven) + s_setprio around the compute phase (T5).
__global__ __launch_bounds__(256) void k_gemm_sk128(
    const short* __restrict__ A, const short* __restrict__ B, int K, int ldA, int ldB,
    short* __restrict__ P, int ldC, size_t pstride)
{
  __shared__ __align__(16) short As[128 * 64];   // 16 KB each
  __shared__ __align__(16) short Bs[128 * 64];
  const int t = threadIdx.x;

  const int sk = blockIdx.z;
  A += (size_t)sk * K;
  B += (size_t)sk * K;

  const int gx = gridDim.x;
  int flat = blockIdx.y * gx + blockIdx.x;
  const int cpx = (gx * gridDim.y) >> 3;
  flat = (flat & 7) * cpx + (flat >> 3);
  const int bx = flat % gx, by = flat / gx;
  const int m0 = by * 128, n0 = bx * 128;

  const int wid = t >> 6, l = t & 63;
  const int wr = wid >> 1, wc = wid & 1;
  const int lr = l & 15, lk = l >> 4;

  f32x4 acc[4][4] = {};

  const int side = wid >> 1;
  const int hrow = (wid & 1) * 64;             // wave-uniform row base
  const short* Xp = side ? B : A;
  const int ldX = side ? ldB : ldA;
  const int x0 = side ? n0 : m0;
  short* dbase = (side ? Bs : As) + hrow * 64; // wave-uniform LDS base
  const int lrow = l >> 3, lcol = l & 7;
  const short* g0 = Xp + (size_t)(x0 + hrow + lrow) * ldX + (lcol ^ lrow) * 8;
  const size_t st8 = (size_t)8 * ldX;          // +8 rows per chunk

  const int niters = K >> 6;                   // 16 for K=1024
  int kk = (flat + sk * 3) & (niters - 1);     // staggered start de-correlates drains

  for (int it = 0; it < niters; ++it) {
    const int koff = kk << 6;
    kk = (kk + 1) & (niters - 1);
    __syncthreads();                           // previous iteration's reads done
    gld16(g0 + koff,            dbase);
    gld16(g0 + koff + st8,      dbase + 512);
    gld16(g0 + koff + 2 * st8,  dbase + 1024);
    gld16(g0 + koff + 3 * st8,  dbase + 1536);
    gld16(g0 + koff + 4 * st8,  dbase + 2048);
    gld16(g0 + koff + 5 * st8,  dbase + 2560);
    gld16(g0 + koff + 6 * st8,  dbase + 3072);
    gld16(g0 + koff + 7 * st8,  dbase + 3584);
    __syncthreads();                           // compiler drains vmcnt before barrier

    __builtin_amdgcn_s_setprio(1);             // T5: favor compute-phase wave
    #pragma unroll
    for (int ks = 0; ks < 2; ++ks) {
      bf16x8 av[4], bv[4];
      #pragma unroll
      for (int mi = 0; mi < 4; ++mi) {
        const int row = wr * 64 + mi * 16 + lr;
        av[mi] = *(const bf16x8*)&As[row * 64 + ((ks * 4 + lk) ^ (lr & 7)) * 8];
      }
      #pragma unroll
      for (int ni = 0; ni < 4; ++ni) {
        const int row = wc * 64 + ni * 16 + lr;
        bv[ni] = *(const bf16x8*)&Bs[row * 64 + ((ks * 4 + lk) ^ (lr & 7)) * 8];
      }
      #pragma unroll
      for (int mi = 0; mi < 4; ++mi)
        #pragma unroll
        for (int ni = 0; ni < 4; ++ni)
          acc[mi][ni] = __builtin_amdgcn_mfma_f32_16x16x32_bf16(av[mi], bv[ni], acc[mi][ni], 0, 0, 0);
    }
    __builtin_amdgcn_s_setprio(0);
  }

  short* outp = P + pstride * sk;
  #pragma unroll
  for (int mi = 0; mi < 4; ++mi) {
    #pragma unroll
    for (int r = 0; r < 4; ++r) {
      const int m = m0 + wr * 64 + mi * 16 + lk * 4 + r;
      #pragma unroll
      for (int ni = 0; ni < 4; ++ni) {
        const int n = n0 + wc * 64 + ni * 16 + lr;
        outp[(size_t)m * ldC + n] = f2bf(acc[mi][ni][r]);
      }
    }
  }
}

// ---- reduce S partials + normalize; fallback substitutes raw h row (coalesced)
__global__ __launch_bounds__(256) void k_sk_reduce_sub(
    const short* __restrict__ P, int N, size_t pstride, int S,
    const float* __restrict__ colsum, const u32* __restrict__ colmax,
    const short* __restrict__ hraw, int ldh,
    short* __restrict__ out, int ldo)
{
  const int idx = blockIdx.x * 256 + threadIdx.x;
  const int nq = N >> 2;
  const int m = idx / nq;
  const int c4 = (idx - m * nq) * 4;
  const size_t base = (size_t)m * N + c4;
  float a0 = 0.f, a1 = 0.f, a2 = 0.f, a3 = 0.f;
  for (int s = 0; s < S; ++s) {
    s16x4 v = *(const s16x4*)&P[pstride * s + base];
    a0 += bf2f(v.x); a1 += bf2f(v.y); a2 += bf2f(v.z); a3 += bf2f(v.w);
  }
  const float cs = colsum[m];
  const float rc = 1.f / (cs + EPS_A);
  const float rcw = rc / (cs * rc + EPS_A);
  const bool he = __uint_as_float(colmax[m]) * rc > THR_A;
  s16x4 o;
  if (he) {
    o.x = f2bf(a0 * rcw); o.y = f2bf(a1 * rcw);
    o.z = f2bf(a2 * rcw); o.w = f2bf(a3 * rcw);
  } else {
    o = *(const s16x4*)&hraw[(size_t)m * ldh + c4];
  }
  *(s16x4*)&out[(size_t)m * ldo + c4] = o;
}

// ---- reduce S partials + normalize; fallback gathers T^T (rare, ballot-skipped)
__global__ __launch_bounds__(256) void k_sk_reduce(
    const short* __restrict__ P, int N, size_t pstride, int S,
    const float* __restrict__ colsum, const u32* __restrict__ colmax,
    const short* __restrict__ Tfall, short* __restrict__ out, int ldo)
{
  const int idx = blockIdx.x * 256 + threadIdx.x;
  const int nq = N >> 2;
  const int m = idx / nq;
  const int c4 = (idx - m * nq) * 4;
  const size_t base = (size_t)m * N + c4;
  float a0 = 0.f, a1 = 0.f, a2 = 0.f, a3 = 0.f;
  for (int s = 0; s < S; ++s) {
    s16x4 v = *(const s16x4*)&P[pstride * s + base];
    a0 += bf2f(v.x); a1 += bf2f(v.y); a2 += bf2f(v.z); a3 += bf2f(v.w);
  }
  const float cs = colsum[m];
  const float rc = 1.f / (cs + EPS_A);
  const float rcw = rc / (cs * rc + EPS_A);
  const bool he = __uint_as_float(colmax[m]) * rc > THR_A;
  a0 *= rcw; a1 *= rcw; a2 *= rcw; a3 *= rcw;
  if (__ballot(!he)) {
    if (!he) {
      a0 = bf2f(Tfall[(size_t)(c4 + 0) * NN + m]);
      a1 = bf2f(Tfall[(size_t)(c4 + 1) * NN + m]);
      a2 = bf2f(Tfall[(size_t)(c4 + 2) * NN + m]);
      a3 = bf2f(Tfall[(size_t)(c4 + 3) * NN + m]);
    }
  }
  s16x4 o;
  o.x = f2bf(a0); o.y = f2bf(a1); o.z = f2bf(a2); o.w = f2bf(a3);
  *(s16x4*)&out[(size_t)m * ldo + c4] = o;
}

// ---- row LayerNorm + ReLU, fp32 in.  MODE 0: bf16 out (ld-strided), MODE 1: fp32 out
template <int MODE>
__device__ __forceinline__ void ln_relu_body(
    const float* __restrict__ X, int W,
    const float* __restrict__ g, const float* __restrict__ be,
    void* __restrict__ out, int ldo)
{
  const int row = blockIdx.x;
  const int t = threadIdx.x;
  const float* x = X + (size_t)row * W;
  float v0 = x[t], v1 = 0.f;
  float s = v0, ss = v0 * v0;
  if (W == 512) { v1 = x[t + 256]; s += v1; ss += v1 * v1; }
  #pragma unroll
  for (int off = 32; off; off >>= 1) {
    s += __shfl_down(s, off);
    ss += __shfl_down(ss, off);
  }
  __shared__ float red[8];
  const int wid = t >> 6;
  if ((t & 63) == 0) { red[wid] = s; red[4 + wid] = ss; }
  __syncthreads();
  s = red[0] + red[1] + red[2] + red[3];
  ss = red[4] + red[5] + red[6] + red[7];
  const float mu = s / W;
  const float var = ss / W - mu * mu;
  const float sc = rsqrtf(var + 1e-5f);
  float y = fmaxf((v0 - mu) * sc * g[t] + be[t], 0.f);
  if (MODE == 0) ((short*)out)[(size_t)row * ldo + t] = f2bf(y);
  else           ((float*)out)[(size_t)row * ldo + t] = y;
  if (W == 512) {
    float y1 = fmaxf((v1 - mu) * sc * g[t + 256] + be[t + 256], 0.f);
    if (MODE == 0) ((short*)out)[(size_t)row * ldo + t + 256] = f2bf(y1);
    else           ((float*)out)[(size_t)row * ldo + t + 256] = y1;
  }
}

__global__ __launch_bounds__(256) void k_ln_relu_bf16(
    const float* __restrict__ X, int W, const float* __restrict__ g,
    const float* __restrict__ be, short* __restrict__ out, int ldo) {
  ln_relu_body<0>(X, W, g, be, out, ldo);
}
__global__ __launch_bounds__(256) void k_ln_relu_f32(
    const float* __restrict__ X, int W, const float* __restrict__ g,
    const float* __restrict__ be, float* __restrict__ out, int ldo) {
  ln_relu_body<1>(X, W, g, be, out, ldo);
}

extern "C" void kernel_launch(void* const* d_in, const int* in_sizes, int n_in,
                              void* d_out, int out_size, void* d_ws, size_t ws_size,
                              hipStream_t stream) {
  const float* nf      = (const float*)d_in[0];
  const float* Mob     = (const float*)d_in[1];
  const float* W_in1   = (const float*)d_in[2];
  const float* b_in1   = (const float*)d_in[3];
  const float* W_out1  = (const float*)d_in[4];
  const float* b_out1  = (const float*)d_in[5];
  const float* W_self1 = (const float*)d_in[6];
  const float* b_self1 = (const float*)d_in[7];
  const float* g1      = (const float*)d_in[8];
  const float* be1     = (const float*)d_in[9];
  const float* W_in2   = (const float*)d_in[10];
  const float* b_in2   = (const float*)d_in[11];
  const float* W_out2  = (const float*)d_in[12];
  const float* b_out2  = (const float*)d_in[13];
  const float* W_self2 = (const float*)d_in[14];
  const float* b_self2 = (const float*)d_in[15];
  const float* g2      = (const float*)d_in[16];
  const float* be2     = (const float*)d_in[17];

  char* ws = (char*)d_ws;
  float* colsum = (float*)(ws);                       // 32 KB
  u32*   colmax = (u32*)(ws + 32768);                 // 32 KB
  short* Mt     = (short*)(ws + 131072);              // [8192][8192] bf16
  short* nft    = (short*)(ws + 134348800);           // [256][8192]
  short* A1cat  = (short*)(ws + 138543104);           // [8192][512]: [A1|nf]
  float* C2f    = (float*)(ws + 146931712);           // [8192][512] f32
  short* Acat2  = (short*)(ws + 163708928);           // [8192][768]: [agg2|h1]
  short* T2t    = (short*)(ws + 176291840);           // [256][8192]
  short* Bcat1  = (short*)(ws + 180486144);           // [512][512]: [Wc1^T|Wself1^T]
  short* Bcat2  = (short*)(ws + 181010432);           // [256][768]
  short* Win2t  = (short*)(ws + 181403648);           // [256][512]
  short* Wout1t = (short*)(ws + 181665792);           // [512][512]
  short* Win1b  = (short*)(ws + 182190080);           // [256][512]
  float* bias1c = (float*)(ws + 182452224);           // [512]
  float* bias2c = (float*)(ws + 182454272);           // [256]
  short* P1     = (short*)(ws + 188743680);           // 8 x [8192][256] bf16
  short* P2     = (short*)(ws + 222298112);           // 8 x [8192][256] bf16

  hipMemsetAsync(ws, 0, 65536, stream);  // zero colsum + colmax every call

  k_prep_all<<<9603, 256, 0, stream>>>(Mob, nf, W_in1, W_out1, W_self1, W_in2,
                                       W_out2, W_self2, b_in1, b_out1, b_self1,
                                       b_out2, b_self2, Mt, colsum, colmax, nft,
                                       A1cat, Win1b, Wout1t, Bcat1, Win2t, Bcat2,
                                       bias1c, bias2c);
  // Wc1^T = W_out1^T @ W_in1 : [512][256] into Bcat1 cols 0:256
  k_gemm_raw_n<<<dim3(4, 8), 256, 0, stream>>>(Wout1t, Win1b, 512, 512, 512,
                                               Bcat1, 512);

  // ---- layer 1 (reassociated): G1 = Mt @ nft^T  (M=8192,N=256,K=8192, z=8)
  k_gemm_sk128<<<dim3(2, 64, 8), 256, 0, stream>>>(Mt, nft, 1024, NN, NN,
                                                   P1, 256, (size_t)8192 * 256);
  k_sk_reduce_sub<<<2048, 256, 0, stream>>>(P1, 256, (size_t)8192 * 256, 8,
                                            colsum, colmax, A1cat + 256, 512,
                                            A1cat, 512);
  k_g64<128, 2><<<dim3(4, 128), 256, 0, stream>>>(A1cat, Bcat1, 512, 512, 512,
                                                  C2f, 512, bias1c);
  k_ln_relu_bf16<<<8192, 256, 0, stream>>>(C2f, 512, g1, be1, Acat2 + 256, 768);

  // ---- layer 2: T2t = W_in2^T@h1^T + b_in2; agg2; out2; LN
  k_g64<64, 0><<<dim3(128, 4), 256, 0, stream>>>(Win2t, Acat2 + 256, 512, 512, 768,
                                                 T2t, NN, b_in2);
  k_gemm_sk128<<<dim3(2, 64, 8), 256, 0, stream>>>(Mt, T2t, 1024, NN, NN,
                                                   P2, 256, (size_t)8192 * 256);
  k_sk_reduce<<<2048, 256, 0, stream>>>(P2, 256, (size_t)8192 * 256, 8,
                                        colsum, colmax, T2t, Acat2, 768);
  k_g64<64, 2><<<dim3(4, 128), 256, 0, stream>>>(Acat2, Bcat2, 768, 768, 768,
                                                 C2f, 256, bias2c);
  k_ln_relu_f32<<<8192, 256, 0, stream>>>(C2f, 256, g2, be2, (float*)d_out, 256);
}

// Round 19
// 278.896 us; speedup vs baseline: 2.4137x; 1.0696x over previous
//
#include <hip/hip_runtime.h>
#include <stdint.h>

typedef short bf16x8 __attribute__((ext_vector_type(8)));
typedef short s16x4 __attribute__((ext_vector_type(4)));
typedef float f32x4 __attribute__((ext_vector_type(4)));
typedef unsigned int u32;
typedef unsigned char u8;

#define EPS_A 1e-8f
#define THR_A 1e-6f
#define NN 8192

static __device__ __forceinline__ short f2bf(float f) {
  u32 u = __float_as_uint(f);
  u = u + 0x7FFFu + ((u >> 16) & 1u);   // RNE, no NaN inputs here
  return (short)(u >> 16);
}
static __device__ __forceinline__ float bf2f(short s) {
  return __uint_as_float(((u32)(unsigned short)s) << 16);
}
static __device__ __forceinline__ u8 f2fp8(float v) {
  return (u8)(__builtin_amdgcn_cvt_pk_fp8_f32(v, v, 0, false) & 0xff);
}
// async global->LDS, 16B per lane; DIRECT addrspacecasts (proven round 12)
static __device__ __forceinline__ void gld16(const void* g, void* l) {
  __builtin_amdgcn_global_load_lds(
      (const __attribute__((address_space(1))) u32*)g,
      (__attribute__((address_space(3))) u32*)l, 16, 0, 0);
}

// ---- fused prep: Mt8 (fp8) transpose-cast + colsum/colmax, weight/feature casts,
//      bias folds — ONE launch, 9603 blocks
__global__ __launch_bounds__(256) void k_prep_all(
    const float* __restrict__ Mob, const float* __restrict__ nf,
    const float* __restrict__ W_in1, const float* __restrict__ W_out1,
    const float* __restrict__ W_self1, const float* __restrict__ W_in2,
    const float* __restrict__ W_out2, const float* __restrict__ W_self2,
    const float* __restrict__ b_in1, const float* __restrict__ b_out1,
    const float* __restrict__ b_self1, const float* __restrict__ b_out2,
    const float* __restrict__ b_self2,
    u8* __restrict__ Mt8, float* __restrict__ colsum, u32* __restrict__ colmax,
    u8* __restrict__ nft8, short* __restrict__ A1cat, short* __restrict__ Win1b,
    short* __restrict__ Wout1t, short* __restrict__ Bcat1, short* __restrict__ Win2t,
    short* __restrict__ Bcat2, float* __restrict__ bias1c, float* __restrict__ bias2c)
{
  __shared__ __align__(16) u32 sbuf[256 * 17];   // 17408 B, reused per block role
  int b = blockIdx.x;
  const int t = threadIdx.x;
  if (b < 4096) {                      // Mt8: transpose-cast fp8 + colsum/colmax
    const int i0 = (b & 31) * 256;
    const int j0 = (b >> 5) * 64;
    const int i = i0 + t;
    float s = 0.f, mx = 0.f;
    #pragma unroll 4
    for (int j4 = 0; j4 < 16; ++j4) {
      float v0 = Mob[(size_t)(j0 + j4 * 4 + 0) * NN + i];
      float v1 = Mob[(size_t)(j0 + j4 * 4 + 1) * NN + i];
      float v2 = Mob[(size_t)(j0 + j4 * 4 + 2) * NN + i];
      float v3 = Mob[(size_t)(j0 + j4 * 4 + 3) * NN + i];
      s += v0 + v1 + v2 + v3;
      mx = fmaxf(fmaxf(mx, fmaxf(v0, v1)), fmaxf(v2, v3));
      u32 pk = __builtin_amdgcn_cvt_pk_fp8_f32(v0, v1, 0, false);
      pk = __builtin_amdgcn_cvt_pk_fp8_f32(v2, v3, (int)pk, true);
      sbuf[t * 17 + j4] = pk;
    }
    atomicAdd(&colsum[i], s);
    atomicMax(&colmax[i], __float_as_uint(mx));  // M >= 0: uint order == float order
    __syncthreads();
    #pragma unroll
    for (int p = 0; p < 4; ++p) {               // 64 rows/pass, 4 x 16B per row
      const int r = p * 64 + (t >> 2);
      const int c = t & 3;
      const u32* src = &sbuf[r * 17 + c * 4];
      int4 w = make_int4(src[0], src[1], src[2], src[3]);
      *(int4*)&Mt8[(size_t)(i0 + r) * NN + j0 + c * 16] = w;
    }
    return;
  }
  b -= 4096;
  if (b < 512) {                       // nf^T -> fp8: LDS-tiled transpose 8192x256
    u8* tile = (u8*)sbuf;              // [64][68]
    const int r0 = (b & 127) * 64, c0 = (b >> 7) * 64;
    #pragma unroll
    for (int p = 0; p < 16; ++p) {
      const int rr = p * 4 + (t >> 6), cc = t & 63;
      tile[rr * 68 + cc] = f2fp8(nf[(size_t)(r0 + rr) * 256 + c0 + cc]);
    }
    __syncthreads();
    #pragma unroll
    for (int q = 0; q < 16; ++q) {
      const int cc = q * 4 + (t >> 6), rr = t & 63;
      nft8[(size_t)(c0 + cc) * 8192 + r0 + rr] = tile[rr * 68 + cc];
    }
    return;
  }
  b -= 512;
  if (b < 2048) {                      // nf -> A1cat cols 256:512 (bf16)
    const int idx = b * 256 + t;
    const float4 v = ((const float4*)nf)[idx];
    const int i = idx >> 6;
    const int c = (idx & 63) * 4;
    s16x4 o;
    o.x = f2bf(v.x); o.y = f2bf(v.y); o.z = f2bf(v.z); o.w = f2bf(v.w);
    *(s16x4*)&A1cat[(size_t)i * 512 + 256 + c] = o;
    return;
  }
  b -= 2048;
  if (b < 128) {                       // W_in1 straight cast 256x512
    const int idx = b * 256 + t;
    const float4 v = ((const float4*)W_in1)[idx];
    s16x4 o;
    o.x = f2bf(v.x); o.y = f2bf(v.y); o.z = f2bf(v.z); o.w = f2bf(v.w);
    *(s16x4*)&Win1b[idx * 4] = o;
    return;
  }
  b -= 128;
  if (b < 1024) {                      // W_out1^T 512x512 -> Wout1t ld 512
    const int idx = b * 256 + t;
    const int r = idx >> 9, c = idx & 511;
    Wout1t[(size_t)c * 512 + r] = f2bf(W_out1[idx]);
    return;
  }
  b -= 1024;
  if (b < 512) {                       // W_self1^T 256x512 -> Bcat1+256 ld 512
    const int idx = b * 256 + t;
    const int r = idx >> 9, c = idx & 511;
    Bcat1[(size_t)c * 512 + 256 + r] = f2bf(W_self1[idx]);
    return;
  }
  b -= 512;
  if (b < 512) {                       // W_in2^T 512x256 -> Win2t ld 512
    const int idx = b * 256 + t;
    const int r = idx >> 8, c = idx & 255;
    Win2t[(size_t)c * 512 + r] = f2bf(W_in2[idx]);
    return;
  }
  b -= 512;
  if (b < 256) {                       // W_out2^T 256x256 -> Bcat2 ld 768
    const int idx = b * 256 + t;
    const int r = idx >> 8, c = idx & 255;
    Bcat2[(size_t)c * 768 + r] = f2bf(W_out2[idx]);
    return;
  }
  b -= 256;
  if (b < 512) {                       // W_self2^T 512x256 -> Bcat2+256 ld 768
    const int idx = b * 256 + t;
    const int r = idx >> 8, c = idx & 255;
    Bcat2[(size_t)c * 768 + 256 + r] = f2bf(W_self2[idx]);
    return;
  }
  b -= 512;
  if (b < 2) {                         // bias1c = b_in1@W_out1 + b_out1 + b_self1
    const int n = b * 256 + t;
    float a = b_out1[n] + b_self1[n];
    for (int p = 0; p < 512; ++p) a += b_in1[p] * W_out1[(size_t)p * 512 + n];
    bias1c[n] = a;
    return;
  }
  bias2c[t] = b_out2[t] + b_self2[t];  // last block
}

// ---- old 64x64 reg-staged body (kept ONLY for tiny Wc1 GEMM; proven)
__global__ __launch_bounds__(256) void k_gemm_raw_n(
    const short* __restrict__ A, const short* __restrict__ B, int K, int ldA, int ldB,
    short* __restrict__ C, int ldC)
{
  constexpr int LDP = 40;
  __shared__ __align__(16) short As[64 * LDP];
  __shared__ __align__(16) short Bs[64 * LDP];
  const int t = threadIdx.x;
  const int m0 = blockIdx.y * 64, n0 = blockIdx.x * 64;
  const int wid = t >> 6, l = t & 63;
  const int wr = wid >> 1, wc = wid & 1;
  const int lr = l & 15, lk = l >> 4;
  f32x4 acc[2][2] = {};
  const int sr = t >> 2;
  const int sc = (t & 3) * 8;
  const short* gA0 = A + (size_t)(m0 + sr) * ldA + sc;
  const short* gB0 = B + (size_t)(n0 + sr) * ldB + sc;
  for (int k0 = 0; k0 < K; k0 += 32) {
    const int4 a0 = *(const int4*)(gA0 + k0);
    const int4 b0 = *(const int4*)(gB0 + k0);
    __syncthreads();
    *(int4*)&As[sr * LDP + sc] = a0;
    *(int4*)&Bs[sr * LDP + sc] = b0;
    __syncthreads();
    bf16x8 av[2], bv[2];
    #pragma unroll
    for (int mi = 0; mi < 2; ++mi)
      av[mi] = *(const bf16x8*)&As[(wr * 32 + mi * 16 + lr) * LDP + lk * 8];
    #pragma unroll
    for (int ni = 0; ni < 2; ++ni)
      bv[ni] = *(const bf16x8*)&Bs[(wc * 32 + ni * 16 + lr) * LDP + lk * 8];
    #pragma unroll
    for (int mi = 0; mi < 2; ++mi)
      #pragma unroll
      for (int ni = 0; ni < 2; ++ni)
        acc[mi][ni] = __builtin_amdgcn_mfma_f32_16x16x32_bf16(av[mi], bv[ni], acc[mi][ni], 0, 0, 0);
  }
  #pragma unroll
  for (int mi = 0; mi < 2; ++mi)
    #pragma unroll
    for (int r = 0; r < 4; ++r) {
      const int m = m0 + wr * 32 + mi * 16 + lk * 4 + r;
      #pragma unroll
      for (int ni = 0; ni < 2; ++ni) {
        const int n = n0 + wc * 32 + ni * 16 + lr;
        C[(size_t)m * ldC + n] = f2bf(acc[mi][ni][r]);
      }
    }
}

// ---- 64 x BN bf16 GEMM, BK=64, gld_lds staging, swizzled unified LDS,
// staggered K, setprio (proven r16/17).
// EPI 0: +bias0[m] bf16; EPI 2: +bias0[n] fp32; EPI 4: +bias0[m] bf16 AND fp8 copy.
template <int BN, int EPI>
__global__ __launch_bounds__(256) void k_g64(
    const short* __restrict__ A, const short* __restrict__ B, int K, int ldA, int ldB,
    void* __restrict__ Cout, int ldC, const float* __restrict__ bias0,
    u8* __restrict__ C8)
{
  constexpr int ROWS = 64 + BN;
  constexpr int CH = ROWS / 32;
  constexpr int NI = BN / 32;
  __shared__ __align__(16) short S[ROWS * 64];
  const int t = threadIdx.x;

  const int gx = gridDim.x;
  int flat = blockIdx.y * gx + blockIdx.x;
  const int cpx = (gx * gridDim.y) >> 3;
  flat = (flat & 7) * cpx + (flat >> 3);
  const int bx = flat % gx, by = flat / gx;
  const int m0 = by * 64, n0 = bx * BN;

  const int wid = t >> 6, l = t & 63;
  const int wr = wid >> 1, wc = wid & 1;
  const int lr = l & 15, lk = l >> 4;

  f32x4 acc[2][NI] = {};

  const int lrow = l >> 3, lcol = l & 7;
  const int wbase = wid * (ROWS / 4);
  short* dbase = S + wbase * 64;
  const short* gsrc[CH];
  #pragma unroll
  for (int c = 0; c < CH; ++c) {
    const int ar = wbase + c * 8 + lrow;
    const int scol = (lcol ^ (ar & 7)) * 8;
    gsrc[c] = (ar < 64) ? A + (size_t)(m0 + ar) * ldA + scol
                        : B + (size_t)(n0 + ar - 64) * ldB + scol;
  }

  const int niters = K >> 6;
  int kk = flat % niters;
  for (int it = 0; it < niters; ++it) {
    const int koff = kk << 6;
    kk = (kk + 1 == niters) ? 0 : kk + 1;
    __syncthreads();
    #pragma unroll
    for (int c = 0; c < CH; ++c)
      gld16(gsrc[c] + koff, dbase + c * 512);
    __syncthreads();

    __builtin_amdgcn_s_setprio(1);
    #pragma unroll
    for (int ks = 0; ks < 2; ++ks) {
      bf16x8 av[2], bv[NI];
      #pragma unroll
      for (int mi = 0; mi < 2; ++mi) {
        const int row = wr * 32 + mi * 16 + lr;
        av[mi] = *(const bf16x8*)&S[row * 64 + ((ks * 4 + lk) ^ (row & 7)) * 8];
      }
      #pragma unroll
      for (int ni = 0; ni < NI; ++ni) {
        const int row = 64 + wc * (BN / 2) + ni * 16 + lr;
        bv[ni] = *(const bf16x8*)&S[row * 64 + ((ks * 4 + lk) ^ (row & 7)) * 8];
      }
      #pragma unroll
      for (int mi = 0; mi < 2; ++mi)
        #pragma unroll
        for (int ni = 0; ni < NI; ++ni)
          acc[mi][ni] = __builtin_amdgcn_mfma_f32_16x16x32_bf16(av[mi], bv[ni], acc[mi][ni], 0, 0, 0);
    }
    __builtin_amdgcn_s_setprio(0);
  }

  #pragma unroll
  for (int mi = 0; mi < 2; ++mi) {
    #pragma unroll
    for (int r = 0; r < 4; ++r) {
      const int m = m0 + wr * 32 + mi * 16 + lk * 4 + r;
      float bm = 0.f;
      if (EPI == 0 || EPI == 4) bm = bias0[m];
      #pragma unroll
      for (int ni = 0; ni < NI; ++ni) {
        const int n = n0 + wc * (BN / 2) + ni * 16 + lr;
        float v = acc[mi][ni][r];
        if (EPI == 0 || EPI == 4) {
          v += bm;
          ((short*)Cout)[(size_t)m * ldC + n] = f2bf(v);
          if (EPI == 4) C8[(size_t)m * ldC + n] = f2fp8(v);
        } else {
          ((float*)Cout)[(size_t)m * ldC + n] = v + bias0[n];
        }
      }
    }
  }
}

// ---- 128x128 split-K fp8 GEMM, BK=64 bytes, gld_lds staging (linear dest,
// involution-swizzled 16B source), staggered circular K, setprio.
// LDS [128 rows][64 B]/side; logical 16B-slot q stored at qp = q ^ (row&3).
__global__ __launch_bounds__(256) void k_sk128_f8(
    const u8* __restrict__ A, const u8* __restrict__ B, int K, int ldA, int ldB,
    short* __restrict__ P, int ldC, size_t pstride)
{
  __shared__ __align__(16) u8 As[128 * 64];   // 8 KB each
  __shared__ __align__(16) u8 Bs[128 * 64];
  const int t = threadIdx.x;

  const int sk = blockIdx.z;
  A += (size_t)sk * K;
  B += (size_t)sk * K;

  const int gx = gridDim.x;
  int flat = blockIdx.y * gx + blockIdx.x;
  const int cpx = (gx * gridDim.y) >> 3;
  flat = (flat & 7) * cpx + (flat >> 3);
  const int bx = flat % gx, by = flat / gx;
  const int m0 = by * 128, n0 = bx * 128;

  const int wid = t >> 6, l = t & 63;
  const int wr = wid >> 1, wc = wid & 1;
  const int lr = l & 15, lk = l >> 4;      // lk = k-group 0..3 (8B each)

  f32x4 acc[4][4] = {};

  // staging: waves 0,1 -> As halves; waves 2,3 -> Bs halves. 4 chunks x 1KB/wave.
  const int side = wid >> 1;
  const int hrow = (wid & 1) * 64;
  const u8* Xp = side ? B : A;
  const int ldX = side ? ldB : ldA;
  const int x0 = side ? n0 : m0;
  u8* dbase = (side ? Bs : As) + hrow * 64;
  const u8* gsrc[4];
  #pragma unroll
  for (int c = 0; c < 4; ++c) {
    const int row = hrow + c * 16 + (l >> 2);
    const int ql = (l & 3) ^ (row & 3);
    gsrc[c] = Xp + (size_t)(x0 + row) * ldX + ql * 16;
  }

  const int niters = K >> 6;               // 16 for K=1024
  int kk = (flat + sk * 3) & (niters - 1); // staggered start
  for (int it = 0; it < niters; ++it) {
    const int koff = kk << 6;
    kk = (kk + 1) & (niters - 1);
    __syncthreads();
    gld16(gsrc[0] + koff, dbase);
    gld16(gsrc[1] + koff, dbase + 1024);
    gld16(gsrc[2] + koff, dbase + 2048);
    gld16(gsrc[3] + koff, dbase + 3072);
    __syncthreads();

    __builtin_amdgcn_s_setprio(1);
    #pragma unroll
    for (int ks = 0; ks < 2; ++ks) {       // 32-byte k-slices
      const int q = ks * 2 + (lk >> 1);    // logical 16B slot
      const int inner = (lk & 1) * 8;
      long av[4], bv[4];
      #pragma unroll
      for (int mi = 0; mi < 4; ++mi) {
        const int row = wr * 64 + mi * 16 + lr;
        av[mi] = *(const long*)&As[row * 64 + ((q ^ (row & 3)) << 4) + inner];
      }
      #pragma unroll
      for (int ni = 0; ni < 4; ++ni) {
        const int row = wc * 64 + ni * 16 + lr;
        bv[ni] = *(const long*)&Bs[row * 64 + ((q ^ (row & 3)) << 4) + inner];
      }
      #pragma unroll
      for (int mi = 0; mi < 4; ++mi)
        #pragma unroll
        for (int ni = 0; ni < 4; ++ni)
          acc[mi][ni] = __builtin_amdgcn_mfma_f32_16x16x32_fp8_fp8(av[mi], bv[ni], acc[mi][ni], 0, 0, 0);
    }
    __builtin_amdgcn_s_setprio(0);
  }

  short* outp = P + pstride * sk;
  #pragma unroll
  for (int mi = 0; mi < 4; ++mi) {
    #pragma unroll
    for (int r = 0; r < 4; ++r) {
      const int m = m0 + wr * 64 + mi * 16 + lk * 4 + r;
      #pragma unroll
      for (int ni = 0; ni < 4; ++ni) {
        const int n = n0 + wc * 64 + ni * 16 + lr;
        outp[(size_t)m * ldC + n] = f2bf(acc[mi][ni][r]);
      }
    }
  }
}

// ---- reduce S partials + normalize; fallback substitutes raw h row (coalesced)
__global__ __launch_bounds__(256) void k_sk_reduce_sub(
    const short* __restrict__ P, int N, size_t pstride, int S,
    const float* __restrict__ colsum, const u32* __restrict__ colmax,
    const short* __restrict__ hraw, int ldh,
    short* __restrict__ out, int ldo)
{
  const int idx = blockIdx.x * 256 + threadIdx.x;
  const int nq = N >> 2;
  const int m = idx / nq;
  const int c4 = (idx - m * nq) * 4;
  const size_t base = (size_t)m * N + c4;
  float a0 = 0.f, a1 = 0.f, a2 = 0.f, a3 = 0.f;
  for (int s = 0; s < S; ++s) {
    s16x4 v = *(const s16x4*)&P[pstride * s + base];
    a0 += bf2f(v.x); a1 += bf2f(v.y); a2 += bf2f(v.z); a3 += bf2f(v.w);
  }
  const float cs = colsum[m];
  const float rc = 1.f / (cs + EPS_A);
  const float rcw = rc / (cs * rc + EPS_A);
  const bool he = __uint_as_float(colmax[m]) * rc > THR_A;
  s16x4 o;
  if (he) {
    o.x = f2bf(a0 * rcw); o.y = f2bf(a1 * rcw);
    o.z = f2bf(a2 * rcw); o.w = f2bf(a3 * rcw);
  } else {
    o = *(const s16x4*)&hraw[(size_t)m * ldh + c4];
  }
  *(s16x4*)&out[(size_t)m * ldo + c4] = o;
}

// ---- reduce S partials + normalize; fallback gathers bf16 T^T (rare, ballot-skip)
__global__ __launch_bounds__(256) void k_sk_reduce(
    const short* __restrict__ P, int N, size_t pstride, int S,
    const float* __restrict__ colsum, const u32* __restrict__ colmax,
    const short* __restrict__ Tfall, short* __restrict__ out, int ldo)
{
  const int idx = blockIdx.x * 256 + threadIdx.x;
  const int nq = N >> 2;
  const int m = idx / nq;
  const int c4 = (idx - m * nq) * 4;
  const size_t base = (size_t)m * N + c4;
  float a0 = 0.f, a1 = 0.f, a2 = 0.f, a3 = 0.f;
  for (int s = 0; s < S; ++s) {
    s16x4 v = *(const s16x4*)&P[pstride * s + base];
    a0 += bf2f(v.x); a1 += bf2f(v.y); a2 += bf2f(v.z); a3 += bf2f(v.w);
  }
  const float cs = colsum[m];
  const float rc = 1.f / (cs + EPS_A);
  const float rcw = rc / (cs * rc + EPS_A);
  const bool he = __uint_as_float(colmax[m]) * rc > THR_A;
  a0 *= rcw; a1 *= rcw; a2 *= rcw; a3 *= rcw;
  if (__ballot(!he)) {
    if (!he) {
      a0 = bf2f(Tfall[(size_t)(c4 + 0) * NN + m]);
      a1 = bf2f(Tfall[(size_t)(c4 + 1) * NN + m]);
      a2 = bf2f(Tfall[(size_t)(c4 + 2) * NN + m]);
      a3 = bf2f(Tfall[(size_t)(c4 + 3) * NN + m]);
    }
  }
  s16x4 o;
  o.x = f2bf(a0); o.y = f2bf(a1); o.z = f2bf(a2); o.w = f2bf(a3);
  *(s16x4*)&out[(size_t)m * ldo + c4] = o;
}

// ---- row LayerNorm + ReLU, fp32 in.  MODE 0: bf16 out (ld-strided), MODE 1: fp32 out
template <int MODE>
__device__ __forceinline__ void ln_relu_body(
    const float* __restrict__ X, int W,
    const float* __restrict__ g, const float* __restrict__ be,
    void* __restrict__ out, int ldo)
{
  const int row = blockIdx.x;
  const int t = threadIdx.x;
  const float* x = X + (size_t)row * W;
  float v0 = x[t], v1 = 0.f;
  float s = v0, ss = v0 * v0;
  if (W == 512) { v1 = x[t + 256]; s += v1; ss += v1 * v1; }
  #pragma unroll
  for (int off = 32; off; off >>= 1) {
    s += __shfl_down(s, off);
    ss += __shfl_down(ss, off);
  }
  __shared__ float red[8];
  const int wid = t >> 6;
  if ((t & 63) == 0) { red[wid] = s; red[4 + wid] = ss; }
  __syncthreads();
  s = red[0] + red[1] + red[2] + red[3];
  ss = red[4] + red[5] + red[6] + red[7];
  const float mu = s / W;
  const float var = ss / W - mu * mu;
  const float sc = rsqrtf(var + 1e-5f);
  float y = fmaxf((v0 - mu) * sc * g[t] + be[t], 0.f);
  if (MODE == 0) ((short*)out)[(size_t)row * ldo + t] = f2bf(y);
  else           ((float*)out)[(size_t)row * ldo + t] = y;
  if (W == 512) {
    float y1 = fmaxf((v1 - mu) * sc * g[t + 256] + be[t + 256], 0.f);
    if (MODE == 0) ((short*)out)[(size_t)row * ldo + t + 256] = f2bf(y1);
    else           ((float*)out)[(size_t)row * ldo + t + 256] = y1;
  }
}

__global__ __launch_bounds__(256) void k_ln_relu_bf16(
    const float* __restrict__ X, int W, const float* __restrict__ g,
    const float* __restrict__ be, short* __restrict__ out, int ldo) {
  ln_relu_body<0>(X, W, g, be, out, ldo);
}
__global__ __launch_bounds__(256) void k_ln_relu_f32(
    const float* __restrict__ X, int W, const float* __restrict__ g,
    const float* __restrict__ be, float* __restrict__ out, int ldo) {
  ln_relu_body<1>(X, W, g, be, out, ldo);
}

extern "C" void kernel_launch(void* const* d_in, const int* in_sizes, int n_in,
                              void* d_out, int out_size, void* d_ws, size_t ws_size,
                              hipStream_t stream) {
  const float* nf      = (const float*)d_in[0];
  const float* Mob     = (const float*)d_in[1];
  const float* W_in1   = (const float*)d_in[2];
  const float* b_in1   = (const float*)d_in[3];
  const float* W_out1  = (const float*)d_in[4];
  const float* b_out1  = (const float*)d_in[5];
  const float* W_self1 = (const float*)d_in[6];
  const float* b_self1 = (const float*)d_in[7];
  const float* g1      = (const float*)d_in[8];
  const float* be1     = (const float*)d_in[9];
  const float* W_in2   = (const float*)d_in[10];
  const float* b_in2   = (const float*)d_in[11];
  const float* W_out2  = (const float*)d_in[12];
  const float* b_out2  = (const float*)d_in[13];
  const float* W_self2 = (const float*)d_in[14];
  const float* b_self2 = (const float*)d_in[15];
  const float* g2      = (const float*)d_in[16];
  const float* be2     = (const float*)d_in[17];

  char* ws = (char*)d_ws;
  float* colsum = (float*)(ws);                       // 32 KB
  u32*   colmax = (u32*)(ws + 32768);                 // 32 KB
  u8*    Mt8    = (u8*)(ws + 131072);                 // [8192][8192] fp8 = 67 MB
  u8*    nft8   = (u8*)(ws + 67239936);               // [256][8192] fp8
  u8*    T2t8   = (u8*)(ws + 69337088);               // [256][8192] fp8
  short* A1cat  = (short*)(ws + 71434240);            // [8192][512]: [A1|nf]
  float* C2f    = (float*)(ws + 79822848);            // [8192][512] f32
  short* Acat2  = (short*)(ws + 96600064);            // [8192][768]: [agg2|h1]
  short* T2t    = (short*)(ws + 109182976);           // [256][8192] bf16 (fallback)
  short* Bcat1  = (short*)(ws + 113377280);           // [512][512]: [Wc1^T|Wself1^T]
  short* Bcat2  = (short*)(ws + 113901568);           // [256][768]
  short* Win2t  = (short*)(ws + 114294784);           // [256][512]
  short* Wout1t = (short*)(ws + 114556928);           // [512][512]
  short* Win1b  = (short*)(ws + 115081216);           // [256][512]
  float* bias1c = (float*)(ws + 115343360);           // [512]
  float* bias2c = (float*)(ws + 115345408);           // [256]
  short* P1     = (short*)(ws + 117440512);           // 8 x [8192][256] bf16
  short* P2     = (short*)(ws + 150994944);           // 8 x [8192][256] bf16

  hipMemsetAsync(ws, 0, 65536, stream);  // zero colsum + colmax every call

  k_prep_all<<<9603, 256, 0, stream>>>(Mob, nf, W_in1, W_out1, W_self1, W_in2,
                                       W_out2, W_self2, b_in1, b_out1, b_self1,
                                       b_out2, b_self2, Mt8, colsum, colmax, nft8,
                                       A1cat, Win1b, Wout1t, Bcat1, Win2t, Bcat2,
                                       bias1c, bias2c);
  // Wc1^T = W_out1^T @ W_in1 : [512][256] into Bcat1 cols 0:256
  k_gemm_raw_n<<<dim3(4, 8), 256, 0, stream>>>(Wout1t, Win1b, 512, 512, 512,
                                               Bcat1, 512);

  // ---- layer 1 (reassociated, fp8): G1 = Mt8 @ nft8^T (M=8192,N=256,K=8192,z=8)
  k_sk128_f8<<<dim3(2, 64, 8), 256, 0, stream>>>(Mt8, nft8, 1024, NN, NN,
                                                 P1, 256, (size_t)8192 * 256);
  k_sk_reduce_sub<<<2048, 256, 0, stream>>>(P1, 256, (size_t)8192 * 256, 8,
                                            colsum, colmax, A1cat + 256, 512,
                                            A1cat, 512);
  k_g64<128, 2><<<dim3(4, 128), 256, 0, stream>>>(A1cat, Bcat1, 512, 512, 512,
                                                  C2f, 512, bias1c, nullptr);
  k_ln_relu_bf16<<<8192, 256, 0, stream>>>(C2f, 512, g1, be1, Acat2 + 256, 768);

  // ---- layer 2: T2t (bf16 + fp8) = W_in2^T@h1^T + b_in2; fp8 agg2; out2; LN
  k_g64<64, 4><<<dim3(128, 4), 256, 0, stream>>>(Win2t, Acat2 + 256, 512, 512, 768,
                                                 T2t, NN, b_in2, T2t8);
  k_sk128_f8<<<dim3(2, 64, 8), 256, 0, stream>>>(Mt8, T2t8, 1024, NN, NN,
                                                 P2, 256, (size_t)8192 * 256);
  k_sk_reduce<<<2048, 256, 0, stream>>>(P2, 256, (size_t)8192 * 256, 8,
                                        colsum, colmax, T2t, Acat2, 768);
  k_g64<64, 2><<<dim3(4, 128), 256, 0, stream>>>(Acat2, Bcat2, 768, 768, 768,
                                                 C2f, 256, bias2c, nullptr);
  k_ln_relu_f32<<<8192, 256, 0, stream>>>(C2f, 256, g2, be2, (float*)d_out, 256);
}

// Round 20
// 266.102 us; speedup vs baseline: 2.5298x; 1.0481x over previous
//
#include <hip/hip_runtime.h>
#include <stdint.h>

typedef short bf16x8 __attribute__((ext_vector_type(8)));
typedef short s16x4 __attribute__((ext_vector_type(4)));
typedef float f32x4 __attribute__((ext_vector_type(4)));
typedef unsigned int u32;
typedef unsigned char u8;

#define EPS_A 1e-8f
#define THR_A 1e-6f
#define NN 8192

static __device__ __forceinline__ short f2bf(float f) {
  u32 u = __float_as_uint(f);
  u = u + 0x7FFFu + ((u >> 16) & 1u);   // RNE, no NaN inputs here
  return (short)(u >> 16);
}
static __device__ __forceinline__ float bf2f(short s) {
  return __uint_as_float(((u32)(unsigned short)s) << 16);
}
static __device__ __forceinline__ u8 f2fp8(float v) {
  return (u8)(__builtin_amdgcn_cvt_pk_fp8_f32(v, v, 0, false) & 0xff);
}
// async global->LDS, 16B per lane; DIRECT addrspacecasts (proven round 12)
static __device__ __forceinline__ void gld16(const void* g, void* l) {
  __builtin_amdgcn_global_load_lds(
      (const __attribute__((address_space(1))) u32*)g,
      (__attribute__((address_space(3))) u32*)l, 16, 0, 0);
}

// ---- fused prep: Mt8 (fp8) transpose-cast + colsum/colmax, weight/feature casts,
//      bias folds — ONE launch, 9603 blocks
__global__ __launch_bounds__(256) void k_prep_all(
    const float* __restrict__ Mob, const float* __restrict__ nf,
    const float* __restrict__ W_in1, const float* __restrict__ W_out1,
    const float* __restrict__ W_self1, const float* __restrict__ W_in2,
    const float* __restrict__ W_out2, const float* __restrict__ W_self2,
    const float* __restrict__ b_in1, const float* __restrict__ b_out1,
    const float* __restrict__ b_self1, const float* __restrict__ b_out2,
    const float* __restrict__ b_self2,
    u8* __restrict__ Mt8, float* __restrict__ colsum, u32* __restrict__ colmax,
    u8* __restrict__ nft8, short* __restrict__ A1cat, short* __restrict__ Win1b,
    short* __restrict__ Wout1t, short* __restrict__ Bcat1, short* __restrict__ Win2t,
    short* __restrict__ Bcat2, float* __restrict__ bias1c, float* __restrict__ bias2c)
{
  __shared__ __align__(16) u32 sbuf[256 * 17];   // 17408 B, reused per block role
  int b = blockIdx.x;
  const int t = threadIdx.x;
  if (b < 4096) {                      // Mt8: transpose-cast fp8 + colsum/colmax
    const int i0 = (b & 31) * 256;
    const int j0 = (b >> 5) * 64;
    const int i = i0 + t;
    float s = 0.f, mx = 0.f;
    #pragma unroll 4
    for (int j4 = 0; j4 < 16; ++j4) {
      float v0 = Mob[(size_t)(j0 + j4 * 4 + 0) * NN + i];
      float v1 = Mob[(size_t)(j0 + j4 * 4 + 1) * NN + i];
      float v2 = Mob[(size_t)(j0 + j4 * 4 + 2) * NN + i];
      float v3 = Mob[(size_t)(j0 + j4 * 4 + 3) * NN + i];
      s += v0 + v1 + v2 + v3;
      mx = fmaxf(fmaxf(mx, fmaxf(v0, v1)), fmaxf(v2, v3));
      u32 pk = __builtin_amdgcn_cvt_pk_fp8_f32(v0, v1, 0, false);
      pk = __builtin_amdgcn_cvt_pk_fp8_f32(v2, v3, (int)pk, true);
      sbuf[t * 17 + j4] = pk;
    }
    atomicAdd(&colsum[i], s);
    atomicMax(&colmax[i], __float_as_uint(mx));  // M >= 0: uint order == float order
    __syncthreads();
    #pragma unroll
    for (int p = 0; p < 4; ++p) {               // 64 rows/pass, 4 x 16B per row
      const int r = p * 64 + (t >> 2);
      const int c = t & 3;
      const u32* src = &sbuf[r * 17 + c * 4];
      int4 w = make_int4(src[0], src[1], src[2], src[3]);
      *(int4*)&Mt8[(size_t)(i0 + r) * NN + j0 + c * 16] = w;
    }
    return;
  }
  b -= 4096;
  if (b < 512) {                       // nf^T -> fp8: LDS-tiled transpose 8192x256
    u8* tile = (u8*)sbuf;              // [64][68]
    const int r0 = (b & 127) * 64, c0 = (b >> 7) * 64;
    #pragma unroll
    for (int p = 0; p < 16; ++p) {
      const int rr = p * 4 + (t >> 6), cc = t & 63;
      tile[rr * 68 + cc] = f2fp8(nf[(size_t)(r0 + rr) * 256 + c0 + cc]);
    }
    __syncthreads();
    #pragma unroll
    for (int q = 0; q < 16; ++q) {
      const int cc = q * 4 + (t >> 6), rr = t & 63;
      nft8[(size_t)(c0 + cc) * 8192 + r0 + rr] = tile[rr * 68 + cc];
    }
    return;
  }
  b -= 512;
  if (b < 2048) {                      // nf -> A1cat cols 256:512 (bf16)
    const int idx = b * 256 + t;
    const float4 v = ((const float4*)nf)[idx];
    const int i = idx >> 6;
    const int c = (idx & 63) * 4;
    s16x4 o;
    o.x = f2bf(v.x); o.y = f2bf(v.y); o.z = f2bf(v.z); o.w = f2bf(v.w);
    *(s16x4*)&A1cat[(size_t)i * 512 + 256 + c] = o;
    return;
  }
  b -= 2048;
  if (b < 128) {                       // W_in1 straight cast 256x512
    const int idx = b * 256 + t;
    const float4 v = ((const float4*)W_in1)[idx];
    s16x4 o;
    o.x = f2bf(v.x); o.y = f2bf(v.y); o.z = f2bf(v.z); o.w = f2bf(v.w);
    *(s16x4*)&Win1b[idx * 4] = o;
    return;
  }
  b -= 128;
  if (b < 1024) {                      // W_out1^T 512x512 -> Wout1t ld 512
    const int idx = b * 256 + t;
    const int r = idx >> 9, c = idx & 511;
    Wout1t[(size_t)c * 512 + r] = f2bf(W_out1[idx]);
    return;
  }
  b -= 1024;
  if (b < 512) {                       // W_self1^T 256x512 -> Bcat1+256 ld 512
    const int idx = b * 256 + t;
    const int r = idx >> 9, c = idx & 511;
    Bcat1[(size_t)c * 512 + 256 + r] = f2bf(W_self1[idx]);
    return;
  }
  b -= 512;
  if (b < 512) {                       // W_in2^T 512x256 -> Win2t ld 512
    const int idx = b * 256 + t;
    const int r = idx >> 8, c = idx & 255;
    Win2t[(size_t)c * 512 + r] = f2bf(W_in2[idx]);
    return;
  }
  b -= 512;
  if (b < 256) {                       // W_out2^T 256x256 -> Bcat2 ld 768
    const int idx = b * 256 + t;
    const int r = idx >> 8, c = idx & 255;
    Bcat2[(size_t)c * 768 + r] = f2bf(W_out2[idx]);
    return;
  }
  b -= 256;
  if (b < 512) {                       // W_self2^T 512x256 -> Bcat2+256 ld 768
    const int idx = b * 256 + t;
    const int r = idx >> 8, c = idx & 255;
    Bcat2[(size_t)c * 768 + 256 + r] = f2bf(W_self2[idx]);
    return;
  }
  b -= 512;
  if (b < 2) {                         // bias1c = b_in1@W_out1 + b_out1 + b_self1
    const int n = b * 256 + t;
    float a = b_out1[n] + b_self1[n];
    for (int p = 0; p < 512; ++p) a += b_in1[p] * W_out1[(size_t)p * 512 + n];
    bias1c[n] = a;
    return;
  }
  bias2c[t] = b_out2[t] + b_self2[t];  // last block
}

// ---- old 64x64 reg-staged body (kept ONLY for tiny Wc1 GEMM; proven)
__global__ __launch_bounds__(256) void k_gemm_raw_n(
    const short* __restrict__ A, const short* __restrict__ B, int K, int ldA, int ldB,
    short* __restrict__ C, int ldC)
{
  constexpr int LDP = 40;
  __shared__ __align__(16) short As[64 * LDP];
  __shared__ __align__(16) short Bs[64 * LDP];
  const int t = threadIdx.x;
  const int m0 = blockIdx.y * 64, n0 = blockIdx.x * 64;
  const int wid = t >> 6, l = t & 63;
  const int wr = wid >> 1, wc = wid & 1;
  const int lr = l & 15, lk = l >> 4;
  f32x4 acc[2][2] = {};
  const int sr = t >> 2;
  const int sc = (t & 3) * 8;
  const short* gA0 = A + (size_t)(m0 + sr) * ldA + sc;
  const short* gB0 = B + (size_t)(n0 + sr) * ldB + sc;
  for (int k0 = 0; k0 < K; k0 += 32) {
    const int4 a0 = *(const int4*)(gA0 + k0);
    const int4 b0 = *(const int4*)(gB0 + k0);
    __syncthreads();
    *(int4*)&As[sr * LDP + sc] = a0;
    *(int4*)&Bs[sr * LDP + sc] = b0;
    __syncthreads();
    bf16x8 av[2], bv[2];
    #pragma unroll
    for (int mi = 0; mi < 2; ++mi)
      av[mi] = *(const bf16x8*)&As[(wr * 32 + mi * 16 + lr) * LDP + lk * 8];
    #pragma unroll
    for (int ni = 0; ni < 2; ++ni)
      bv[ni] = *(const bf16x8*)&Bs[(wc * 32 + ni * 16 + lr) * LDP + lk * 8];
    #pragma unroll
    for (int mi = 0; mi < 2; ++mi)
      #pragma unroll
      for (int ni = 0; ni < 2; ++ni)
        acc[mi][ni] = __builtin_amdgcn_mfma_f32_16x16x32_bf16(av[mi], bv[ni], acc[mi][ni], 0, 0, 0);
  }
  #pragma unroll
  for (int mi = 0; mi < 2; ++mi)
    #pragma unroll
    for (int r = 0; r < 4; ++r) {
      const int m = m0 + wr * 32 + mi * 16 + lk * 4 + r;
      #pragma unroll
      for (int ni = 0; ni < 2; ++ni) {
        const int n = n0 + wc * 32 + ni * 16 + lr;
        C[(size_t)m * ldC + n] = f2bf(acc[mi][ni][r]);
      }
    }
}

// ---- 64 x BN bf16 GEMM, BK=64, gld_lds staging, swizzled unified LDS,
// staggered K, setprio (proven r16/17).
// EPI 0: +bias0[m] bf16; EPI 2: +bias0[n] fp32; EPI 4: +bias0[m] bf16 AND fp8 copy.
template <int BN, int EPI>
__global__ __launch_bounds__(256) void k_g64(
    const short* __restrict__ A, const short* __restrict__ B, int K, int ldA, int ldB,
    void* __restrict__ Cout, int ldC, const float* __restrict__ bias0,
    u8* __restrict__ C8)
{
  constexpr int ROWS = 64 + BN;
  constexpr int CH = ROWS / 32;
  constexpr int NI = BN / 32;
  __shared__ __align__(16) short S[ROWS * 64];
  const int t = threadIdx.x;

  const int gx = gridDim.x;
  int flat = blockIdx.y * gx + blockIdx.x;
  const int cpx = (gx * gridDim.y) >> 3;
  flat = (flat & 7) * cpx + (flat >> 3);
  const int bx = flat % gx, by = flat / gx;
  const int m0 = by * 64, n0 = bx * BN;

  const int wid = t >> 6, l = t & 63;
  const int wr = wid >> 1, wc = wid & 1;
  const int lr = l & 15, lk = l >> 4;

  f32x4 acc[2][NI] = {};

  const int lrow = l >> 3, lcol = l & 7;
  const int wbase = wid * (ROWS / 4);
  short* dbase = S + wbase * 64;
  const short* gsrc[CH];
  #pragma unroll
  for (int c = 0; c < CH; ++c) {
    const int ar = wbase + c * 8 + lrow;
    const int scol = (lcol ^ (ar & 7)) * 8;
    gsrc[c] = (ar < 64) ? A + (size_t)(m0 + ar) * ldA + scol
                        : B + (size_t)(n0 + ar - 64) * ldB + scol;
  }

  const int niters = K >> 6;
  int kk = flat % niters;
  for (int it = 0; it < niters; ++it) {
    const int koff = kk << 6;
    kk = (kk + 1 == niters) ? 0 : kk + 1;
    __syncthreads();
    #pragma unroll
    for (int c = 0; c < CH; ++c)
      gld16(gsrc[c] + koff, dbase + c * 512);
    __syncthreads();

    __builtin_amdgcn_s_setprio(1);
    #pragma unroll
    for (int ks = 0; ks < 2; ++ks) {
      bf16x8 av[2], bv[NI];
      #pragma unroll
      for (int mi = 0; mi < 2; ++mi) {
        const int row = wr * 32 + mi * 16 + lr;
        av[mi] = *(const bf16x8*)&S[row * 64 + ((ks * 4 + lk) ^ (row & 7)) * 8];
      }
      #pragma unroll
      for (int ni = 0; ni < NI; ++ni) {
        const int row = 64 + wc * (BN / 2) + ni * 16 + lr;
        bv[ni] = *(const bf16x8*)&S[row * 64 + ((ks * 4 + lk) ^ (row & 7)) * 8];
      }
      #pragma unroll
      for (int mi = 0; mi < 2; ++mi)
        #pragma unroll
        for (int ni = 0; ni < NI; ++ni)
          acc[mi][ni] = __builtin_amdgcn_mfma_f32_16x16x32_bf16(av[mi], bv[ni], acc[mi][ni], 0, 0, 0);
    }
    __builtin_amdgcn_s_setprio(0);
  }

  #pragma unroll
  for (int mi = 0; mi < 2; ++mi) {
    #pragma unroll
    for (int r = 0; r < 4; ++r) {
      const int m = m0 + wr * 32 + mi * 16 + lk * 4 + r;
      float bm = 0.f;
      if (EPI == 0 || EPI == 4) bm = bias0[m];
      #pragma unroll
      for (int ni = 0; ni < NI; ++ni) {
        const int n = n0 + wc * (BN / 2) + ni * 16 + lr;
        float v = acc[mi][ni][r];
        if (EPI == 0 || EPI == 4) {
          v += bm;
          ((short*)Cout)[(size_t)m * ldC + n] = f2bf(v);
          if (EPI == 4) C8[(size_t)m * ldC + n] = f2fp8(v);
        } else {
          ((float*)Cout)[(size_t)m * ldC + n] = v + bias0[n];
        }
      }
    }
  }
}

// ---- 128x128 split-K fp8 GEMM, BK=64 bytes, DOUBLE-BUFFERED gld_lds staging
// with counted vmcnt(4) + raw s_barrier (T4): load latency hides under compute.
// LDS S[2][16KB]: As @0, Bs @8192 per buffer; logical 16B-slot q at q^(row&3).
__global__ __launch_bounds__(256) void k_sk128_f8(
    const u8* __restrict__ A, const u8* __restrict__ B, int K, int ldA, int ldB,
    short* __restrict__ P, int ldC, size_t pstride)
{
  __shared__ __align__(16) u8 S[2][16384];   // 32 KB total
  const int t = threadIdx.x;

  const int sk = blockIdx.z;
  A += (size_t)sk * K;
  B += (size_t)sk * K;

  const int gx = gridDim.x;
  int flat = blockIdx.y * gx + blockIdx.x;
  const int cpx = (gx * gridDim.y) >> 3;
  flat = (flat & 7) * cpx + (flat >> 3);
  const int bx = flat % gx, by = flat / gx;
  const int m0 = by * 128, n0 = bx * 128;

  const int wid = t >> 6, l = t & 63;
  const int wr = wid >> 1, wc = wid & 1;
  const int lr = l & 15, lk = l >> 4;      // lk = k-group 0..3 (8B each)

  f32x4 acc[4][4] = {};

  // staging: waves 0,1 -> As halves; waves 2,3 -> Bs halves. 4 chunks x 1KB/wave.
  const int side = wid >> 1;
  const int hrow = (wid & 1) * 64;
  const u8* Xp = side ? B : A;
  const int ldX = side ? ldB : ldA;
  const int x0 = side ? n0 : m0;
  const int doff = side * 8192 + hrow * 64;     // wave-uniform offset within buffer
  u8* d0 = &S[0][doff];
  u8* d1 = &S[1][doff];
  const u8* gsrc[4];
  #pragma unroll
  for (int c = 0; c < 4; ++c) {
    const int row = hrow + c * 16 + (l >> 2);
    const int ql = (l & 3) ^ (row & 3);
    gsrc[c] = Xp + (size_t)(x0 + row) * ldX + ql * 16;
  }

  const int niters = K >> 6;               // 16 for K=1024
  int kk = (flat + sk * 3) & (niters - 1); // staggered start
  // prologue: issue tile 0 into buffer 0
  {
    const int koff = kk << 6;
    kk = (kk + 1) & (niters - 1);
    gld16(gsrc[0] + koff, d0);
    gld16(gsrc[1] + koff, d0 + 1024);
    gld16(gsrc[2] + koff, d0 + 2048);
    gld16(gsrc[3] + koff, d0 + 3072);
  }

  int buf = 0;
  for (int it = 0; it < niters; ++it) {
    if (it + 1 < niters) {
      const int koff = kk << 6;
      kk = (kk + 1) & (niters - 1);
      u8* nb = buf ? d0 : d1;              // next buffer's wave region
      gld16(gsrc[0] + koff, nb);
      gld16(gsrc[1] + koff, nb + 1024);
      gld16(gsrc[2] + koff, nb + 2048);
      gld16(gsrc[3] + koff, nb + 3072);
      asm volatile("s_waitcnt vmcnt(4)" ::: "memory");  // current tile's 4 done
    } else {
      asm volatile("s_waitcnt vmcnt(0)" ::: "memory");  // final tile drain
    }
    __builtin_amdgcn_sched_barrier(0);     // rule #18: pin ds_reads after wait
    __builtin_amdgcn_s_barrier();          // raw: all waves' current tile ready

    const u8* Ab = &S[buf][0];
    const u8* Bb = &S[buf][8192];
    __builtin_amdgcn_s_setprio(1);
    #pragma unroll
    for (int ks = 0; ks < 2; ++ks) {       // 32-byte k-slices
      const int q = ks * 2 + (lk >> 1);    // logical 16B slot
      const int inner = (lk & 1) * 8;
      long av[4], bv[4];
      #pragma unroll
      for (int mi = 0; mi < 4; ++mi) {
        const int row = wr * 64 + mi * 16 + lr;
        av[mi] = *(const long*)&Ab[row * 64 + ((q ^ (row & 3)) << 4) + inner];
      }
      #pragma unroll
      for (int ni = 0; ni < 4; ++ni) {
        const int row = wc * 64 + ni * 16 + lr;
        bv[ni] = *(const long*)&Bb[row * 64 + ((q ^ (row & 3)) << 4) + inner];
      }
      #pragma unroll
      for (int mi = 0; mi < 4; ++mi)
        #pragma unroll
        for (int ni = 0; ni < 4; ++ni)
          acc[mi][ni] = __builtin_amdgcn_mfma_f32_16x16x32_fp8_fp8(av[mi], bv[ni], acc[mi][ni], 0, 0, 0);
    }
    __builtin_amdgcn_s_setprio(0);
    __builtin_amdgcn_s_barrier();          // raw: all waves done reading buf
    buf ^= 1;
  }

  short* outp = P + pstride * sk;
  #pragma unroll
  for (int mi = 0; mi < 4; ++mi) {
    #pragma unroll
    for (int r = 0; r < 4; ++r) {
      const int m = m0 + wr * 64 + mi * 16 + lk * 4 + r;
      #pragma unroll
      for (int ni = 0; ni < 4; ++ni) {
        const int n = n0 + wc * 64 + ni * 16 + lr;
        outp[(size_t)m * ldC + n] = f2bf(acc[mi][ni][r]);
      }
    }
  }
}

// ---- reduce S partials + normalize; fallback substitutes raw h row (coalesced)
__global__ __launch_bounds__(256) void k_sk_reduce_sub(
    const short* __restrict__ P, int N, size_t pstride, int S,
    const float* __restrict__ colsum, const u32* __restrict__ colmax,
    const short* __restrict__ hraw, int ldh,
    short* __restrict__ out, int ldo)
{
  const int idx = blockIdx.x * 256 + threadIdx.x;
  const int nq = N >> 2;
  const int m = idx / nq;
  const int c4 = (idx - m * nq) * 4;
  const size_t base = (size_t)m * N + c4;
  float a0 = 0.f, a1 = 0.f, a2 = 0.f, a3 = 0.f;
  for (int s = 0; s < S; ++s) {
    s16x4 v = *(const s16x4*)&P[pstride * s + base];
    a0 += bf2f(v.x); a1 += bf2f(v.y); a2 += bf2f(v.z); a3 += bf2f(v.w);
  }
  const float cs = colsum[m];
  const float rc = 1.f / (cs + EPS_A);
  const float rcw = rc / (cs * rc + EPS_A);
  const bool he = __uint_as_float(colmax[m]) * rc > THR_A;
  s16x4 o;
  if (he) {
    o.x = f2bf(a0 * rcw); o.y = f2bf(a1 * rcw);
    o.z = f2bf(a2 * rcw); o.w = f2bf(a3 * rcw);
  } else {
    o = *(const s16x4*)&hraw[(size_t)m * ldh + c4];
  }
  *(s16x4*)&out[(size_t)m * ldo + c4] = o;
}

// ---- reduce S partials + normalize; fallback gathers bf16 T^T (rare, ballot-skip)
__global__ __launch_bounds__(256) void k_sk_reduce(
    const short* __restrict__ P, int N, size_t pstride, int S,
    const float* __restrict__ colsum, const u32* __restrict__ colmax,
    const short* __restrict__ Tfall, short* __restrict__ out, int ldo)
{
  const int idx = blockIdx.x * 256 + threadIdx.x;
  const int nq = N >> 2;
  const int m = idx / nq;
  const int c4 = (idx - m * nq) * 4;
  const size_t base = (size_t)m * N + c4;
  float a0 = 0.f, a1 = 0.f, a2 = 0.f, a3 = 0.f;
  for (int s = 0; s < S; ++s) {
    s16x4 v = *(const s16x4*)&P[pstride * s + base];
    a0 += bf2f(v.x); a1 += bf2f(v.y); a2 += bf2f(v.z); a3 += bf2f(v.w);
  }
  const float cs = colsum[m];
  const float rc = 1.f / (cs + EPS_A);
  const float rcw = rc / (cs * rc + EPS_A);
  const bool he = __uint_as_float(colmax[m]) * rc > THR_A;
  a0 *= rcw; a1 *= rcw; a2 *= rcw; a3 *= rcw;
  if (__ballot(!he)) {
    if (!he) {
      a0 = bf2f(Tfall[(size_t)(c4 + 0) * NN + m]);
      a1 = bf2f(Tfall[(size_t)(c4 + 1) * NN + m]);
      a2 = bf2f(Tfall[(size_t)(c4 + 2) * NN + m]);
      a3 = bf2f(Tfall[(size_t)(c4 + 3) * NN + m]);
    }
  }
  s16x4 o;
  o.x = f2bf(a0); o.y = f2bf(a1); o.z = f2bf(a2); o.w = f2bf(a3);
  *(s16x4*)&out[(size_t)m * ldo + c4] = o;
}

// ---- row LayerNorm + ReLU, fp32 in.  MODE 0: bf16 out (ld-strided), MODE 1: fp32 out
template <int MODE>
__device__ __forceinline__ void ln_relu_body(
    const float* __restrict__ X, int W,
    const float* __restrict__ g, const float* __restrict__ be,
    void* __restrict__ out, int ldo)
{
  const int row = blockIdx.x;
  const int t = threadIdx.x;
  const float* x = X + (size_t)row * W;
  float v0 = x[t], v1 = 0.f;
  float s = v0, ss = v0 * v0;
  if (W == 512) { v1 = x[t + 256]; s += v1; ss += v1 * v1; }
  #pragma unroll
  for (int off = 32; off; off >>= 1) {
    s += __shfl_down(s, off);
    ss += __shfl_down(ss, off);
  }
  __shared__ float red[8];
  const int wid = t >> 6;
  if ((t & 63) == 0) { red[wid] = s; red[4 + wid] = ss; }
  __syncthreads();
  s = red[0] + red[1] + red[2] + red[3];
  ss = red[4] + red[5] + red[6] + red[7];
  const float mu = s / W;
  const float var = ss / W - mu * mu;
  const float sc = rsqrtf(var + 1e-5f);
  float y = fmaxf((v0 - mu) * sc * g[t] + be[t], 0.f);
  if (MODE == 0) ((short*)out)[(size_t)row * ldo + t] = f2bf(y);
  else           ((float*)out)[(size_t)row * ldo + t] = y;
  if (W == 512) {
    float y1 = fmaxf((v1 - mu) * sc * g[t + 256] + be[t + 256], 0.f);
    if (MODE == 0) ((short*)out)[(size_t)row * ldo + t + 256] = f2bf(y1);
    else           ((float*)out)[(size_t)row * ldo + t + 256] = y1;
  }
}

__global__ __launch_bounds__(256) void k_ln_relu_bf16(
    const float* __restrict__ X, int W, const float* __restrict__ g,
    const float* __restrict__ be, short* __restrict__ out, int ldo) {
  ln_relu_body<0>(X, W, g, be, out, ldo);
}
__global__ __launch_bounds__(256) void k_ln_relu_f32(
    const float* __restrict__ X, int W, const float* __restrict__ g,
    const float* __restrict__ be, float* __restrict__ out, int ldo) {
  ln_relu_body<1>(X, W, g, be, out, ldo);
}

extern "C" void kernel_launch(void* const* d_in, const int* in_sizes, int n_in,
                              void* d_out, int out_size, void* d_ws, size_t ws_size,
                              hipStream_t stream) {
  const float* nf      = (const float*)d_in[0];
  const float* Mob     = (const float*)d_in[1];
  const float* W_in1   = (const float*)d_in[2];
  const float* b_in1   = (const float*)d_in[3];
  const float* W_out1  = (const float*)d_in[4];
  const float* b_out1  = (const float*)d_in[5];
  const float* W_self1 = (const float*)d_in[6];
  const float* b_self1 = (const float*)d_in[7];
  const float* g1      = (const float*)d_in[8];
  const float* be1     = (const float*)d_in[9];
  const float* W_in2   = (const float*)d_in[10];
  const float* b_in2   = (const float*)d_in[11];
  const float* W_out2  = (const float*)d_in[12];
  const float* b_out2  = (const float*)d_in[13];
  const float* W_self2 = (const float*)d_in[14];
  const float* b_self2 = (const float*)d_in[15];
  const float* g2      = (const float*)d_in[16];
  const float* be2     = (const float*)d_in[17];

  char* ws = (char*)d_ws;
  float* colsum = (float*)(ws);                       // 32 KB
  u32*   colmax = (u32*)(ws + 32768);                 // 32 KB
  u8*    Mt8    = (u8*)(ws + 131072);                 // [8192][8192] fp8 = 67 MB
  u8*    nft8   = (u8*)(ws + 67239936);               // [256][8192] fp8
  u8*    T2t8   = (u8*)(ws + 69337088);               // [256][8192] fp8
  short* A1cat  = (short*)(ws + 71434240);            // [8192][512]: [A1|nf]
  float* C2f    = (float*)(ws + 79822848);            // [8192][512] f32
  short* Acat2  = (short*)(ws + 96600064);            // [8192][768]: [agg2|h1]
  short* T2t    = (short*)(ws + 109182976);           // [256][8192] bf16 (fallback)
  short* Bcat1  = (short*)(ws + 113377280);           // [512][512]: [Wc1^T|Wself1^T]
  short* Bcat2  = (short*)(ws + 113901568);           // [256][768]
  short* Win2t  = (short*)(ws + 114294784);           // [256][512]
  short* Wout1t = (short*)(ws + 114556928);           // [512][512]
  short* Win1b  = (short*)(ws + 115081216);           // [256][512]
  float* bias1c = (float*)(ws + 115343360);           // [512]
  float* bias2c = (float*)(ws + 115345408);           // [256]
  short* P1     = (short*)(ws + 117440512);           // 8 x [8192][256] bf16
  short* P2     = (short*)(ws + 150994944);           // 8 x [8192][256] bf16

  hipMemsetAsync(ws, 0, 65536, stream);  // zero colsum + colmax every call

  k_prep_all<<<9603, 256, 0, stream>>>(Mob, nf, W_in1, W_out1, W_self1, W_in2,
                                       W_out2, W_self2, b_in1, b_out1, b_self1,
                                       b_out2, b_self2, Mt8, colsum, colmax, nft8,
                                       A1cat, Win1b, Wout1t, Bcat1, Win2t, Bcat2,
                                       bias1c, bias2c);
  // Wc1^T = W_out1^T @ W_in1 : [512][256] into Bcat1 cols 0:256
  k_gemm_raw_n<<<dim3(4, 8), 256, 0, stream>>>(Wout1t, Win1b, 512, 512, 512,
                                               Bcat1, 512);

  // ---- layer 1 (reassociated, fp8): G1 = Mt8 @ nft8^T (M=8192,N=256,K=8192,z=8)
  k_sk128_f8<<<dim3(2, 64, 8), 256, 0, stream>>>(Mt8, nft8, 1024, NN, NN,
                                                 P1, 256, (size_t)8192 * 256);
  k_sk_reduce_sub<<<2048, 256, 0, stream>>>(P1, 256, (size_t)8192 * 256, 8,
                                            colsum, colmax, A1cat + 256, 512,
                                            A1cat, 512);
  k_g64<128, 2><<<dim3(4, 128), 256, 0, stream>>>(A1cat, Bcat1, 512, 512, 512,
                                                  C2f, 512, bias1c, nullptr);
  k_ln_relu_bf16<<<8192, 256, 0, stream>>>(C2f, 512, g1, be1, Acat2 + 256, 768);

  // ---- layer 2: T2t (bf16 + fp8) = W_in2^T@h1^T + b_in2; fp8 agg2; out2; LN
  k_g64<64, 4><<<dim3(128, 4), 256, 0, stream>>>(Win2t, Acat2 + 256, 512, 512, 768,
                                                 T2t, NN, b_in2, T2t8);
  k_sk128_f8<<<dim3(2, 64, 8), 256, 0, stream>>>(Mt8, T2t8, 1024, NN, NN,
                                                 P2, 256, (size_t)8192 * 256);
  k_sk_reduce<<<2048, 256, 0, stream>>>(P2, 256, (size_t)8192 * 256, 8,
                                        colsum, colmax, T2t, Acat2, 768);
  k_g64<64, 2><<<dim3(4, 128), 256, 0, stream>>>(Acat2, Bcat2, 768, 768, 768,
                                                 C2f, 256, bias2c, nullptr);
  k_ln_relu_f32<<<8192, 256, 0, stream>>>(C2f, 256, g2, be2, (float*)d_out, 256);
}

// Round 21
// 263.318 us; speedup vs baseline: 2.5565x; 1.0106x over previous
//
#include <hip/hip_runtime.h>
#include <stdint.h>

typedef short bf16x8 __attribute__((ext_vector_type(8)));
typedef short s16x4 __attribute__((ext_vector_type(4)));
typedef float f32x4 __attribute__((ext_vector_type(4)));
typedef unsigned int u32;
typedef unsigned char u8;

#define EPS_A 1e-8f
#define THR_A 1e-6f
#define NN 8192

static __device__ __forceinline__ short f2bf(float f) {
  u32 u = __float_as_uint(f);
  u = u + 0x7FFFu + ((u >> 16) & 1u);   // RNE, no NaN inputs here
  return (short)(u >> 16);
}
static __device__ __forceinline__ float bf2f(short s) {
  return __uint_as_float(((u32)(unsigned short)s) << 16);
}
static __device__ __forceinline__ u8 f2fp8(float v) {
  return (u8)(__builtin_amdgcn_cvt_pk_fp8_f32(v, v, 0, false) & 0xff);
}
// async global->LDS, 16B per lane; DIRECT addrspacecasts (proven round 12)
static __device__ __forceinline__ void gld16(const void* g, void* l) {
  __builtin_amdgcn_global_load_lds(
      (const __attribute__((address_space(1))) u32*)g,
      (__attribute__((address_space(3))) u32*)l, 16, 0, 0);
}

// ---- fused prep: Mt8 (fp8) transpose-cast + colsum/colmax, weight/feature casts,
//      bias folds — ONE launch, 9603 blocks
__global__ __launch_bounds__(256) void k_prep_all(
    const float* __restrict__ Mob, const float* __restrict__ nf,
    const float* __restrict__ W_in1, const float* __restrict__ W_out1,
    const float* __restrict__ W_self1, const float* __restrict__ W_in2,
    const float* __restrict__ W_out2, const float* __restrict__ W_self2,
    const float* __restrict__ b_in1, const float* __restrict__ b_out1,
    const float* __restrict__ b_self1, const float* __restrict__ b_out2,
    const float* __restrict__ b_self2,
    u8* __restrict__ Mt8, float* __restrict__ colsum, u32* __restrict__ colmax,
    u8* __restrict__ nft8, short* __restrict__ A1cat, short* __restrict__ Win1b,
    short* __restrict__ Wout1t, short* __restrict__ Bcat1, short* __restrict__ Win2t,
    short* __restrict__ Bcat2, float* __restrict__ bias1c, float* __restrict__ bias2c)
{
  __shared__ __align__(16) u32 sbuf[256 * 17];   // 17408 B, reused per block role
  int b = blockIdx.x;
  const int t = threadIdx.x;
  if (b < 4096) {                      // Mt8: transpose-cast fp8 + colsum/colmax
    const int i0 = (b & 31) * 256;
    const int j0 = (b >> 5) * 64;
    const int i = i0 + t;
    float s = 0.f, mx = 0.f;
    #pragma unroll 4
    for (int j4 = 0; j4 < 16; ++j4) {
      float v0 = Mob[(size_t)(j0 + j4 * 4 + 0) * NN + i];
      float v1 = Mob[(size_t)(j0 + j4 * 4 + 1) * NN + i];
      float v2 = Mob[(size_t)(j0 + j4 * 4 + 2) * NN + i];
      float v3 = Mob[(size_t)(j0 + j4 * 4 + 3) * NN + i];
      s += v0 + v1 + v2 + v3;
      mx = fmaxf(fmaxf(mx, fmaxf(v0, v1)), fmaxf(v2, v3));
      u32 pk = __builtin_amdgcn_cvt_pk_fp8_f32(v0, v1, 0, false);
      pk = __builtin_amdgcn_cvt_pk_fp8_f32(v2, v3, (int)pk, true);
      sbuf[t * 17 + j4] = pk;
    }
    atomicAdd(&colsum[i], s);
    atomicMax(&colmax[i], __float_as_uint(mx));  // M >= 0: uint order == float order
    __syncthreads();
    #pragma unroll
    for (int p = 0; p < 4; ++p) {               // 64 rows/pass, 4 x 16B per row
      const int r = p * 64 + (t >> 2);
      const int c = t & 3;
      const u32* src = &sbuf[r * 17 + c * 4];
      int4 w = make_int4(src[0], src[1], src[2], src[3]);
      *(int4*)&Mt8[(size_t)(i0 + r) * NN + j0 + c * 16] = w;
    }
    return;
  }
  b -= 4096;
  if (b < 512) {                       // nf^T -> fp8: LDS-tiled transpose 8192x256
    u8* tile = (u8*)sbuf;              // [64][68]
    const int r0 = (b & 127) * 64, c0 = (b >> 7) * 64;
    #pragma unroll
    for (int p = 0; p < 16; ++p) {
      const int rr = p * 4 + (t >> 6), cc = t & 63;
      tile[rr * 68 + cc] = f2fp8(nf[(size_t)(r0 + rr) * 256 + c0 + cc]);
    }
    __syncthreads();
    #pragma unroll
    for (int q = 0; q < 16; ++q) {
      const int cc = q * 4 + (t >> 6), rr = t & 63;
      nft8[(size_t)(c0 + cc) * 8192 + r0 + rr] = tile[rr * 68 + cc];
    }
    return;
  }
  b -= 512;
  if (b < 2048) {                      // nf -> A1cat cols 256:512 (bf16)
    const int idx = b * 256 + t;
    const float4 v = ((const float4*)nf)[idx];
    const int i = idx >> 6;
    const int c = (idx & 63) * 4;
    s16x4 o;
    o.x = f2bf(v.x); o.y = f2bf(v.y); o.z = f2bf(v.z); o.w = f2bf(v.w);
    *(s16x4*)&A1cat[(size_t)i * 512 + 256 + c] = o;
    return;
  }
  b -= 2048;
  if (b < 128) {                       // W_in1 straight cast 256x512
    const int idx = b * 256 + t;
    const float4 v = ((const float4*)W_in1)[idx];
    s16x4 o;
    o.x = f2bf(v.x); o.y = f2bf(v.y); o.z = f2bf(v.z); o.w = f2bf(v.w);
    *(s16x4*)&Win1b[idx * 4] = o;
    return;
  }
  b -= 128;
  if (b < 1024) {                      // W_out1^T 512x512 -> Wout1t ld 512
    const int idx = b * 256 + t;
    const int r = idx >> 9, c = idx & 511;
    Wout1t[(size_t)c * 512 + r] = f2bf(W_out1[idx]);
    return;
  }
  b -= 1024;
  if (b < 512) {                       // W_self1^T 256x512 -> Bcat1+256 ld 512
    const int idx = b * 256 + t;
    const int r = idx >> 9, c = idx & 511;
    Bcat1[(size_t)c * 512 + 256 + r] = f2bf(W_self1[idx]);
    return;
  }
  b -= 512;
  if (b < 512) {                       // W_in2^T 512x256 -> Win2t ld 512
    const int idx = b * 256 + t;
    const int r = idx >> 8, c = idx & 255;
    Win2t[(size_t)c * 512 + r] = f2bf(W_in2[idx]);
    return;
  }
  b -= 512;
  if (b < 256) {                       // W_out2^T 256x256 -> Bcat2 ld 768
    const int idx = b * 256 + t;
    const int r = idx >> 8, c = idx & 255;
    Bcat2[(size_t)c * 768 + r] = f2bf(W_out2[idx]);
    return;
  }
  b -= 256;
  if (b < 512) {                       // W_self2^T 512x256 -> Bcat2+256 ld 768
    const int idx = b * 256 + t;
    const int r = idx >> 8, c = idx & 255;
    Bcat2[(size_t)c * 768 + 256 + r] = f2bf(W_self2[idx]);
    return;
  }
  b -= 512;
  if (b < 2) {                         // bias1c = b_in1@W_out1 + b_out1 + b_self1
    const int n = b * 256 + t;
    float a = b_out1[n] + b_self1[n];
    for (int p = 0; p < 512; ++p) a += b_in1[p] * W_out1[(size_t)p * 512 + n];
    bias1c[n] = a;
    return;
  }
  bias2c[t] = b_out2[t] + b_self2[t];  // last block
}

// ---- old 64x64 reg-staged body (kept ONLY for tiny Wc1 GEMM; proven)
__global__ __launch_bounds__(256) void k_gemm_raw_n(
    const short* __restrict__ A, const short* __restrict__ B, int K, int ldA, int ldB,
    short* __restrict__ C, int ldC)
{
  constexpr int LDP = 40;
  __shared__ __align__(16) short As[64 * LDP];
  __shared__ __align__(16) short Bs[64 * LDP];
  const int t = threadIdx.x;
  const int m0 = blockIdx.y * 64, n0 = blockIdx.x * 64;
  const int wid = t >> 6, l = t & 63;
  const int wr = wid >> 1, wc = wid & 1;
  const int lr = l & 15, lk = l >> 4;
  f32x4 acc[2][2] = {};
  const int sr = t >> 2;
  const int sc = (t & 3) * 8;
  const short* gA0 = A + (size_t)(m0 + sr) * ldA + sc;
  const short* gB0 = B + (size_t)(n0 + sr) * ldB + sc;
  for (int k0 = 0; k0 < K; k0 += 32) {
    const int4 a0 = *(const int4*)(gA0 + k0);
    const int4 b0 = *(const int4*)(gB0 + k0);
    __syncthreads();
    *(int4*)&As[sr * LDP + sc] = a0;
    *(int4*)&Bs[sr * LDP + sc] = b0;
    __syncthreads();
    bf16x8 av[2], bv[2];
    #pragma unroll
    for (int mi = 0; mi < 2; ++mi)
      av[mi] = *(const bf16x8*)&As[(wr * 32 + mi * 16 + lr) * LDP + lk * 8];
    #pragma unroll
    for (int ni = 0; ni < 2; ++ni)
      bv[ni] = *(const bf16x8*)&Bs[(wc * 32 + ni * 16 + lr) * LDP + lk * 8];
    #pragma unroll
    for (int mi = 0; mi < 2; ++mi)
      #pragma unroll
      for (int ni = 0; ni < 2; ++ni)
        acc[mi][ni] = __builtin_amdgcn_mfma_f32_16x16x32_bf16(av[mi], bv[ni], acc[mi][ni], 0, 0, 0);
  }
  #pragma unroll
  for (int mi = 0; mi < 2; ++mi)
    #pragma unroll
    for (int r = 0; r < 4; ++r) {
      const int m = m0 + wr * 32 + mi * 16 + lk * 4 + r;
      #pragma unroll
      for (int ni = 0; ni < 2; ++ni) {
        const int n = n0 + wc * 32 + ni * 16 + lr;
        C[(size_t)m * ldC + n] = f2bf(acc[mi][ni][r]);
      }
    }
}

// ---- 64 x BN bf16 GEMM, BK=64, DOUBLE-BUFFERED gld_lds staging (T4: counted
// vmcnt + raw s_barrier), swizzled unified LDS, staggered K, setprio.
// EPI 0: +bias0[m] bf16; EPI 2: +bias0[n] fp32; EPI 4: +bias0[m] bf16 AND fp8 copy.
template <int BN, int EPI>
__global__ __launch_bounds__(256) void k_g64(
    const short* __restrict__ A, const short* __restrict__ B, int K, int ldA, int ldB,
    void* __restrict__ Cout, int ldC, const float* __restrict__ bias0,
    u8* __restrict__ C8)
{
  constexpr int ROWS = 64 + BN;
  constexpr int CH = ROWS / 32;             // chunks per wave (8 rows each)
  constexpr int NI = BN / 32;
  __shared__ __align__(16) short S[2][ROWS * 64];
  const int t = threadIdx.x;

  const int gx = gridDim.x;
  int flat = blockIdx.y * gx + blockIdx.x;
  const int cpx = (gx * gridDim.y) >> 3;
  flat = (flat & 7) * cpx + (flat >> 3);
  const int bx = flat % gx, by = flat / gx;
  const int m0 = by * 64, n0 = bx * BN;

  const int wid = t >> 6, l = t & 63;
  const int wr = wid >> 1, wc = wid & 1;
  const int lr = l & 15, lk = l >> 4;

  f32x4 acc[2][NI] = {};

  const int lrow = l >> 3, lcol = l & 7;
  const int wbase = wid * (ROWS / 4);
  short* d0 = &S[0][wbase * 64];            // wave-uniform LDS bases
  short* d1 = &S[1][wbase * 64];
  const short* gsrc[CH];
  #pragma unroll
  for (int c = 0; c < CH; ++c) {
    const int ar = wbase + c * 8 + lrow;    // chunk wholly A or wholly B (8-aligned)
    const int scol = (lcol ^ (ar & 7)) * 8;
    gsrc[c] = (ar < 64) ? A + (size_t)(m0 + ar) * ldA + scol
                        : B + (size_t)(n0 + ar - 64) * ldB + scol;
  }

  const int niters = K >> 6;                // 8 or 12
  int kk = flat % niters;                   // staggered start
  // prologue: tile 0 -> buffer 0
  {
    const int koff = kk << 6;
    kk = (kk + 1 == niters) ? 0 : kk + 1;
    #pragma unroll
    for (int c = 0; c < CH; ++c)
      gld16(gsrc[c] + koff, d0 + c * 512);
  }

  int buf = 0;
  for (int it = 0; it < niters; ++it) {
    if (it + 1 < niters) {
      const int koff = kk << 6;
      kk = (kk + 1 == niters) ? 0 : kk + 1;
      short* nb = buf ? d0 : d1;
      #pragma unroll
      for (int c = 0; c < CH; ++c)
        gld16(gsrc[c] + koff, nb + c * 512);
      if constexpr (CH == 6)
        asm volatile("s_waitcnt vmcnt(6)" ::: "memory");
      else
        asm volatile("s_waitcnt vmcnt(4)" ::: "memory");
    } else {
      asm volatile("s_waitcnt vmcnt(0)" ::: "memory");
    }
    __builtin_amdgcn_sched_barrier(0);      // rule #18: pin LDS reads after wait
    __builtin_amdgcn_s_barrier();           // all waves' current tile ready

    const short* Sb = S[buf];
    __builtin_amdgcn_s_setprio(1);
    #pragma unroll
    for (int ks = 0; ks < 2; ++ks) {
      bf16x8 av[2], bv[NI];
      #pragma unroll
      for (int mi = 0; mi < 2; ++mi) {
        const int row = wr * 32 + mi * 16 + lr;
        av[mi] = *(const bf16x8*)&Sb[row * 64 + ((ks * 4 + lk) ^ (row & 7)) * 8];
      }
      #pragma unroll
      for (int ni = 0; ni < NI; ++ni) {
        const int row = 64 + wc * (BN / 2) + ni * 16 + lr;
        bv[ni] = *(const bf16x8*)&Sb[row * 64 + ((ks * 4 + lk) ^ (row & 7)) * 8];
      }
      #pragma unroll
      for (int mi = 0; mi < 2; ++mi)
        #pragma unroll
        for (int ni = 0; ni < NI; ++ni)
          acc[mi][ni] = __builtin_amdgcn_mfma_f32_16x16x32_bf16(av[mi], bv[ni], acc[mi][ni], 0, 0, 0);
    }
    __builtin_amdgcn_s_setprio(0);
    __builtin_amdgcn_s_barrier();           // all waves done reading buf
    buf ^= 1;
  }

  #pragma unroll
  for (int mi = 0; mi < 2; ++mi) {
    #pragma unroll
    for (int r = 0; r < 4; ++r) {
      const int m = m0 + wr * 32 + mi * 16 + lk * 4 + r;
      float bm = 0.f;
      if (EPI == 0 || EPI == 4) bm = bias0[m];
      #pragma unroll
      for (int ni = 0; ni < NI; ++ni) {
        const int n = n0 + wc * (BN / 2) + ni * 16 + lr;
        float v = acc[mi][ni][r];
        if (EPI == 0 || EPI == 4) {
          v += bm;
          ((short*)Cout)[(size_t)m * ldC + n] = f2bf(v);
          if (EPI == 4) C8[(size_t)m * ldC + n] = f2fp8(v);
        } else {
          ((float*)Cout)[(size_t)m * ldC + n] = v + bias0[n];
        }
      }
    }
  }
}

// ---- 128x128 split-K fp8 GEMM, BK=64 bytes, DOUBLE-BUFFERED gld_lds staging
// with counted vmcnt(4) + raw s_barrier (T4, proven r20).
// LDS S[2][16KB]: As @0, Bs @8192 per buffer; logical 16B-slot q at q^(row&3).
__global__ __launch_bounds__(256) void k_sk128_f8(
    const u8* __restrict__ A, const u8* __restrict__ B, int K, int ldA, int ldB,
    short* __restrict__ P, int ldC, size_t pstride)
{
  __shared__ __align__(16) u8 S[2][16384];   // 32 KB total
  const int t = threadIdx.x;

  const int sk = blockIdx.z;
  A += (size_t)sk * K;
  B += (size_t)sk * K;

  const int gx = gridDim.x;
  int flat = blockIdx.y * gx + blockIdx.x;
  const int cpx = (gx * gridDim.y) >> 3;
  flat = (flat & 7) * cpx + (flat >> 3);
  const int bx = flat % gx, by = flat / gx;
  const int m0 = by * 128, n0 = bx * 128;

  const int wid = t >> 6, l = t & 63;
  const int wr = wid >> 1, wc = wid & 1;
  const int lr = l & 15, lk = l >> 4;      // lk = k-group 0..3 (8B each)

  f32x4 acc[4][4] = {};

  const int side = wid >> 1;
  const int hrow = (wid & 1) * 64;
  const u8* Xp = side ? B : A;
  const int ldX = side ? ldB : ldA;
  const int x0 = side ? n0 : m0;
  const int doff = side * 8192 + hrow * 64;     // wave-uniform offset within buffer
  u8* d0 = &S[0][doff];
  u8* d1 = &S[1][doff];
  const u8* gsrc[4];
  #pragma unroll
  for (int c = 0; c < 4; ++c) {
    const int row = hrow + c * 16 + (l >> 2);
    const int ql = (l & 3) ^ (row & 3);
    gsrc[c] = Xp + (size_t)(x0 + row) * ldX + ql * 16;
  }

  const int niters = K >> 6;               // 16 for K=1024
  int kk = (flat + sk * 3) & (niters - 1); // staggered start
  // prologue: issue tile 0 into buffer 0
  {
    const int koff = kk << 6;
    kk = (kk + 1) & (niters - 1);
    gld16(gsrc[0] + koff, d0);
    gld16(gsrc[1] + koff, d0 + 1024);
    gld16(gsrc[2] + koff, d0 + 2048);
    gld16(gsrc[3] + koff, d0 + 3072);
  }

  int buf = 0;
  for (int it = 0; it < niters; ++it) {
    if (it + 1 < niters) {
      const int koff = kk << 6;
      kk = (kk + 1) & (niters - 1);
      u8* nb = buf ? d0 : d1;              // next buffer's wave region
      gld16(gsrc[0] + koff, nb);
      gld16(gsrc[1] + koff, nb + 1024);
      gld16(gsrc[2] + koff, nb + 2048);
      gld16(gsrc[3] + koff, nb + 3072);
      asm volatile("s_waitcnt vmcnt(4)" ::: "memory");  // current tile's 4 done
    } else {
      asm volatile("s_waitcnt vmcnt(0)" ::: "memory");  // final tile drain
    }
    __builtin_amdgcn_sched_barrier(0);     // rule #18: pin ds_reads after wait
    __builtin_amdgcn_s_barrier();          // raw: all waves' current tile ready

    const u8* Ab = &S[buf][0];
    const u8* Bb = &S[buf][8192];
    __builtin_amdgcn_s_setprio(1);
    #pragma unroll
    for (int ks = 0; ks < 2; ++ks) {       // 32-byte k-slices
      const int q = ks * 2 + (lk >> 1);    // logical 16B slot
      const int inner = (lk & 1) * 8;
      long av[4], bv[4];
      #pragma unroll
      for (int mi = 0; mi < 4; ++mi) {
        const int row = wr * 64 + mi * 16 + lr;
        av[mi] = *(const long*)&Ab[row * 64 + ((q ^ (row & 3)) << 4) + inner];
      }
      #pragma unroll
      for (int ni = 0; ni < 4; ++ni) {
        const int row = wc * 64 + ni * 16 + lr;
        bv[ni] = *(const long*)&Bb[row * 64 + ((q ^ (row & 3)) << 4) + inner];
      }
      #pragma unroll
      for (int mi = 0; mi < 4; ++mi)
        #pragma unroll
        for (int ni = 0; ni < 4; ++ni)
          acc[mi][ni] = __builtin_amdgcn_mfma_f32_16x16x32_fp8_fp8(av[mi], bv[ni], acc[mi][ni], 0, 0, 0);
    }
    __builtin_amdgcn_s_setprio(0);
    __builtin_amdgcn_s_barrier();          // raw: all waves done reading buf
    buf ^= 1;
  }

  short* outp = P + pstride * sk;
  #pragma unroll
  for (int mi = 0; mi < 4; ++mi) {
    #pragma unroll
    for (int r = 0; r < 4; ++r) {
      const int m = m0 + wr * 64 + mi * 16 + lk * 4 + r;
      #pragma unroll
      for (int ni = 0; ni < 4; ++ni) {
        const int n = n0 + wc * 64 + ni * 16 + lr;
        outp[(size_t)m * ldC + n] = f2bf(acc[mi][ni][r]);
      }
    }
  }
}

// ---- reduce S partials + normalize; fallback substitutes raw h row (coalesced)
__global__ __launch_bounds__(256) void k_sk_reduce_sub(
    const short* __restrict__ P, int N, size_t pstride, int S,
    const float* __restrict__ colsum, const u32* __restrict__ colmax,
    const short* __restrict__ hraw, int ldh,
    short* __restrict__ out, int ldo)
{
  const int idx = blockIdx.x * 256 + threadIdx.x;
  const int nq = N >> 2;
  const int m = idx / nq;
  const int c4 = (idx - m * nq) * 4;
  const size_t base = (size_t)m * N + c4;
  float a0 = 0.f, a1 = 0.f, a2 = 0.f, a3 = 0.f;
  for (int s = 0; s < S; ++s) {
    s16x4 v = *(const s16x4*)&P[pstride * s + base];
    a0 += bf2f(v.x); a1 += bf2f(v.y); a2 += bf2f(v.z); a3 += bf2f(v.w);
  }
  const float cs = colsum[m];
  const float rc = 1.f / (cs + EPS_A);
  const float rcw = rc / (cs * rc + EPS_A);
  const bool he = __uint_as_float(colmax[m]) * rc > THR_A;
  s16x4 o;
  if (he) {
    o.x = f2bf(a0 * rcw); o.y = f2bf(a1 * rcw);
    o.z = f2bf(a2 * rcw); o.w = f2bf(a3 * rcw);
  } else {
    o = *(const s16x4*)&hraw[(size_t)m * ldh + c4];
  }
  *(s16x4*)&out[(size_t)m * ldo + c4] = o;
}

// ---- reduce S partials + normalize; fallback gathers bf16 T^T (rare, ballot-skip)
__global__ __launch_bounds__(256) void k_sk_reduce(
    const short* __restrict__ P, int N, size_t pstride, int S,
    const float* __restrict__ colsum, const u32* __restrict__ colmax,
    const short* __restrict__ Tfall, short* __restrict__ out, int ldo)
{
  const int idx = blockIdx.x * 256 + threadIdx.x;
  const int nq = N >> 2;
  const int m = idx / nq;
  const int c4 = (idx - m * nq) * 4;
  const size_t base = (size_t)m * N + c4;
  float a0 = 0.f, a1 = 0.f, a2 = 0.f, a3 = 0.f;
  for (int s = 0; s < S; ++s) {
    s16x4 v = *(const s16x4*)&P[pstride * s + base];
    a0 += bf2f(v.x); a1 += bf2f(v.y); a2 += bf2f(v.z); a3 += bf2f(v.w);
  }
  const float cs = colsum[m];
  const float rc = 1.f / (cs + EPS_A);
  const float rcw = rc / (cs * rc + EPS_A);
  const bool he = __uint_as_float(colmax[m]) * rc > THR_A;
  a0 *= rcw; a1 *= rcw; a2 *= rcw; a3 *= rcw;
  if (__ballot(!he)) {
    if (!he) {
      a0 = bf2f(Tfall[(size_t)(c4 + 0) * NN + m]);
      a1 = bf2f(Tfall[(size_t)(c4 + 1) * NN + m]);
      a2 = bf2f(Tfall[(size_t)(c4 + 2) * NN + m]);
      a3 = bf2f(Tfall[(size_t)(c4 + 3) * NN + m]);
    }
  }
  s16x4 o;
  o.x = f2bf(a0); o.y = f2bf(a1); o.z = f2bf(a2); o.w = f2bf(a3);
  *(s16x4*)&out[(size_t)m * ldo + c4] = o;
}

// ---- row LayerNorm + ReLU, fp32 in.  MODE 0: bf16 out (ld-strided), MODE 1: fp32 out
template <int MODE>
__device__ __forceinline__ void ln_relu_body(
    const float* __restrict__ X, int W,
    const float* __restrict__ g, const float* __restrict__ be,
    void* __restrict__ out, int ldo)
{
  const int row = blockIdx.x;
  const int t = threadIdx.x;
  const float* x = X + (size_t)row * W;
  float v0 = x[t], v1 = 0.f;
  float s = v0, ss = v0 * v0;
  if (W == 512) { v1 = x[t + 256]; s += v1; ss += v1 * v1; }
  #pragma unroll
  for (int off = 32; off; off >>= 1) {
    s += __shfl_down(s, off);
    ss += __shfl_down(ss, off);
  }
  __shared__ float red[8];
  const int wid = t >> 6;
  if ((t & 63) == 0) { red[wid] = s; red[4 + wid] = ss; }
  __syncthreads();
  s = red[0] + red[1] + red[2] + red[3];
  ss = red[4] + red[5] + red[6] + red[7];
  const float mu = s / W;
  const float var = ss / W - mu * mu;
  const float sc = rsqrtf(var + 1e-5f);
  float y = fmaxf((v0 - mu) * sc * g[t] + be[t], 0.f);
  if (MODE == 0) ((short*)out)[(size_t)row * ldo + t] = f2bf(y);
  else           ((float*)out)[(size_t)row * ldo + t] = y;
  if (W == 512) {
    float y1 = fmaxf((v1 - mu) * sc * g[t + 256] + be[t + 256], 0.f);
    if (MODE == 0) ((short*)out)[(size_t)row * ldo + t + 256] = f2bf(y1);
    else           ((float*)out)[(size_t)row * ldo + t + 256] = y1;
  }
}

__global__ __launch_bounds__(256) void k_ln_relu_bf16(
    const float* __restrict__ X, int W, const float* __restrict__ g,
    const float* __restrict__ be, short* __restrict__ out, int ldo) {
  ln_relu_body<0>(X, W, g, be, out, ldo);
}
__global__ __launch_bounds__(256) void k_ln_relu_f32(
    const float* __restrict__ X, int W, const float* __restrict__ g,
    const float* __restrict__ be, float* __restrict__ out, int ldo) {
  ln_relu_body<1>(X, W, g, be, out, ldo);
}

extern "C" void kernel_launch(void* const* d_in, const int* in_sizes, int n_in,
                              void* d_out, int out_size, void* d_ws, size_t ws_size,
                              hipStream_t stream) {
  const float* nf      = (const float*)d_in[0];
  const float* Mob     = (const float*)d_in[1];
  const float* W_in1   = (const float*)d_in[2];
  const float* b_in1   = (const float*)d_in[3];
  const float* W_out1  = (const float*)d_in[4];
  const float* b_out1  = (const float*)d_in[5];
  const float* W_self1 = (const float*)d_in[6];
  const float* b_self1 = (const float*)d_in[7];
  const float* g1      = (const float*)d_in[8];
  const float* be1     = (const float*)d_in[9];
  const float* W_in2   = (const float*)d_in[10];
  const float* b_in2   = (const float*)d_in[11];
  const float* W_out2  = (const float*)d_in[12];
  const float* b_out2  = (const float*)d_in[13];
  const float* W_self2 = (const float*)d_in[14];
  const float* b_self2 = (const float*)d_in[15];
  const float* g2      = (const float*)d_in[16];
  const float* be2     = (const float*)d_in[17];

  char* ws = (char*)d_ws;
  float* colsum = (float*)(ws);                       // 32 KB
  u32*   colmax = (u32*)(ws + 32768);                 // 32 KB
  u8*    Mt8    = (u8*)(ws + 131072);                 // [8192][8192] fp8 = 67 MB
  u8*    nft8   = (u8*)(ws + 67239936);               // [256][8192] fp8
  u8*    T2t8   = (u8*)(ws + 69337088);               // [256][8192] fp8
  short* A1cat  = (short*)(ws + 71434240);            // [8192][512]: [A1|nf]
  float* C2f    = (float*)(ws + 79822848);            // [8192][512] f32
  short* Acat2  = (short*)(ws + 96600064);            // [8192][768]: [agg2|h1]
  short* T2t    = (short*)(ws + 109182976);           // [256][8192] bf16 (fallback)
  short* Bcat1  = (short*)(ws + 113377280);           // [512][512]: [Wc1^T|Wself1^T]
  short* Bcat2  = (short*)(ws + 113901568);           // [256][768]
  short* Win2t  = (short*)(ws + 114294784);           // [256][512]
  short* Wout1t = (short*)(ws + 114556928);           // [512][512]
  short* Win1b  = (short*)(ws + 115081216);           // [256][512]
  float* bias1c = (float*)(ws + 115343360);           // [512]
  float* bias2c = (float*)(ws + 115345408);           // [256]
  short* P1     = (short*)(ws + 117440512);           // 8 x [8192][256] bf16
  short* P2     = (short*)(ws + 150994944);           // 8 x [8192][256] bf16

  hipMemsetAsync(ws, 0, 65536, stream);  // zero colsum + colmax every call

  k_prep_all<<<9603, 256, 0, stream>>>(Mob, nf, W_in1, W_out1, W_self1, W_in2,
                                       W_out2, W_self2, b_in1, b_out1, b_self1,
                                       b_out2, b_self2, Mt8, colsum, colmax, nft8,
                                       A1cat, Win1b, Wout1t, Bcat1, Win2t, Bcat2,
                                       bias1c, bias2c);
  // Wc1^T = W_out1^T @ W_in1 : [512][256] into Bcat1 cols 0:256
  k_gemm_raw_n<<<dim3(4, 8), 256, 0, stream>>>(Wout1t, Win1b, 512, 512, 512,
                                               Bcat1, 512);

  // ---- layer 1 (reassociated, fp8): G1 = Mt8 @ nft8^T (M=8192,N=256,K=8192,z=8)
  k_sk128_f8<<<dim3(2, 64, 8), 256, 0, stream>>>(Mt8, nft8, 1024, NN, NN,
                                                 P1, 256, (size_t)8192 * 256);
  k_sk_reduce_sub<<<2048, 256, 0, stream>>>(P1, 256, (size_t)8192 * 256, 8,
                                            colsum, colmax, A1cat + 256, 512,
                                            A1cat, 512);
  k_g64<128, 2><<<dim3(4, 128), 256, 0, stream>>>(A1cat, Bcat1, 512, 512, 512,
                                                  C2f, 512, bias1c, nullptr);
  k_ln_relu_bf16<<<8192, 256, 0, stream>>>(C2f, 512, g1, be1, Acat2 + 256, 768);

  // ---- layer 2: T2t (bf16 + fp8) = W_in2^T@h1^T + b_in2; fp8 agg2; out2; LN
  k_g64<64, 4><<<dim3(128, 4), 256, 0, stream>>>(Win2t, Acat2 + 256, 512, 512, 768,
                                                 T2t, NN, b_in2, T2t8);
  k_sk128_f8<<<dim3(2, 64, 8), 256, 0, stream>>>(Mt8, T2t8, 1024, NN, NN,
                                                 P2, 256, (size_t)8192 * 256);
  k_sk_reduce<<<2048, 256, 0, stream>>>(P2, 256, (size_t)8192 * 256, 8,
                                        colsum, colmax, T2t, Acat2, 768);
  k_g64<64, 2><<<dim3(4, 128), 256, 0, stream>>>(Acat2, Bcat2, 768, 768, 768,
                                                 C2f, 256, bias2c, nullptr);
  k_ln_relu_f32<<<8192, 256, 0, stream>>>(C2f, 256, g2, be2, (float*)d_out, 256);
}

// Round 22
// 262.620 us; speedup vs baseline: 2.5633x; 1.0027x over previous
//
#include <hip/hip_runtime.h>
#include <stdint.h>

typedef short bf16x8 __attribute__((ext_vector_type(8)));
typedef short s16x4 __attribute__((ext_vector_type(4)));
typedef float f32x4 __attribute__((ext_vector_type(4)));
typedef unsigned int u32;
typedef unsigned char u8;

#define EPS_A 1e-8f
#define THR_A 1e-6f
#define NN 8192

static __device__ __forceinline__ short f2bf(float f) {
  u32 u = __float_as_uint(f);
  u = u + 0x7FFFu + ((u >> 16) & 1u);   // RNE, no NaN inputs here
  return (short)(u >> 16);
}
static __device__ __forceinline__ float bf2f(short s) {
  return __uint_as_float(((u32)(unsigned short)s) << 16);
}
static __device__ __forceinline__ u8 f2fp8(float v) {
  return (u8)(__builtin_amdgcn_cvt_pk_fp8_f32(v, v, 0, false) & 0xff);
}
// async global->LDS, 16B per lane; DIRECT addrspacecasts (proven round 12)
static __device__ __forceinline__ void gld16(const void* g, void* l) {
  __builtin_amdgcn_global_load_lds(
      (const __attribute__((address_space(1))) u32*)g,
      (__attribute__((address_space(3))) u32*)l, 16, 0, 0);
}

// ---- fused prep: Mt8 (fp8) transpose-cast + colsum/colmax, weight/feature casts,
//      bias folds — ONE launch, 9603 blocks
__global__ __launch_bounds__(256) void k_prep_all(
    const float* __restrict__ Mob, const float* __restrict__ nf,
    const float* __restrict__ W_in1, const float* __restrict__ W_out1,
    const float* __restrict__ W_self1, const float* __restrict__ W_in2,
    const float* __restrict__ W_out2, const float* __restrict__ W_self2,
    const float* __restrict__ b_in1, const float* __restrict__ b_out1,
    const float* __restrict__ b_self1, const float* __restrict__ b_out2,
    const float* __restrict__ b_self2,
    u8* __restrict__ Mt8, float* __restrict__ colsum, u32* __restrict__ colmax,
    u8* __restrict__ nft8, short* __restrict__ A1cat, short* __restrict__ Win1b,
    short* __restrict__ Wout1t, short* __restrict__ Bcat1, short* __restrict__ Win2t,
    short* __restrict__ Bcat2, float* __restrict__ bias1c, float* __restrict__ bias2c)
{
  __shared__ __align__(16) u32 sbuf[256 * 17];   // 17408 B, reused per block role
  int b = blockIdx.x;
  const int t = threadIdx.x;
  if (b < 4096) {                      // Mt8: transpose-cast fp8 + colsum/colmax
    const int i0 = (b & 31) * 256;
    const int j0 = (b >> 5) * 64;
    const int i = i0 + t;
    float s = 0.f, mx = 0.f;
    #pragma unroll 4
    for (int j4 = 0; j4 < 16; ++j4) {
      float v0 = Mob[(size_t)(j0 + j4 * 4 + 0) * NN + i];
      float v1 = Mob[(size_t)(j0 + j4 * 4 + 1) * NN + i];
      float v2 = Mob[(size_t)(j0 + j4 * 4 + 2) * NN + i];
      float v3 = Mob[(size_t)(j0 + j4 * 4 + 3) * NN + i];
      s += v0 + v1 + v2 + v3;
      mx = fmaxf(fmaxf(mx, fmaxf(v0, v1)), fmaxf(v2, v3));
      u32 pk = __builtin_amdgcn_cvt_pk_fp8_f32(v0, v1, 0, false);
      pk = __builtin_amdgcn_cvt_pk_fp8_f32(v2, v3, (int)pk, true);
      sbuf[t * 17 + j4] = pk;
    }
    atomicAdd(&colsum[i], s);
    atomicMax(&colmax[i], __float_as_uint(mx));  // M >= 0: uint order == float order
    __syncthreads();
    #pragma unroll
    for (int p = 0; p < 4; ++p) {               // 64 rows/pass, 4 x 16B per row
      const int r = p * 64 + (t >> 2);
      const int c = t & 3;
      const u32* src = &sbuf[r * 17 + c * 4];
      int4 w = make_int4(src[0], src[1], src[2], src[3]);
      *(int4*)&Mt8[(size_t)(i0 + r) * NN + j0 + c * 16] = w;
    }
    return;
  }
  b -= 4096;
  if (b < 512) {                       // nf^T -> fp8: LDS-tiled transpose 8192x256
    u8* tile = (u8*)sbuf;              // [64][68]
    const int r0 = (b & 127) * 64, c0 = (b >> 7) * 64;
    #pragma unroll
    for (int p = 0; p < 16; ++p) {
      const int rr = p * 4 + (t >> 6), cc = t & 63;
      tile[rr * 68 + cc] = f2fp8(nf[(size_t)(r0 + rr) * 256 + c0 + cc]);
    }
    __syncthreads();
    #pragma unroll
    for (int q = 0; q < 16; ++q) {
      const int cc = q * 4 + (t >> 6), rr = t & 63;
      nft8[(size_t)(c0 + cc) * 8192 + r0 + rr] = tile[rr * 68 + cc];
    }
    return;
  }
  b -= 512;
  if (b < 2048) {                      // nf -> A1cat cols 256:512 (bf16)
    const int idx = b * 256 + t;
    const float4 v = ((const float4*)nf)[idx];
    const int i = idx >> 6;
    const int c = (idx & 63) * 4;
    s16x4 o;
    o.x = f2bf(v.x); o.y = f2bf(v.y); o.z = f2bf(v.z); o.w = f2bf(v.w);
    *(s16x4*)&A1cat[(size_t)i * 512 + 256 + c] = o;
    return;
  }
  b -= 2048;
  if (b < 128) {                       // W_in1 straight cast 256x512
    const int idx = b * 256 + t;
    const float4 v = ((const float4*)W_in1)[idx];
    s16x4 o;
    o.x = f2bf(v.x); o.y = f2bf(v.y); o.z = f2bf(v.z); o.w = f2bf(v.w);
    *(s16x4*)&Win1b[idx * 4] = o;
    return;
  }
  b -= 128;
  if (b < 1024) {                      // W_out1^T 512x512 -> Wout1t ld 512
    const int idx = b * 256 + t;
    const int r = idx >> 9, c = idx & 511;
    Wout1t[(size_t)c * 512 + r] = f2bf(W_out1[idx]);
    return;
  }
  b -= 1024;
  if (b < 512) {                       // W_self1^T 256x512 -> Bcat1+256 ld 512
    const int idx = b * 256 + t;
    const int r = idx >> 9, c = idx & 511;
    Bcat1[(size_t)c * 512 + 256 + r] = f2bf(W_self1[idx]);
    return;
  }
  b -= 512;
  if (b < 512) {                       // W_in2^T 512x256 -> Win2t ld 512
    const int idx = b * 256 + t;
    const int r = idx >> 8, c = idx & 255;
    Win2t[(size_t)c * 512 + r] = f2bf(W_in2[idx]);
    return;
  }
  b -= 512;
  if (b < 256) {                       // W_out2^T 256x256 -> Bcat2 ld 768
    const int idx = b * 256 + t;
    const int r = idx >> 8, c = idx & 255;
    Bcat2[(size_t)c * 768 + r] = f2bf(W_out2[idx]);
    return;
  }
  b -= 256;
  if (b < 512) {                       // W_self2^T 512x256 -> Bcat2+256 ld 768
    const int idx = b * 256 + t;
    const int r = idx >> 8, c = idx & 255;
    Bcat2[(size_t)c * 768 + 256 + r] = f2bf(W_self2[idx]);
    return;
  }
  b -= 512;
  if (b < 2) {                         // bias1c = b_in1@W_out1 + b_out1 + b_self1
    const int n = b * 256 + t;
    float a = b_out1[n] + b_self1[n];
    for (int p = 0; p < 512; ++p) a += b_in1[p] * W_out1[(size_t)p * 512 + n];
    bias1c[n] = a;
    return;
  }
  bias2c[t] = b_out2[t] + b_self2[t];  // last block
}

// ---- old 64x64 reg-staged body (kept ONLY for tiny Wc1 GEMM; proven)
__global__ __launch_bounds__(256) void k_gemm_raw_n(
    const short* __restrict__ A, const short* __restrict__ B, int K, int ldA, int ldB,
    short* __restrict__ C, int ldC)
{
  constexpr int LDP = 40;
  __shared__ __align__(16) short As[64 * LDP];
  __shared__ __align__(16) short Bs[64 * LDP];
  const int t = threadIdx.x;
  const int m0 = blockIdx.y * 64, n0 = blockIdx.x * 64;
  const int wid = t >> 6, l = t & 63;
  const int wr = wid >> 1, wc = wid & 1;
  const int lr = l & 15, lk = l >> 4;
  f32x4 acc[2][2] = {};
  const int sr = t >> 2;
  const int sc = (t & 3) * 8;
  const short* gA0 = A + (size_t)(m0 + sr) * ldA + sc;
  const short* gB0 = B + (size_t)(n0 + sr) * ldB + sc;
  for (int k0 = 0; k0 < K; k0 += 32) {
    const int4 a0 = *(const int4*)(gA0 + k0);
    const int4 b0 = *(const int4*)(gB0 + k0);
    __syncthreads();
    *(int4*)&As[sr * LDP + sc] = a0;
    *(int4*)&Bs[sr * LDP + sc] = b0;
    __syncthreads();
    bf16x8 av[2], bv[2];
    #pragma unroll
    for (int mi = 0; mi < 2; ++mi)
      av[mi] = *(const bf16x8*)&As[(wr * 32 + mi * 16 + lr) * LDP + lk * 8];
    #pragma unroll
    for (int ni = 0; ni < 2; ++ni)
      bv[ni] = *(const bf16x8*)&Bs[(wc * 32 + ni * 16 + lr) * LDP + lk * 8];
    #pragma unroll
    for (int mi = 0; mi < 2; ++mi)
      #pragma unroll
      for (int ni = 0; ni < 2; ++ni)
        acc[mi][ni] = __builtin_amdgcn_mfma_f32_16x16x32_bf16(av[mi], bv[ni], acc[mi][ni], 0, 0, 0);
  }
  #pragma unroll
  for (int mi = 0; mi < 2; ++mi)
    #pragma unroll
    for (int r = 0; r < 4; ++r) {
      const int m = m0 + wr * 32 + mi * 16 + lk * 4 + r;
      #pragma unroll
      for (int ni = 0; ni < 2; ++ni) {
        const int n = n0 + wc * 32 + ni * 16 + lr;
        C[(size_t)m * ldC + n] = f2bf(acc[mi][ni][r]);
      }
    }
}

// ---- 64 x BN bf16 GEMM, BK=64, DOUBLE-BUFFERED gld_lds staging (T4: counted
// vmcnt + raw s_barrier), swizzled unified LDS, staggered K, setprio.
// EPI 0: +bias0[m] bf16; EPI 2: +bias0[n] fp32; EPI 4: +bias0[m] bf16 AND fp8 copy.
template <int BN, int EPI>
__global__ __launch_bounds__(256) void k_g64(
    const short* __restrict__ A, const short* __restrict__ B, int K, int ldA, int ldB,
    void* __restrict__ Cout, int ldC, const float* __restrict__ bias0,
    u8* __restrict__ C8)
{
  constexpr int ROWS = 64 + BN;
  constexpr int CH = ROWS / 32;             // chunks per wave (8 rows each)
  constexpr int NI = BN / 32;
  __shared__ __align__(16) short S[2][ROWS * 64];
  const int t = threadIdx.x;

  const int gx = gridDim.x;
  int flat = blockIdx.y * gx + blockIdx.x;
  const int cpx = (gx * gridDim.y) >> 3;
  flat = (flat & 7) * cpx + (flat >> 3);
  const int bx = flat % gx, by = flat / gx;
  const int m0 = by * 64, n0 = bx * BN;

  const int wid = t >> 6, l = t & 63;
  const int wr = wid >> 1, wc = wid & 1;
  const int lr = l & 15, lk = l >> 4;

  f32x4 acc[2][NI] = {};

  const int lrow = l >> 3, lcol = l & 7;
  const int wbase = wid * (ROWS / 4);
  short* d0 = &S[0][wbase * 64];            // wave-uniform LDS bases
  short* d1 = &S[1][wbase * 64];
  const short* gsrc[CH];
  #pragma unroll
  for (int c = 0; c < CH; ++c) {
    const int ar = wbase + c * 8 + lrow;    // chunk wholly A or wholly B (8-aligned)
    const int scol = (lcol ^ (ar & 7)) * 8;
    gsrc[c] = (ar < 64) ? A + (size_t)(m0 + ar) * ldA + scol
                        : B + (size_t)(n0 + ar - 64) * ldB + scol;
  }

  const int niters = K >> 6;                // 8 or 12
  int kk = flat % niters;                   // staggered start
  // prologue: tile 0 -> buffer 0
  {
    const int koff = kk << 6;
    kk = (kk + 1 == niters) ? 0 : kk + 1;
    #pragma unroll
    for (int c = 0; c < CH; ++c)
      gld16(gsrc[c] + koff, d0 + c * 512);
  }

  int buf = 0;
  for (int it = 0; it < niters; ++it) {
    if (it + 1 < niters) {
      const int koff = kk << 6;
      kk = (kk + 1 == niters) ? 0 : kk + 1;
      short* nb = buf ? d0 : d1;
      #pragma unroll
      for (int c = 0; c < CH; ++c)
        gld16(gsrc[c] + koff, nb + c * 512);
      if constexpr (CH == 6)
        asm volatile("s_waitcnt vmcnt(6)" ::: "memory");
      else
        asm volatile("s_waitcnt vmcnt(4)" ::: "memory");
    } else {
      asm volatile("s_waitcnt vmcnt(0)" ::: "memory");
    }
    __builtin_amdgcn_sched_barrier(0);      // rule #18: pin LDS reads after wait
    __builtin_amdgcn_s_barrier();           // all waves' current tile ready

    const short* Sb = S[buf];
    __builtin_amdgcn_s_setprio(1);
    #pragma unroll
    for (int ks = 0; ks < 2; ++ks) {
      bf16x8 av[2], bv[NI];
      #pragma unroll
      for (int mi = 0; mi < 2; ++mi) {
        const int row = wr * 32 + mi * 16 + lr;
        av[mi] = *(const bf16x8*)&Sb[row * 64 + ((ks * 4 + lk) ^ (row & 7)) * 8];
      }
      #pragma unroll
      for (int ni = 0; ni < NI; ++ni) {
        const int row = 64 + wc * (BN / 2) + ni * 16 + lr;
        bv[ni] = *(const bf16x8*)&Sb[row * 64 + ((ks * 4 + lk) ^ (row & 7)) * 8];
      }
      #pragma unroll
      for (int mi = 0; mi < 2; ++mi)
        #pragma unroll
        for (int ni = 0; ni < NI; ++ni)
          acc[mi][ni] = __builtin_amdgcn_mfma_f32_16x16x32_bf16(av[mi], bv[ni], acc[mi][ni], 0, 0, 0);
    }
    __builtin_amdgcn_s_setprio(0);
    __builtin_amdgcn_s_barrier();           // all waves done reading buf
    buf ^= 1;
  }

  #pragma unroll
  for (int mi = 0; mi < 2; ++mi) {
    #pragma unroll
    for (int r = 0; r < 4; ++r) {
      const int m = m0 + wr * 32 + mi * 16 + lk * 4 + r;
      float bm = 0.f;
      if (EPI == 0 || EPI == 4) bm = bias0[m];
      #pragma unroll
      for (int ni = 0; ni < NI; ++ni) {
        const int n = n0 + wc * (BN / 2) + ni * 16 + lr;
        float v = acc[mi][ni][r];
        if (EPI == 0 || EPI == 4) {
          v += bm;
          ((short*)Cout)[(size_t)m * ldC + n] = f2bf(v);
          if (EPI == 4) C8[(size_t)m * ldC + n] = f2fp8(v);
        } else {
          ((float*)Cout)[(size_t)m * ldC + n] = v + bias0[n];
        }
      }
    }
  }
}

// ---- 128x128 split-K fp8 GEMM, BK=64 bytes, DOUBLE-BUFFERED gld_lds staging
// with counted vmcnt(4) + raw s_barrier (T4, proven r20).
// LDS S[2][16KB]: As @0, Bs @8192 per buffer; logical 16B-slot q at q^(row&3).
__global__ __launch_bounds__(256) void k_sk128_f8(
    const u8* __restrict__ A, const u8* __restrict__ B, int K, int ldA, int ldB,
    short* __restrict__ P, int ldC, size_t pstride)
{
  __shared__ __align__(16) u8 S[2][16384];   // 32 KB total
  const int t = threadIdx.x;

  const int sk = blockIdx.z;
  A += (size_t)sk * K;
  B += (size_t)sk * K;

  const int gx = gridDim.x;
  int flat = blockIdx.y * gx + blockIdx.x;
  const int cpx = (gx * gridDim.y) >> 3;
  flat = (flat & 7) * cpx + (flat >> 3);
  const int bx = flat % gx, by = flat / gx;
  const int m0 = by * 128, n0 = bx * 128;

  const int wid = t >> 6, l = t & 63;
  const int wr = wid >> 1, wc = wid & 1;
  const int lr = l & 15, lk = l >> 4;      // lk = k-group 0..3 (8B each)

  f32x4 acc[4][4] = {};

  const int side = wid >> 1;
  const int hrow = (wid & 1) * 64;
  const u8* Xp = side ? B : A;
  const int ldX = side ? ldB : ldA;
  const int x0 = side ? n0 : m0;
  const int doff = side * 8192 + hrow * 64;     // wave-uniform offset within buffer
  u8* d0 = &S[0][doff];
  u8* d1 = &S[1][doff];
  const u8* gsrc[4];
  #pragma unroll
  for (int c = 0; c < 4; ++c) {
    const int row = hrow + c * 16 + (l >> 2);
    const int ql = (l & 3) ^ (row & 3);
    gsrc[c] = Xp + (size_t)(x0 + row) * ldX + ql * 16;
  }

  const int niters = K >> 6;               // 16 for K=1024
  int kk = (flat + sk * 3) & (niters - 1); // staggered start
  // prologue: issue tile 0 into buffer 0
  {
    const int koff = kk << 6;
    kk = (kk + 1) & (niters - 1);
    gld16(gsrc[0] + koff, d0);
    gld16(gsrc[1] + koff, d0 + 1024);
    gld16(gsrc[2] + koff, d0 + 2048);
    gld16(gsrc[3] + koff, d0 + 3072);
  }

  int buf = 0;
  for (int it = 0; it < niters; ++it) {
    if (it + 1 < niters) {
      const int koff = kk << 6;
      kk = (kk + 1) & (niters - 1);
      u8* nb = buf ? d0 : d1;              // next buffer's wave region
      gld16(gsrc[0] + koff, nb);
      gld16(gsrc[1] + koff, nb + 1024);
      gld16(gsrc[2] + koff, nb + 2048);
      gld16(gsrc[3] + koff, nb + 3072);
      asm volatile("s_waitcnt vmcnt(4)" ::: "memory");  // current tile's 4 done
    } else {
      asm volatile("s_waitcnt vmcnt(0)" ::: "memory");  // final tile drain
    }
    __builtin_amdgcn_sched_barrier(0);     // rule #18: pin ds_reads after wait
    __builtin_amdgcn_s_barrier();          // raw: all waves' current tile ready

    const u8* Ab = &S[buf][0];
    const u8* Bb = &S[buf][8192];
    __builtin_amdgcn_s_setprio(1);
    #pragma unroll
    for (int ks = 0; ks < 2; ++ks) {       // 32-byte k-slices
      const int q = ks * 2 + (lk >> 1);    // logical 16B slot
      const int inner = (lk & 1) * 8;
      long av[4], bv[4];
      #pragma unroll
      for (int mi = 0; mi < 4; ++mi) {
        const int row = wr * 64 + mi * 16 + lr;
        av[mi] = *(const long*)&Ab[row * 64 + ((q ^ (row & 3)) << 4) + inner];
      }
      #pragma unroll
      for (int ni = 0; ni < 4; ++ni) {
        const int row = wc * 64 + ni * 16 + lr;
        bv[ni] = *(const long*)&Bb[row * 64 + ((q ^ (row & 3)) << 4) + inner];
      }
      #pragma unroll
      for (int mi = 0; mi < 4; ++mi)
        #pragma unroll
        for (int ni = 0; ni < 4; ++ni)
          acc[mi][ni] = __builtin_amdgcn_mfma_f32_16x16x32_fp8_fp8(av[mi], bv[ni], acc[mi][ni], 0, 0, 0);
    }
    __builtin_amdgcn_s_setprio(0);
    __builtin_amdgcn_s_barrier();          // raw: all waves done reading buf
    buf ^= 1;
  }

  short* outp = P + pstride * sk;
  #pragma unroll
  for (int mi = 0; mi < 4; ++mi) {
    #pragma unroll
    for (int r = 0; r < 4; ++r) {
      const int m = m0 + wr * 64 + mi * 16 + lk * 4 + r;
      #pragma unroll
      for (int ni = 0; ni < 4; ++ni) {
        const int n = n0 + wc * 64 + ni * 16 + lr;
        outp[(size_t)m * ldC + n] = f2bf(acc[mi][ni][r]);
      }
    }
  }
}

// ---- reduce 8 partials + normalize (8 elems/thread, fully unrolled);
// fallback substitutes raw h row (coalesced)
__global__ __launch_bounds__(256) void k_sk_reduce_sub(
    const short* __restrict__ P, int N, size_t pstride,
    const float* __restrict__ colsum, const u32* __restrict__ colmax,
    const short* __restrict__ hraw, int ldh,
    short* __restrict__ out, int ldo)
{
  const int idx = blockIdx.x * 256 + threadIdx.x;   // one 8-elem group per thread
  const int n8 = N >> 3;
  const int m = idx / n8;
  const int c8 = (idx - m * n8) * 8;
  const size_t base = (size_t)m * N + c8;
  float a[8] = {};
  #pragma unroll
  for (int s = 0; s < 8; ++s) {
    bf16x8 v = *(const bf16x8*)&P[pstride * s + base];
    #pragma unroll
    for (int e = 0; e < 8; ++e) a[e] += bf2f(v[e]);
  }
  const float cs = colsum[m];
  const float rc = 1.f / (cs + EPS_A);
  const float rcw = rc / (cs * rc + EPS_A);
  const bool he = __uint_as_float(colmax[m]) * rc > THR_A;
  bf16x8 o;
  if (he) {
    #pragma unroll
    for (int e = 0; e < 8; ++e) o[e] = f2bf(a[e] * rcw);
  } else {
    o = *(const bf16x8*)&hraw[(size_t)m * ldh + c8];
  }
  *(bf16x8*)&out[(size_t)m * ldo + c8] = o;
}

// ---- reduce 8 partials + normalize (8 elems/thread); fallback gathers bf16 T^T
__global__ __launch_bounds__(256) void k_sk_reduce(
    const short* __restrict__ P, int N, size_t pstride,
    const float* __restrict__ colsum, const u32* __restrict__ colmax,
    const short* __restrict__ Tfall, short* __restrict__ out, int ldo)
{
  const int idx = blockIdx.x * 256 + threadIdx.x;
  const int n8 = N >> 3;
  const int m = idx / n8;
  const int c8 = (idx - m * n8) * 8;
  const size_t base = (size_t)m * N + c8;
  float a[8] = {};
  #pragma unroll
  for (int s = 0; s < 8; ++s) {
    bf16x8 v = *(const bf16x8*)&P[pstride * s + base];
    #pragma unroll
    for (int e = 0; e < 8; ++e) a[e] += bf2f(v[e]);
  }
  const float cs = colsum[m];
  const float rc = 1.f / (cs + EPS_A);
  const float rcw = rc / (cs * rc + EPS_A);
  const bool he = __uint_as_float(colmax[m]) * rc > THR_A;
  #pragma unroll
  for (int e = 0; e < 8; ++e) a[e] *= rcw;
  if (__ballot(!he)) {
    if (!he) {
      #pragma unroll
      for (int e = 0; e < 8; ++e)
        a[e] = bf2f(Tfall[(size_t)(c8 + e) * NN + m]);
    }
  }
  bf16x8 o;
  #pragma unroll
  for (int e = 0; e < 8; ++e) o[e] = f2bf(a[e]);
  *(bf16x8*)&out[(size_t)m * ldo + c8] = o;
}

// ---- row LayerNorm + ReLU, fp32 in.  MODE 0: bf16 out (ld-strided), MODE 1: fp32 out
template <int MODE>
__device__ __forceinline__ void ln_relu_body(
    const float* __restrict__ X, int W,
    const float* __restrict__ g, const float* __restrict__ be,
    void* __restrict__ out, int ldo)
{
  const int row = blockIdx.x;
  const int t = threadIdx.x;
  const float* x = X + (size_t)row * W;
  float v0 = x[t], v1 = 0.f;
  float s = v0, ss = v0 * v0;
  if (W == 512) { v1 = x[t + 256]; s += v1; ss += v1 * v1; }
  #pragma unroll
  for (int off = 32; off; off >>= 1) {
    s += __shfl_down(s, off);
    ss += __shfl_down(ss, off);
  }
  __shared__ float red[8];
  const int wid = t >> 6;
  if ((t & 63) == 0) { red[wid] = s; red[4 + wid] = ss; }
  __syncthreads();
  s = red[0] + red[1] + red[2] + red[3];
  ss = red[4] + red[5] + red[6] + red[7];
  const float mu = s / W;
  const float var = ss / W - mu * mu;
  const float sc = rsqrtf(var + 1e-5f);
  float y = fmaxf((v0 - mu) * sc * g[t] + be[t], 0.f);
  if (MODE == 0) ((short*)out)[(size_t)row * ldo + t] = f2bf(y);
  else           ((float*)out)[(size_t)row * ldo + t] = y;
  if (W == 512) {
    float y1 = fmaxf((v1 - mu) * sc * g[t + 256] + be[t + 256], 0.f);
    if (MODE == 0) ((short*)out)[(size_t)row * ldo + t + 256] = f2bf(y1);
    else           ((float*)out)[(size_t)row * ldo + t + 256] = y1;
  }
}

__global__ __launch_bounds__(256) void k_ln_relu_bf16(
    const float* __restrict__ X, int W, const float* __restrict__ g,
    const float* __restrict__ be, short* __restrict__ out, int ldo) {
  ln_relu_body<0>(X, W, g, be, out, ldo);
}
__global__ __launch_bounds__(256) void k_ln_relu_f32(
    const float* __restrict__ X, int W, const float* __restrict__ g,
    const float* __restrict__ be, float* __restrict__ out, int ldo) {
  ln_relu_body<1>(X, W, g, be, out, ldo);
}

extern "C" void kernel_launch(void* const* d_in, const int* in_sizes, int n_in,
                              void* d_out, int out_size, void* d_ws, size_t ws_size,
                              hipStream_t stream) {
  const float* nf      = (const float*)d_in[0];
  const float* Mob     = (const float*)d_in[1];
  const float* W_in1   = (const float*)d_in[2];
  const float* b_in1   = (const float*)d_in[3];
  const float* W_out1  = (const float*)d_in[4];
  const float* b_out1  = (const float*)d_in[5];
  const float* W_self1 = (const float*)d_in[6];
  const float* b_self1 = (const float*)d_in[7];
  const float* g1      = (const float*)d_in[8];
  const float* be1     = (const float*)d_in[9];
  const float* W_in2   = (const float*)d_in[10];
  const float* b_in2   = (const float*)d_in[11];
  const float* W_out2  = (const float*)d_in[12];
  const float* b_out2  = (const float*)d_in[13];
  const float* W_self2 = (const float*)d_in[14];
  const float* b_self2 = (const float*)d_in[15];
  const float* g2      = (const float*)d_in[16];
  const float* be2     = (const float*)d_in[17];

  char* ws = (char*)d_ws;
  float* colsum = (float*)(ws);                       // 32 KB
  u32*   colmax = (u32*)(ws + 32768);                 // 32 KB
  u8*    Mt8    = (u8*)(ws + 131072);                 // [8192][8192] fp8 = 67 MB
  u8*    nft8   = (u8*)(ws + 67239936);               // [256][8192] fp8
  u8*    T2t8   = (u8*)(ws + 69337088);               // [256][8192] fp8
  short* A1cat  = (short*)(ws + 71434240);            // [8192][512]: [A1|nf]
  float* C2f    = (float*)(ws + 79822848);            // [8192][512] f32
  short* Acat2  = (short*)(ws + 96600064);            // [8192][768]: [agg2|h1]
  short* T2t    = (short*)(ws + 109182976);           // [256][8192] bf16 (fallback)
  short* Bcat1  = (short*)(ws + 113377280);           // [512][512]: [Wc1^T|Wself1^T]
  short* Bcat2  = (short*)(ws + 113901568);           // [256][768]
  short* Win2t  = (short*)(ws + 114294784);           // [256][512]
  short* Wout1t = (short*)(ws + 114556928);           // [512][512]
  short* Win1b  = (short*)(ws + 115081216);           // [256][512]
  float* bias1c = (float*)(ws + 115343360);           // [512]
  float* bias2c = (float*)(ws + 115345408);           // [256]
  short* P1     = (short*)(ws + 117440512);           // 8 x [8192][256] bf16
  short* P2     = (short*)(ws + 150994944);           // 8 x [8192][256] bf16

  hipMemsetAsync(ws, 0, 65536, stream);  // zero colsum + colmax every call

  k_prep_all<<<9603, 256, 0, stream>>>(Mob, nf, W_in1, W_out1, W_self1, W_in2,
                                       W_out2, W_self2, b_in1, b_out1, b_self1,
                                       b_out2, b_self2, Mt8, colsum, colmax, nft8,
                                       A1cat, Win1b, Wout1t, Bcat1, Win2t, Bcat2,
                                       bias1c, bias2c);
  // Wc1^T = W_out1^T @ W_in1 : [512][256] into Bcat1 cols 0:256
  k_gemm_raw_n<<<dim3(4, 8), 256, 0, stream>>>(Wout1t, Win1b, 512, 512, 512,
                                               Bcat1, 512);

  // ---- layer 1 (reassociated, fp8): G1 = Mt8 @ nft8^T (M=8192,N=256,K=8192,z=8)
  k_sk128_f8<<<dim3(2, 64, 8), 256, 0, stream>>>(Mt8, nft8, 1024, NN, NN,
                                                 P1, 256, (size_t)8192 * 256);
  k_sk_reduce_sub<<<1024, 256, 0, stream>>>(P1, 256, (size_t)8192 * 256,
                                            colsum, colmax, A1cat + 256, 512,
                                            A1cat, 512);
  k_g64<128, 2><<<dim3(4, 128), 256, 0, stream>>>(A1cat, Bcat1, 512, 512, 512,
                                                  C2f, 512, bias1c, nullptr);
  k_ln_relu_bf16<<<8192, 256, 0, stream>>>(C2f, 512, g1, be1, Acat2 + 256, 768);

  // ---- layer 2: T2t (bf16 + fp8) = W_in2^T@h1^T + b_in2; fp8 agg2; out2; LN
  k_g64<64, 4><<<dim3(128, 4), 256, 0, stream>>>(Win2t, Acat2 + 256, 512, 512, 768,
                                                 T2t, NN, b_in2, T2t8);
  k_sk128_f8<<<dim3(2, 64, 8), 256, 0, stream>>>(Mt8, T2t8, 1024, NN, NN,
                                                 P2, 256, (size_t)8192 * 256);
  k_sk_reduce<<<1024, 256, 0, stream>>>(P2, 256, (size_t)8192 * 256,
                                        colsum, colmax, T2t, Acat2, 768);
  k_g64<64, 2><<<dim3(4, 128), 256, 0, stream>>>(Acat2, Bcat2, 768, 768, 768,
                                                 C2f, 256, bias2c, nullptr);
  k_ln_relu_f32<<<8192, 256, 0, stream>>>(C2f, 256, g2, be2, (float*)d_out, 256);
}